// Round 8
// baseline (1741.898 us; speedup 1.0000x reference)
//
#include <hip/hip_runtime.h>

// ============================================================================
// MUCRP_17265768530653 — cross-domain VAE forward on MI355X (gfx950)
// Round 9 (R7 base = R5 + tranupd-factorization):
//  - FGW 1024^3 GEMMs fat-tiled: 128x128, 8 waves, 64 blocks (2x the
//    MFMA:staging ratio — R7 showed these kernels are staging-bound)
//  - GMM fused into enc_fused; cyc-sqdiff fused into renc_head
//  - init folded into transpose4; both decoder GEMM launches merged (z=0..3)
// ============================================================================

#define DEVI __device__ __forceinline__

typedef __attribute__((ext_vector_type(4))) float  f32x4;
typedef __attribute__((ext_vector_type(4))) short  s16x4;
typedef __attribute__((ext_vector_type(8))) short  s16x8;
typedef __attribute__((ext_vector_type(8))) __bf16 bf16x8;

#define PS (1.f / 1024.f)
#define UNIF (1.f / (1024.f * 1024.f))

DEVI short f2bf(float f) {              // RNE f32 -> bf16 (bits)
  unsigned u = __float_as_uint(f);
  u += 0x7fffu + ((u >> 16) & 1u);
  return (short)(u >> 16);
}
DEVI float bf2f(unsigned short u) { return __uint_as_float(((unsigned)u) << 16); }

DEVI f32x4 mfma16(bf16x8 a, bf16x8 b, f32x4 c) {
  return __builtin_amdgcn_mfma_f32_16x16x32_bf16(a, b, c, 0, 0, 0);
}

// ---------------------------------------------------------------------------
// Generic tiled MFMA GEMM body (verified R1/R3/R4/R5/R7).
// ---------------------------------------------------------------------------
struct GemmArgs {
  const float* Af;
  const unsigned short* Bt;
  float* outF;
  const float* bias;
  float* partials;
  int M, N, K;
  int lda, ldbt, ldc;
  int totSteps, nSplits;
};

enum { EPI_PARTIAL, EPI_BIAS, EPI_COST, EPI_LOSS };

template<int BM, int BN, int WR, int WC, int EPI>
DEVI void gemm_body(const GemmArgs g)
{
  constexpr int BK = 64, BKP = 72;
  constexpr int NT = WR * WC * 64;
  __shared__ short As[BM * BKP];
  __shared__ short Bs[BN * BKP];

  const int m0 = blockIdx.x * BM;
  int n0 = 0, kb0 = 0, kb1 = g.K, split = 0;
  if constexpr (EPI == EPI_PARTIAL) {
    split = blockIdx.y;
    int s0 = (split * g.totSteps) / g.nSplits;
    int s1 = ((split + 1) * g.totSteps) / g.nSplits;
    kb0 = s0 * BK;
    kb1 = s1 * BK; if (kb1 > g.K) kb1 = g.K;
  } else {
    n0 = blockIdx.y * BN;
  }
  const int tid  = threadIdx.x;
  const int lane = tid & 63;
  const int wv   = tid >> 6;
  const int wr   = wv % WR;
  const int wc   = wv / WR;

  f32x4 acc[2][4];
  #pragma unroll
  for (int i = 0; i < 2; ++i)
    #pragma unroll
    for (int j = 0; j < 4; ++j) acc[i][j] = f32x4{0.f, 0.f, 0.f, 0.f};

  for (int kb = kb0; kb < kb1; kb += BK) {
    {   // stage A (f32 -> bf16)
      constexpr int NV = BM * BK / 4;
      #pragma unroll
      for (int i = 0; i < NV / NT; ++i) {
        int idx = tid + NT * i;
        int r = idx >> 4, q = idx & 15;
        int k = kb + 4 * q;
        f32x4 v = f32x4{0.f, 0.f, 0.f, 0.f};
        if (k < kb1) v = *(const f32x4*)(g.Af + (size_t)(m0 + r) * g.lda + k);
        s16x4 s;
        s.x = f2bf(v.x); s.y = f2bf(v.y); s.z = f2bf(v.z); s.w = f2bf(v.w);
        *(s16x4*)&As[r * BKP + 4 * q] = s;
      }
    }
    {   // stage B (bf16 [N][K])
      constexpr int NV = BN * BK / 8;
      #pragma unroll
      for (int i = 0; i < NV / NT; ++i) {
        int idx = tid + NT * i;
        int r = idx >> 3, q = idx & 7;
        int k = kb + 8 * q;
        s16x8 v{};
        if ((n0 + r) < g.N && k < kb1)
          v = *(const s16x8*)(g.Bt + (size_t)(n0 + r) * g.ldbt + k);
        *(s16x8*)&Bs[r * BKP + 8 * q] = v;
      }
    }
    __syncthreads();
    #pragma unroll
    for (int s = 0; s < 2; ++s) {
      const int ko = 32 * s + 8 * (lane >> 4);
      bf16x8 a0 = *(const bf16x8*)&As[(wr * 32 +      (lane & 15)) * BKP + ko];
      bf16x8 a1 = *(const bf16x8*)&As[(wr * 32 + 16 + (lane & 15)) * BKP + ko];
      #pragma unroll
      for (int fn = 0; fn < 4; ++fn) {
        bf16x8 b = *(const bf16x8*)&Bs[(wc * 64 + fn * 16 + (lane & 15)) * BKP + ko];
        acc[0][fn] = mfma16(a0, b, acc[0][fn]);
        acc[1][fn] = mfma16(a1, b, acc[1][fn]);
      }
    }
    __syncthreads();
  }

  #pragma unroll
  for (int fm = 0; fm < 2; ++fm) {
    #pragma unroll
    for (int fn = 0; fn < 4; ++fn) {
      #pragma unroll
      for (int p = 0; p < 4; ++p) {
        int gm = m0 + wr * 32 + fm * 16 + (lane >> 4) * 4 + p;
        int gn = n0 + wc * 64 + fn * 16 + (lane & 15);
        float v = acc[fm][fn][p];
        if constexpr (EPI == EPI_PARTIAL) {
          g.partials[((size_t)split * g.M + gm) * 256 + gn] = v;
        } else {
          if (gn < g.N) g.outF[(size_t)gm * g.ldc + gn] = v + g.bias[gn];
        }
      }
    }
  }
}

struct Q4 { GemmArgs g[4]; };

template<int BM, int BN, int WR, int WC, int EPI>
__global__ __launch_bounds__(WR*WC*64)
void k_gemmN(Q4 q)
{
  GemmArgs g = q.g[blockIdx.z];
  if constexpr (EPI == EPI_BIAS) {
    if ((int)(blockIdx.y * BN) >= g.N) return;
  }
  gemm_body<BM, BN, WR, WC, EPI>(g);
}

// ---------------------------------------------------------------------------
// FGW GEMM1' fat tile: U[m][n] = bscale * sum_k bf16(cpost[m][k]*dinv[k])
//                                          * bf16(KT[n][k])
// 128x128 tile, 8 waves (2x4), grid 64.
// ---------------------------------------------------------------------------
struct G1Args {
  const unsigned short* A;
  const float* KT;
  const float* dinv;
  const float* braw;
  unsigned short* U;
  const unsigned* nflag;
  int mode;   // 0: uniform  1: factors  2: factors unless nanflag
};

__global__ __launch_bounds__(512)
void k_fgw_g1(G1Args a)
{
  __shared__ short As[128 * 72];
  __shared__ short Bs[128 * 72];
  const bool uni = (a.mode == 0) || (a.mode == 2 && *a.nflag != 0u);

  const int bid = blockIdx.x, tid = threadIdx.x;
  const int lane = tid & 63, wv = tid >> 6;
  const int wr = wv & 1, wc = wv >> 1;              // 2x4 waves, 64x32 each
  const int m0 = (bid >> 3) * 128, n0 = (bid & 7) * 128;

  f32x4 acc[4][2];
  #pragma unroll
  for (int i = 0; i < 4; ++i)
    #pragma unroll
    for (int j = 0; j < 2; ++j) acc[i][j] = f32x4{0.f, 0.f, 0.f, 0.f};

  const short ub = f2bf(UNIF);

  for (int kb = 0; kb < 1024; kb += 64) {
    #pragma unroll
    for (int i = 0; i < 2; ++i) {
      int idx = tid + 512 * i;
      int r = idx >> 3, q = idx & 7;
      s16x8 av = *(const s16x8*)&a.A[(size_t)(m0 + r) * 1024 + kb + 8 * q];
      if (!uni) {
        f32x4 d0 = *(const f32x4*)&a.dinv[kb + 8 * q];
        f32x4 d1 = *(const f32x4*)&a.dinv[kb + 8 * q + 4];
        s16x8 o;
        o[0] = f2bf(bf2f((unsigned short)av[0]) * d0.x);
        o[1] = f2bf(bf2f((unsigned short)av[1]) * d0.y);
        o[2] = f2bf(bf2f((unsigned short)av[2]) * d0.z);
        o[3] = f2bf(bf2f((unsigned short)av[3]) * d0.w);
        o[4] = f2bf(bf2f((unsigned short)av[4]) * d1.x);
        o[5] = f2bf(bf2f((unsigned short)av[5]) * d1.y);
        o[6] = f2bf(bf2f((unsigned short)av[6]) * d1.z);
        o[7] = f2bf(bf2f((unsigned short)av[7]) * d1.w);
        av = o;
      }
      *(s16x8*)&As[r * 72 + 8 * q] = av;
      s16x8 bv;
      if (uni) {
        #pragma unroll
        for (int j = 0; j < 8; ++j) bv[j] = ub;
      } else {
        f32x4 k0 = *(const f32x4*)&a.KT[(size_t)(n0 + r) * 1024 + kb + 8 * q];
        f32x4 k1 = *(const f32x4*)&a.KT[(size_t)(n0 + r) * 1024 + kb + 8 * q + 4];
        bv[0] = f2bf(k0.x); bv[1] = f2bf(k0.y); bv[2] = f2bf(k0.z); bv[3] = f2bf(k0.w);
        bv[4] = f2bf(k1.x); bv[5] = f2bf(k1.y); bv[6] = f2bf(k1.z); bv[7] = f2bf(k1.w);
      }
      *(s16x8*)&Bs[r * 72 + 8 * q] = bv;
    }
    __syncthreads();
    #pragma unroll
    for (int s = 0; s < 2; ++s) {
      const int ko = 32 * s + 8 * (lane >> 4);
      bf16x8 b0 = *(const bf16x8*)&Bs[(wc * 32 +      (lane & 15)) * 72 + ko];
      bf16x8 b1 = *(const bf16x8*)&Bs[(wc * 32 + 16 + (lane & 15)) * 72 + ko];
      #pragma unroll
      for (int fm = 0; fm < 4; ++fm) {
        bf16x8 af = *(const bf16x8*)&As[(wr * 64 + fm * 16 + (lane & 15)) * 72 + ko];
        acc[fm][0] = mfma16(af, b0, acc[fm][0]);
        acc[fm][1] = mfma16(af, b1, acc[fm][1]);
      }
    }
    __syncthreads();
  }

  #pragma unroll
  for (int fm = 0; fm < 4; ++fm) {
    #pragma unroll
    for (int fn = 0; fn < 2; ++fn) {
      int gn = n0 + wc * 32 + fn * 16 + (lane & 15);
      float bs = uni ? 1.f : (PS / a.braw[gn]);
      #pragma unroll
      for (int p = 0; p < 4; ++p) {
        int gm = m0 + wr * 64 + fm * 16 + (lane >> 4) * 4 + p;
        float v = acc[fm][fn][p];
        a.U[(size_t)gm * 1024 + gn] = (unsigned short)f2bf(uni ? v : bs * v);
      }
    }
  }
}

// ---------------------------------------------------------------------------
// FGW GEMM (COST / LOSS), fat tile 128x128, 8 waves, grid 64.
// ---------------------------------------------------------------------------
struct FgwGemmArgs {
  const unsigned short* A;
  const unsigned short* Bt;
  float* cost;
  const float* f1;
  const float* f2;
  const float* cpp;
  unsigned* mx;
  float* loss;
  float* braw2;
  const float* Kf;
  const float* dinv;
  const float* brawv;
  const unsigned* nflag;
};

template<int EPI>
__global__ __launch_bounds__(512)
void k_fgw_gemm(FgwGemmArgs a)
{
  __shared__ short As[128 * 72];
  __shared__ short Bs[128 * 72];
  __shared__ float red[8];

  const int bid = blockIdx.x, tid = threadIdx.x;
  const int lane = tid & 63, wv = tid >> 6;
  const int wr = wv & 1, wc = wv >> 1;
  const int m0 = (bid >> 3) * 128, n0 = (bid & 7) * 128;

  if constexpr (EPI == EPI_COST) {
    if (bid == 0) {
      #pragma unroll
      for (int i = 0; i < 2; ++i) a.braw2[tid + 512 * i] = 0.f;
    }
  }

  f32x4 acc[4][2];
  #pragma unroll
  for (int i = 0; i < 4; ++i)
    #pragma unroll
    for (int j = 0; j < 2; ++j) acc[i][j] = f32x4{0.f, 0.f, 0.f, 0.f};

  for (int kb = 0; kb < 1024; kb += 64) {
    #pragma unroll
    for (int i = 0; i < 2; ++i) {
      int idx = tid + 512 * i;
      int r = idx >> 3, q = idx & 7;
      *(s16x8*)&As[r * 72 + 8 * q] = *(const s16x8*)&a.A [(size_t)(m0 + r) * 1024 + kb + 8 * q];
      *(s16x8*)&Bs[r * 72 + 8 * q] = *(const s16x8*)&a.Bt[(size_t)(n0 + r) * 1024 + kb + 8 * q];
    }
    __syncthreads();
    #pragma unroll
    for (int s = 0; s < 2; ++s) {
      const int ko = 32 * s + 8 * (lane >> 4);
      bf16x8 b0 = *(const bf16x8*)&Bs[(wc * 32 +      (lane & 15)) * 72 + ko];
      bf16x8 b1 = *(const bf16x8*)&Bs[(wc * 32 + 16 + (lane & 15)) * 72 + ko];
      #pragma unroll
      for (int fm = 0; fm < 4; ++fm) {
        bf16x8 af = *(const bf16x8*)&As[(wr * 64 + fm * 16 + (lane & 15)) * 72 + ko];
        acc[fm][0] = mfma16(af, b0, acc[fm][0]);
        acc[fm][1] = mfma16(af, b1, acc[fm][1]);
      }
    }
    __syncthreads();
  }

  bool uni = false;
  if constexpr (EPI == EPI_LOSS) uni = (*a.nflag != 0u);

  float lred = 0.f;
  #pragma unroll
  for (int fm = 0; fm < 4; ++fm) {
    #pragma unroll
    for (int fn = 0; fn < 2; ++fn) {
      int gn = n0 + wc * 32 + fn * 16 + (lane & 15);
      float bs = 0.f;
      if constexpr (EPI == EPI_LOSS) bs = uni ? 0.f : (PS / a.brawv[gn]);
      #pragma unroll
      for (int p = 0; p < 4; ++p) {
        int gm = m0 + wr * 64 + fm * 16 + (lane >> 4) * 4 + p;
        float v = acc[fm][fn][p];
        size_t o = (size_t)gm * 1024 + gn;
        float c = 0.1f * (a.f1[gm] + a.f2[gn] - 2.f * v) + 0.9f * a.cpp[o];
        if constexpr (EPI == EPI_COST) {
          a.cost[o] = c;
          lred = fmaxf(lred, fabsf(c));
        } else {
          float trec = uni ? UNIF : (a.dinv[gm] * bs) * a.Kf[o];
          lred += c * trec;
        }
      }
    }
  }
  #pragma unroll
  for (int off = 32; off; off >>= 1) {
    float t = __shfl_xor(lred, off, 64);
    lred = (EPI == EPI_COST) ? fmaxf(lred, t) : (lred + t);
  }
  if (lane == 0) red[wv] = lred;
  __syncthreads();
  if (tid == 0) {
    float t = red[0];
    #pragma unroll
    for (int i = 1; i < 8; ++i)
      t = (EPI == EPI_COST) ? fmaxf(t, red[i]) : (t + red[i]);
    if constexpr (EPI == EPI_COST) atomicMax(a.mx, __float_as_uint(t));
    else atomicAdd(a.loss, t);
  }
}

// ---------------------------------------------------------------------------
// kbuild: tran reconstructed from (K_old, dinv, braw_old) bit-identically,
// K_new = exp(-cost/mx)*tran (in place), KT, braw2 seed.  Grid (16,16)x256.
// ---------------------------------------------------------------------------
__global__ __launch_bounds__(256)
void k_kbuild(const float* cost, const unsigned* mxbits, float* K, float* KT,
              const float* dinv, const float* brawOld, float* braw2, int uniform)
{
  __shared__ float tt[64 * 65];
  __shared__ float dS[64];
  __shared__ float bS[64];
  __shared__ float csum[4][64];
  const int r0 = blockIdx.x * 64, c0 = blockIdx.y * 64;
  const int tid = threadIdx.x;
  const float inv = 1.f / __uint_as_float(*mxbits);
  if (tid < 64) dS[tid] = dinv[r0 + tid];
  else if (tid >= 64 && tid < 128 && !uniform) bS[tid - 64] = PS / brawOld[c0 + tid - 64];
  __syncthreads();
  float colp = 0.f;
  #pragma unroll
  for (int i = 0; i < 16; ++i) {
    int idx = tid + 256 * i;
    int r = idx >> 6, c = idx & 63;
    size_t o = (size_t)(r0 + r) * 1024 + (c0 + c);
    float trec = uniform ? UNIF : (dS[r] * bS[c]) * K[o];
    float v = expf(-cost[o] * inv) * trec;
    K[o] = v;
    tt[r * 65 + c] = v;
    colp += v * dS[r];
  }
  csum[tid >> 6][tid & 63] = colp;
  __syncthreads();
  #pragma unroll
  for (int i = 0; i < 16; ++i) {
    int idx = tid + 256 * i;
    int c = idx >> 6, r = idx & 63;
    KT[(size_t)(c0 + c) * 1024 + (r0 + r)] = tt[r * 65 + c];
  }
  if (tid < 64)
    atomicAdd(&braw2[c0 + tid],
              csum[0][tid] + csum[1][tid] + csum[2][tid] + csum[3][tid]);
}

// y_raw[r] = M[r,:].(PS/x_raw); optionally emits invOut = PS/x (last matvec).
__global__ __launch_bounds__(256)
void k_matvec(const float* M, const float* xraw, float* yraw, float* invOut)
{
  const int r = blockIdx.x * 4 + (threadIdx.x >> 6);
  const int lane = threadIdx.x & 63;
  const int wv = threadIdx.x >> 6;
  const f32x4* row = (const f32x4*)(M + (size_t)r * 1024);
  const f32x4* xv  = (const f32x4*)xraw;
  float s = 0.f;
  #pragma unroll
  for (int q = 0; q < 4; ++q) {
    f32x4 a = row[lane + 64 * q];
    f32x4 x = xv [lane + 64 * q];
    f32x4 iv;
    iv.x = PS / x.x; iv.y = PS / x.y; iv.z = PS / x.z; iv.w = PS / x.w;
    if (invOut && blockIdx.x == 0 && wv == 0)
      *(f32x4*)&invOut[4 * (lane + 64 * q)] = iv;
    s += a.x * iv.x + a.y * iv.y + a.z * iv.z + a.w * iv.w;
  }
  #pragma unroll
  for (int o = 32; o; o >>= 1) s += __shfl_xor(s, o, 64);
  if (lane == 0) yraw[r] = s;
}

// NaN scan over reconstructed tran.
__global__ __launch_bounds__(256)
void k_nanscan(const float* K, const float* dinv, const float* braw, unsigned* flag)
{
  unsigned bad = 0;
  const int base = blockIdx.x * 256 + threadIdx.x;
  #pragma unroll
  for (int i = 0; i < 16; ++i) {
    int idx = base + 65536 * i;
    int r = idx >> 10, c = idx & 1023;
    float v = (dinv[r] * (PS / braw[c])) * K[idx];
    if (v != v) bad = 1u;
  }
  if (bad) atomicOr(flag, 1u);
}

// ---------------------------------------------------------------------------
// Distance via MFMA expanded form (verified R5).
// ---------------------------------------------------------------------------
struct DistMMArgs {
  const unsigned short* Fx[3]; const unsigned short* Fy[3];
  const float* nx[3]; const float* ny[3];
  unsigned short* outB[2]; float* outF; float* frow[2];
};
__global__ __launch_bounds__(256)
void k_distmm(DistMMArgs a)
{
  __shared__ short As[64 * 72];
  __shared__ short Bs[64 * 72];
  const int z = blockIdx.y;
  const int bid = blockIdx.x, tid = threadIdx.x;
  const int lane = tid & 63, wv = tid >> 6;
  const int wr = wv & 1, wc = wv >> 1;
  const int m0 = (bid >> 4) * 64, n0 = (bid & 15) * 64;
  const unsigned short* X = a.Fx[z];
  const unsigned short* Y = a.Fy[z];

  f32x4 acc[2][2];
  #pragma unroll
  for (int i = 0; i < 2; ++i)
    #pragma unroll
    for (int j = 0; j < 2; ++j) acc[i][j] = f32x4{0.f, 0.f, 0.f, 0.f};

  #pragma unroll
  for (int kb = 0; kb < 128; kb += 64) {
    #pragma unroll
    for (int i = 0; i < 2; ++i) {
      int idx = tid + 256 * i;
      int r = idx >> 3, q = idx & 7;
      *(s16x8*)&As[r * 72 + 8 * q] = *(const s16x8*)&X[(size_t)(m0 + r) * 128 + kb + 8 * q];
      *(s16x8*)&Bs[r * 72 + 8 * q] = *(const s16x8*)&Y[(size_t)(n0 + r) * 128 + kb + 8 * q];
    }
    __syncthreads();
    #pragma unroll
    for (int s = 0; s < 2; ++s) {
      const int ko = 32 * s + 8 * (lane >> 4);
      bf16x8 a0 = *(const bf16x8*)&As[(wr * 32 +      (lane & 15)) * 72 + ko];
      bf16x8 a1 = *(const bf16x8*)&As[(wr * 32 + 16 + (lane & 15)) * 72 + ko];
      bf16x8 b0 = *(const bf16x8*)&Bs[(wc * 32 +      (lane & 15)) * 72 + ko];
      bf16x8 b1 = *(const bf16x8*)&Bs[(wc * 32 + 16 + (lane & 15)) * 72 + ko];
      acc[0][0] = mfma16(a0, b0, acc[0][0]);
      acc[1][0] = mfma16(a1, b0, acc[1][0]);
      acc[0][1] = mfma16(a0, b1, acc[0][1]);
      acc[1][1] = mfma16(a1, b1, acc[1][1]);
    }
    __syncthreads();
  }

  const float* nxp = a.nx[z];
  const float* nyp = a.ny[z];
  float rp[2][4];
  #pragma unroll
  for (int fm = 0; fm < 2; ++fm)
    #pragma unroll
    for (int p = 0; p < 4; ++p) rp[fm][p] = 0.f;

  #pragma unroll
  for (int fm = 0; fm < 2; ++fm) {
    #pragma unroll
    for (int fn = 0; fn < 2; ++fn) {
      #pragma unroll
      for (int p = 0; p < 4; ++p) {
        int gm = m0 + wr * 32 + fm * 16 + (lane >> 4) * 4 + p;
        int gn = n0 + wc * 32 + fn * 16 + (lane & 15);
        float val = nxp[gm] + nyp[gn] - 2.f * acc[fm][fn][p] + 1e-6f;
        if (z == 2) a.outF[(size_t)gm * 1024 + gn] = val;
        else {
          a.outB[z][(size_t)gm * 1024 + gn] = (unsigned short)f2bf(val);
          rp[fm][p] += val * val;
        }
      }
    }
  }
  if (z < 2) {
    #pragma unroll
    for (int fm = 0; fm < 2; ++fm)
      #pragma unroll
      for (int p = 0; p < 4; ++p) {
        float v = rp[fm][p];
        v += __shfl_xor(v, 1, 64);
        v += __shfl_xor(v, 2, 64);
        v += __shfl_xor(v, 4, 64);
        v += __shfl_xor(v, 8, 64);
        rp[fm][p] = v;
      }
    if ((lane & 15) == 0) {
      #pragma unroll
      for (int fm = 0; fm < 2; ++fm)
        #pragma unroll
        for (int p = 0; p < 4; ++p) {
          int gm = m0 + wr * 32 + fm * 16 + (lane >> 4) * 4 + p;
          atomicAdd(&a.frow[z][gm], rp[fm][p] * (1.f / 1024.f));
        }
    }
  }
}

// ---------------------------------------------------------------------------
// batched transpose (4 weight matrices) + init slice (z==4)
// ---------------------------------------------------------------------------
struct T4 {
  const float* in[4]; unsigned short* out[4]; int R[4], C[4], nx[4], nt[4];
  float* dinv; float* f1; float* f2; unsigned* mx; unsigned* nanflag;
  float* cyc; float* ga; float* gb; float* al;
};
__global__ void k_transpose4(T4 d)
{
  const int z = blockIdx.y;
  const int tid = threadIdx.x;
  if (z == 4) {
    if (blockIdx.x == 0) {
      #pragma unroll
      for (int i = 0; i < 4; ++i) {
        int k = tid + 256 * i;
        d.dinv[k] = PS; d.f1[k] = 0.f; d.f2[k] = 0.f;
      }
      if (tid < 16) d.mx[tid] = 0u;
      if (tid == 0) {
        *d.nanflag = 0u; d.cyc[0] = 0.f; d.cyc[1] = 0.f;
        *d.ga = 0.f; *d.gb = 0.f; *d.al = 0.f;
      }
    }
    return;
  }
  __shared__ float t[64][65];
  const int tile = blockIdx.x;
  if (tile >= d.nt[z]) return;
  const int R = d.R[z], C = d.C[z];
  const int r0 = (tile % d.nx[z]) * 64, c0 = (tile / d.nx[z]) * 64;
  const float* in = d.in[z];
  unsigned short* out = d.out[z];
  #pragma unroll
  for (int i = 0; i < 16; ++i) {
    int idx = tid + 256 * i;
    int r = idx >> 6, c = idx & 63;
    float v = 0.f;
    if ((r0 + r) < R && (c0 + c) < C) v = in[(size_t)(r0 + r) * C + (c0 + c)];
    t[r][c] = v;
  }
  __syncthreads();
  #pragma unroll
  for (int i = 0; i < 16; ++i) {
    int idx = tid + 256 * i;
    int c = idx >> 6, r = idx & 63;
    if ((c0 + c) < C && (r0 + r) < R)
      out[(size_t)(c0 + c) * R + (r0 + r)] = (unsigned short)f2bf(t[r][c]);
  }
}

// Wcomb partial reduce + transpose
__global__ void k_wcomb_reduce(const float* partials, unsigned short* WcTa,
                               unsigned short* WcTb)
{
  __shared__ float t[64][65];
  const int z = blockIdx.z;
  const float* P = partials + (size_t)z * 32 * 256 * 256;
  unsigned short* WcT = z ? WcTb : WcTa;
  const int u0 = blockIdx.x * 64, v0 = blockIdx.y * 64;
  const int tid = threadIdx.x;
  #pragma unroll
  for (int i = 0; i < 16; ++i) {
    int idx = tid + 256 * i;
    int u = idx >> 6, v = idx & 63;
    float s = 0.f;
    for (int p = 0; p < 32; ++p)
      s += P[(size_t)p * 65536 + (u0 + u) * 256 + (v0 + v)];
    t[u][v] = s;
  }
  __syncthreads();
  #pragma unroll
  for (int i = 0; i < 16; ++i) {
    int idx = tid + 256 * i;
    int v = idx >> 6, u = idx & 63;
    WcT[(size_t)(v0 + v) * 256 + (u0 + u)] = (unsigned short)f2bf(t[u][v]);
  }
}

// bc[c] = b4 . Wt1[c,:] + b1[c]
struct BcArgs {
  const float* b4[2]; const unsigned short* Wt1[2]; const float* b1[2];
  float* bc[2]; int K[2];
};
__global__ void k_bcvec(BcArgs a)
{
  const int y = blockIdx.y;
  const int c = blockIdx.x * 4 + (threadIdx.x >> 6);
  const int lane = threadIdx.x & 63;
  const int K = a.K[y];
  const unsigned short* wrow = a.Wt1[y] + (size_t)c * K;
  const float* b4 = a.b4[y];
  float s = 0.f;
  for (int k = lane * 8; k < K; k += 512) {
    s16x8 w = *(const s16x8*)&wrow[k];
    f32x4 v0 = *(const f32x4*)&b4[k];
    f32x4 v1 = *(const f32x4*)&b4[k + 4];
    s += v0.x * bf2f((unsigned short)w[0]) + v0.y * bf2f((unsigned short)w[1])
       + v0.z * bf2f((unsigned short)w[2]) + v0.w * bf2f((unsigned short)w[3])
       + v1.x * bf2f((unsigned short)w[4]) + v1.y * bf2f((unsigned short)w[5])
       + v1.z * bf2f((unsigned short)w[6]) + v1.w * bf2f((unsigned short)w[7]);
  }
  #pragma unroll
  for (int o = 32; o; o >>= 1) s += __shfl_xor(s, o, 64);
  if (lane == 0) a.bc[y][c] = s + a.b1[y][c];
}

// ---------------------------------------------------------------------------
// fused: split-K reduce + relu + enc head + reparam + featprep + GMM KL
// grid (1024, 2), 256 threads
// ---------------------------------------------------------------------------
struct EF {
  const float* partials[2]; const float* bias[2];
  const float* W21[2]; const float* b21[2];
  const float* W22[2]; const float* b22[2]; const float* eps[2];
  const float* pmu[2]; const float* plv[2]; float* gmmO[2];
  float* mu[2]; float* lv[2]; float* zO[2];
  unsigned short* F[2]; float* n[2];
};
__global__ __launch_bounds__(256)
void k_enc_fused(EF a)
{
  __shared__ float hrow[256];
  __shared__ float res[128];
  const int y = blockIdx.y;
  const int i = blockIdx.x;
  const int t = threadIdx.x;
  {
    float s = a.bias[y][t];
    const float* P = a.partials[y] + (size_t)i * 256 + t;
    #pragma unroll
    for (int p = 0; p < 16; ++p) s += P[(size_t)p * 262144];
    hrow[t] = fmaxf(s, 0.f);
  }
  __syncthreads();
  if (t < 128) {
    const int c = t & 63;
    const float* W = (t < 64) ? a.W21[y] : a.W22[y];
    float acc = (t < 64) ? a.b21[y][c] : a.b22[y][c];
    #pragma unroll 8
    for (int j = 0; j < 256; ++j) acc += hrow[j] * W[j * 64 + c];
    res[t] = acc;
  }
  __syncthreads();
  if (t < 64) {
    float mu = res[t], lv = res[64 + t];
    a.mu[y][(size_t)i * 64 + t] = mu;
    a.lv[y][(size_t)i * 64 + t] = lv;
    float sig = expf(0.5f * lv);
    float zd = mu + a.eps[y][(size_t)i * 64 + t] * sig;
    a.zO[y][(size_t)i * 64 + t] = zd;
    unsigned short u0 = (unsigned short)f2bf(mu);
    unsigned short u1 = (unsigned short)f2bf(sig);
    unsigned short* Fr = a.F[y] + (size_t)i * 128;
    Fr[t] = u0;
    Fr[64 + t] = u1;
    float r0 = bf2f(u0), r1 = bf2f(u1);
    float p = r0 * r0 + r1 * r1;
    #pragma unroll
    for (int o = 32; o; o >>= 1) p += __shfl_xor(p, o, 64);
    if (t == 0) a.n[y][i] = p;
    // ---- GMM KL (fused; z/mu/lv in registers)
    float tq = lv + (zd - mu) * (zd - mu) * expf(-lv);
    #pragma unroll
    for (int o = 32; o; o >>= 1) tq += __shfl_xor(tq, o, 64);
    const float C0 = 64.f * 1.8378770664093453f;
    float logq = -0.5f * (C0 + tq);
    float lp[20];
    #pragma unroll
    for (int k = 0; k < 20; ++k) {
      float pm = a.pmu[y][k * 64 + t], pl = a.plv[y][k * 64 + t];
      float u = pl + (zd - pm) * (zd - pm) * expf(-pl);
      #pragma unroll
      for (int o = 32; o; o >>= 1) u += __shfl_xor(u, o, 64);
      lp[k] = -0.5f * (C0 + u);
    }
    float mxv = lp[0];
    #pragma unroll
    for (int k = 1; k < 20; ++k) mxv = fmaxf(mxv, lp[k]);
    float se = 0.f;
    #pragma unroll
    for (int k = 0; k < 20; ++k) se += expf(lp[k] - mxv);
    float logp = mxv + logf(se) - 2.9957322735539909f;
    if (t == 0) atomicAdd(a.gmmO[y], logq - logp);
  }
}

// fused re-encode + cycle-loss partial
struct RencArgs {
  const float* hd[2]; const unsigned short* WcT[2]; const float* bc[2];
  const float* W21[2]; const float* b21[2]; const float* W22[2]; const float* b22[2];
  const float* eps[2]; float* fout[2];
  const float* zin[2]; float* cyc;
};
__global__ void k_renc_head(RencArgs a)
{
  __shared__ float hdrow[256];
  __shared__ float hr[256];
  __shared__ float res[128];
  const int y = blockIdx.y;
  const int i = blockIdx.x;
  const int t = threadIdx.x;                  // 256
  hdrow[t] = a.hd[y][(size_t)i * 256 + t];
  __syncthreads();
  {
    const s16x8* wr = (const s16x8*)(a.WcT[y] + (size_t)t * 256);
    float s = a.bc[y][t];
    #pragma unroll 4
    for (int j = 0; j < 32; ++j) {
      s16x8 w = wr[j];
      const float* hp = &hdrow[j * 8];
      s += hp[0] * bf2f((unsigned short)w[0]) + hp[1] * bf2f((unsigned short)w[1])
         + hp[2] * bf2f((unsigned short)w[2]) + hp[3] * bf2f((unsigned short)w[3])
         + hp[4] * bf2f((unsigned short)w[4]) + hp[5] * bf2f((unsigned short)w[5])
         + hp[6] * bf2f((unsigned short)w[6]) + hp[7] * bf2f((unsigned short)w[7]);
    }
    hr[t] = fmaxf(s, 0.f);
  }
  __syncthreads();
  if (t < 128) {
    const int c = t & 63;
    const float* W = (t < 64) ? a.W21[y] : a.W22[y];
    float acc = (t < 64) ? a.b21[y][c] : a.b22[y][c];
    #pragma unroll 8
    for (int j = 0; j < 256; ++j) acc += hr[j] * W[j * 64 + c];
    res[t] = acc;
  }
  __syncthreads();
  if (t < 64) {
    float mu = res[t], lv = res[64 + t];
    float f = mu + a.eps[y][(size_t)i * 64 + t] * expf(0.5f * lv);
    a.fout[y][(size_t)i * 64 + t] = f;
    float d = a.zin[y][(size_t)i * 64 + t] - f;
    d = d * d;
    #pragma unroll
    for (int o = 32; o; o >>= 1) d += __shfl_xor(d, o, 64);
    if (t == 0) atomicAdd(a.cyc + y, d);
  }
}

// batched decoder heads
struct DH4 { const float* z[4]; const float* W3[4]; const float* b3[4]; float* hd[4]; };
__global__ void k_dec_head4(DH4 a)
{
  __shared__ float zrow[64];
  const int y = blockIdx.y;
  const int i = blockIdx.x;
  const int t = threadIdx.x;                  // 256
  if (t < 64) zrow[t] = a.z[y][(size_t)i * 64 + t];
  __syncthreads();
  const float* W3 = a.W3[y];
  float acc = a.b3[y][t];
  #pragma unroll
  for (int d = 0; d < 64; ++d) acc += zrow[d] * W3[d * 256 + t];
  a.hd[y][(size_t)i * 256 + t] = fmaxf(acc, 0.f);
}

__global__ void k_finish(const float* slots, float* o1, float* o2)
{
  if (threadIdx.x == 0) { *o1 = sqrtf(slots[0]); *o2 = sqrtf(slots[1]); }
}

// ---------------------------------------------------------------------------
extern "C" void kernel_launch(void* const* d_in, const int* in_sizes, int n_in,
                              void* d_out, int out_size, void* d_ws, size_t ws_size,
                              hipStream_t stream)
{
  (void)in_sizes; (void)n_in; (void)out_size; (void)ws_size;

  const float* X     = (const float*)d_in[2];
  const float* Y     = (const float*)d_in[3];
  const float* pmua  = (const float*)d_in[4];
  const float* plva  = (const float*)d_in[5];
  const float* pmub  = (const float*)d_in[6];
  const float* plvb  = (const float*)d_in[7];
  const float* epsx  = (const float*)d_in[8];
  const float* epsy  = (const float*)d_in[9];
  const float* epsxr = (const float*)d_in[10];
  const float* epsyr = (const float*)d_in[11];
  const float* W1a = (const float*)d_in[12];  const float* b1a = (const float*)d_in[13];
  const float* W21a= (const float*)d_in[14];  const float* b21a= (const float*)d_in[15];
  const float* W22a= (const float*)d_in[16];  const float* b22a= (const float*)d_in[17];
  const float* W3a = (const float*)d_in[18];  const float* b3a = (const float*)d_in[19];
  const float* W4a = (const float*)d_in[20];  const float* b4a = (const float*)d_in[21];
  const float* W1b = (const float*)d_in[22];  const float* b1b = (const float*)d_in[23];
  const float* W21b= (const float*)d_in[24];  const float* b21b= (const float*)d_in[25];
  const float* W22b= (const float*)d_in[26];  const float* b22b= (const float*)d_in[27];
  const float* W3b = (const float*)d_in[28];  const float* b3b = (const float*)d_in[29];
  const float* W4b = (const float*)d_in[30];  const float* b4b = (const float*)d_in[31];

  float* out = (float*)d_out;
  const size_t P_X = 0, P_Y = 20480000, P_X2Y = 46080000, P_Y2X = 71680000;
  const size_t Z_X = 92160000, Z_Y = 92225536;
  const size_t GMM_A = 92291072, GMM_B = 92291073;
  const size_t F_XR = 92291074, F_YR = 92356610;
  const size_t ALIGN = 92422146, CYC_X = 92422147, CYC_Y = 92422148;

  // ---- workspace carve
  char* w = (char*)d_ws;
  size_t off = 0;
  auto alloc = [&](size_t bytes) -> void* {
    void* p = w + off;
    off += (bytes + 255) & ~(size_t)255;
    return p;
  };
  unsigned short* Wt1a = (unsigned short*)alloc((size_t)256 * 20000 * 2);
  unsigned short* Wt1b = (unsigned short*)alloc((size_t)256 * 25000 * 2);
  unsigned short* W4ta = (unsigned short*)alloc((size_t)20000 * 256 * 2);
  unsigned short* W4tb = (unsigned short*)alloc((size_t)25000 * 256 * 2);
  unsigned short* WcTa = (unsigned short*)alloc((size_t)256 * 256 * 2);
  unsigned short* WcTb = (unsigned short*)alloc((size_t)256 * 256 * 2);
  float* bca  = (float*)alloc(256 * 4);
  float* bcb  = (float*)alloc(256 * 4);
  float* mu_a = (float*)alloc(1024 * 64 * 4);
  float* lv_a = (float*)alloc(1024 * 64 * 4);
  float* mu_b = (float*)alloc(1024 * 64 * 4);
  float* lv_b = (float*)alloc(1024 * 64 * 4);
  float* f1   = (float*)alloc(1024 * 4);
  float* f2   = (float*)alloc(1024 * 4);
  unsigned* mx      = (unsigned*)alloc(16 * 4);
  unsigned* nanflag = (unsigned*)alloc(256);
  float* cyc  = (float*)alloc(256);
  float* draw = (float*)alloc(1024 * 4);
  float* braw = (float*)alloc(1024 * 4);
  float* braw2 = (float*)alloc(1024 * 4);
  float* dinv = (float*)alloc(1024 * 4);
  unsigned short* Fb = (unsigned short*)alloc((size_t)1024 * 128 * 2);
  unsigned short* Fa = (unsigned short*)alloc((size_t)1024 * 128 * 2);
  float* nb = (float*)alloc(1024 * 4);
  float* na = (float*)alloc(1024 * 4);
  char* arena = (char*)alloc((size_t)32 * 1024 * 1024);
  float* partials = (float*)arena;
  size_t ao = 0;
  auto aalloc = [&](size_t bytes) -> void* {
    void* p = arena + ao;
    ao += (bytes + 255) & ~(size_t)255;
    return p;
  };
  unsigned short* cpostB  = (unsigned short*)aalloc((size_t)1024 * 1024 * 2);
  unsigned short* cpriorB = (unsigned short*)aalloc((size_t)1024 * 1024 * 2);
  float* cpp  = (float*)aalloc((size_t)1024 * 1024 * 4);
  unsigned short* Umat  = (unsigned short*)aalloc((size_t)1024 * 1024 * 2);
  float* cost  = (float*)aalloc((size_t)1024 * 1024 * 4);
  float* Kmat  = (float*)aalloc((size_t)1024 * 1024 * 4);
  float* KTmat = (float*)aalloc((size_t)1024 * 1024 * 4);
  float* hd0 = (float*)(arena);
  float* hd1 = (float*)(arena + (size_t)1024 * 256 * 4);
  float* hd2 = (float*)(arena + (size_t)2 * 1024 * 256 * 4);
  float* hd3 = (float*)(arena + (size_t)3 * 1024 * 256 * 4);

  // ---- 1. weight transposes + init (z=4)
  {
    T4 d{};
    d.in[0] = W1a; d.out[0] = Wt1a; d.R[0] = 20000; d.C[0] = 256;
    d.in[1] = W1b; d.out[1] = Wt1b; d.R[1] = 25000; d.C[1] = 256;
    d.in[2] = W4a; d.out[2] = W4ta; d.R[2] = 256;   d.C[2] = 20000;
    d.in[3] = W4b; d.out[3] = W4tb; d.R[3] = 256;   d.C[3] = 25000;
    for (int z = 0; z < 4; ++z) {
      d.nx[z] = (d.R[z] + 63) / 64;
      d.nt[z] = d.nx[z] * ((d.C[z] + 63) / 64);
    }
    d.dinv = dinv; d.f1 = f1; d.f2 = f2; d.mx = mx; d.nanflag = nanflag;
    d.cyc = cyc; d.ga = out + GMM_A; d.gb = out + GMM_B; d.al = out + ALIGN;
    k_transpose4<<<dim3(1564, 5), 256, 0, stream>>>(d);
  }

  // ---- 2. Wcomb = W4 @ W1 -> WcT bf16 + combined bias
  {
    Q4 q{};
    q.g[0].Af = W4a; q.g[0].Bt = Wt1a; q.g[0].partials = partials;
    q.g[0].M = 256; q.g[0].N = 256; q.g[0].K = 20000;
    q.g[0].lda = 20000; q.g[0].ldbt = 20000;
    q.g[0].totSteps = 313; q.g[0].nSplits = 32;
    q.g[1] = q.g[0];
    q.g[1].Af = W4b; q.g[1].Bt = Wt1b;
    q.g[1].partials = partials + (size_t)32 * 65536;
    q.g[1].K = 25000; q.g[1].lda = 25000; q.g[1].ldbt = 25000; q.g[1].totSteps = 391;
    k_gemmN<128, 256, 4, 4, EPI_PARTIAL><<<dim3(2, 32, 2), 1024, 0, stream>>>(q);
    k_wcomb_reduce<<<dim3(4, 4, 2), 256, 0, stream>>>(partials, WcTa, WcTb);
    BcArgs bc{};
    bc.b4[0] = b4a; bc.Wt1[0] = Wt1a; bc.b1[0] = b1a; bc.bc[0] = bca; bc.K[0] = 20000;
    bc.b4[1] = b4b; bc.Wt1[1] = Wt1b; bc.b1[1] = b1b; bc.bc[1] = bcb; bc.K[1] = 25000;
    k_bcvec<<<dim3(64, 2), 256, 0, stream>>>(bc);
  }

  // ---- 3. encoders (batched GEMM + fused reduce/head/featprep/GMM)
  {
    Q4 q{};
    q.g[0].Af = X; q.g[0].Bt = Wt1a; q.g[0].partials = partials;
    q.g[0].M = 1024; q.g[0].N = 256; q.g[0].K = 20000;
    q.g[0].lda = 20000; q.g[0].ldbt = 20000;
    q.g[0].totSteps = 313; q.g[0].nSplits = 16;
    q.g[1] = q.g[0];
    q.g[1].Af = Y; q.g[1].Bt = Wt1b;
    q.g[1].partials = partials + (size_t)16 * 1024 * 256;
    q.g[1].K = 25000; q.g[1].lda = 25000; q.g[1].ldbt = 25000; q.g[1].totSteps = 391;
    k_gemmN<128, 256, 4, 4, EPI_PARTIAL><<<dim3(8, 16, 2), 1024, 0, stream>>>(q);
    EF e{};
    e.partials[0] = partials; e.partials[1] = partials + (size_t)16 * 1024 * 256;
    e.bias[0] = b1a; e.bias[1] = b1b;
    e.W21[0] = W21a; e.b21[0] = b21a; e.W22[0] = W22a; e.b22[0] = b22a;
    e.eps[0] = epsx; e.mu[0] = mu_a; e.lv[0] = lv_a; e.zO[0] = out + Z_X;
    e.F[0] = Fa; e.n[0] = na;
    e.pmu[0] = pmua; e.plv[0] = plva; e.gmmO[0] = out + GMM_A;
    e.W21[1] = W21b; e.b21[1] = b21b; e.W22[1] = W22b; e.b22[1] = b22b;
    e.eps[1] = epsy; e.mu[1] = mu_b; e.lv[1] = lv_b; e.zO[1] = out + Z_Y;
    e.F[1] = Fb; e.n[1] = nb;
    e.pmu[1] = pmub; e.plv[1] = plvb; e.gmmO[1] = out + GMM_B;
    k_enc_fused<<<dim3(1024, 2), 256, 0, stream>>>(e);
  }

  // ---- 4. FGW(mu_b, mu_a, lv_b, lv_a)
  {
    DistMMArgs dm{};
    dm.Fx[0] = Fb; dm.Fy[0] = Fb; dm.nx[0] = nb; dm.ny[0] = nb;
    dm.Fx[1] = Fa; dm.Fy[1] = Fa; dm.nx[1] = na; dm.ny[1] = na;
    dm.Fx[2] = Fb; dm.Fy[2] = Fa; dm.nx[2] = nb; dm.ny[2] = na;
    dm.outB[0] = cpostB; dm.outB[1] = cpriorB; dm.outF = cpp;
    dm.frow[0] = f1; dm.frow[1] = f2;
    k_distmm<<<dim3(256, 3), 256, 0, stream>>>(dm);
  }
  G1Args g1{};
  g1.A = cpostB; g1.KT = KTmat; g1.dinv = dinv; g1.braw = braw;
  g1.U = Umat; g1.nflag = nanflag;
  FgwGemmArgs fg{};
  fg.A = Umat; fg.Bt = cpriorB;
  fg.f1 = f1; fg.f2 = f2; fg.cpp = cpp; fg.cost = cost;
  fg.loss = out + ALIGN; fg.braw2 = braw2;
  fg.Kf = Kmat; fg.dinv = dinv; fg.brawv = braw; fg.nflag = nanflag;
  for (int it = 0; it < 10; ++it) {
    g1.mode = (it == 0) ? 0 : 1;
    k_fgw_g1<<<64, 512, 0, stream>>>(g1);
    fg.mx = mx + it;
    k_fgw_gemm<EPI_COST><<<64, 512, 0, stream>>>(fg);
    k_kbuild<<<dim3(16, 16), 256, 0, stream>>>(cost, mx + it, Kmat, KTmat,
                                               dinv, braw, braw2, it == 0 ? 1 : 0);
    for (int r = 0; r < 5; ++r) {
      k_matvec<<<256, 256, 0, stream>>>(Kmat, r == 0 ? braw2 : braw, draw, nullptr);
      k_matvec<<<256, 256, 0, stream>>>(KTmat, draw, braw, r == 4 ? dinv : nullptr);
    }
  }
  k_nanscan<<<256, 256, 0, stream>>>(Kmat, dinv, braw, nanflag);
  g1.mode = 2;
  k_fgw_g1<<<64, 512, 0, stream>>>(g1);
  k_fgw_gemm<EPI_LOSS><<<64, 512, 0, stream>>>(fg);

  // ---- 5. decoder heads
  {
    DH4 d{};
    d.z[0] = out + Z_X; d.W3[0] = W3a; d.b3[0] = b3a; d.hd[0] = hd0;   // P_X
    d.z[1] = out + Z_Y; d.W3[1] = W3a; d.b3[1] = b3a; d.hd[1] = hd1;   // P_Y2X
    d.z[2] = out + Z_Y; d.W3[2] = W3b; d.b3[2] = b3b; d.hd[2] = hd2;   // P_Y
    d.z[3] = out + Z_X; d.W3[3] = W3b; d.b3[3] = b3b; d.hd[3] = hd3;   // P_X2Y
    k_dec_head4<<<dim3(1024, 4), 256, 0, stream>>>(d);
  }

  // ---- 6. fused re-encoders (+cycle partials)
  {
    RencArgs r{};
    r.hd[0] = hd3; r.WcT[0] = WcTb; r.bc[0] = bcb;                     // enc_b(dec_b(z_x))
    r.W21[0] = W21b; r.b21[0] = b21b; r.W22[0] = W22b; r.b22[0] = b22b;
    r.eps[0] = epsxr; r.fout[0] = out + F_XR; r.zin[0] = out + Z_X;
    r.hd[1] = hd1; r.WcT[1] = WcTa; r.bc[1] = bca;                     // enc_a(dec_a(z_y))
    r.W21[1] = W21a; r.b21[1] = b21a; r.W22[1] = W22a; r.b22[1] = b22a;
    r.eps[1] = epsyr; r.fout[1] = out + F_YR; r.zin[1] = out + Z_Y;
    r.cyc = cyc;
    k_renc_head<<<dim3(1024, 2), 256, 0, stream>>>(r);
  }
  k_finish<<<1, 64, 0, stream>>>(cyc, out + CYC_X, out + CYC_Y);

  // ---- 7. decoder GEMMs (one launch, z=0..3)
  {
    Q4 q{};
    q.g[0].Af = hd0; q.g[0].Bt = W4ta; q.g[0].outF = out + P_X; q.g[0].bias = b4a;
    q.g[0].M = 1024; q.g[0].N = 20000; q.g[0].K = 256;
    q.g[0].lda = 256; q.g[0].ldbt = 256; q.g[0].ldc = 20000;
    q.g[1] = q.g[0]; q.g[1].Af = hd1; q.g[1].outF = out + P_Y2X;
    q.g[2] = q.g[0];
    q.g[2].Af = hd2; q.g[2].Bt = W4tb; q.g[2].outF = out + P_Y; q.g[2].bias = b4b;
    q.g[2].N = 25000; q.g[2].ldc = 25000;
    q.g[3] = q.g[2]; q.g[3].Af = hd3; q.g[3].outF = out + P_X2Y;
    k_gemmN<128, 256, 4, 4, EPI_BIAS><<<dim3(8, 98, 4), 1024, 0, stream>>>(q);
  }
}

// Round 9
// 1548.747 us; speedup vs baseline: 1.1247x; 1.1247x over previous
//
#include <hip/hip_runtime.h>

// ============================================================================
// MUCRP_17265768530653 — cross-domain VAE forward on MI355X (gfx950)
// Round 10: R8 minus the grid-starvation blunder.
//  - FGW 1024^3 GEMMs reverted to 64x64/4-wave/256-block (1 block/CU; R8's
//    128^2 tile gave grid=64 on 256 CUs -> +155us)
//  - decoder GEMM re-shaped <128,128,4,2> 512thr 36KB LDS -> 4 blk/CU, 100%
//    occupancy (was 1024thr/54KB/2 blk/CU, 209us @ 34% HBM)
//  - keeps R8 fusions: GMM in enc_fused, cyc in renc_head, init in transpose4
// ============================================================================

#define DEVI __device__ __forceinline__

typedef __attribute__((ext_vector_type(4))) float  f32x4;
typedef __attribute__((ext_vector_type(4))) short  s16x4;
typedef __attribute__((ext_vector_type(8))) short  s16x8;
typedef __attribute__((ext_vector_type(8))) __bf16 bf16x8;

#define PS (1.f / 1024.f)
#define UNIF (1.f / (1024.f * 1024.f))

DEVI short f2bf(float f) {              // RNE f32 -> bf16 (bits)
  unsigned u = __float_as_uint(f);
  u += 0x7fffu + ((u >> 16) & 1u);
  return (short)(u >> 16);
}
DEVI float bf2f(unsigned short u) { return __uint_as_float(((unsigned)u) << 16); }

DEVI f32x4 mfma16(bf16x8 a, bf16x8 b, f32x4 c) {
  return __builtin_amdgcn_mfma_f32_16x16x32_bf16(a, b, c, 0, 0, 0);
}

// ---------------------------------------------------------------------------
// Generic tiled MFMA GEMM body (verified R1/R3/R4/R5/R7).
// ---------------------------------------------------------------------------
struct GemmArgs {
  const float* Af;
  const unsigned short* Bt;
  float* outF;
  const float* bias;
  float* partials;
  int M, N, K;
  int lda, ldbt, ldc;
  int totSteps, nSplits;
};

enum { EPI_PARTIAL, EPI_BIAS, EPI_COST, EPI_LOSS };

template<int BM, int BN, int WR, int WC, int EPI>
DEVI void gemm_body(const GemmArgs g)
{
  constexpr int BK = 64, BKP = 72;
  constexpr int NT = WR * WC * 64;
  __shared__ short As[BM * BKP];
  __shared__ short Bs[BN * BKP];

  const int m0 = blockIdx.x * BM;
  int n0 = 0, kb0 = 0, kb1 = g.K, split = 0;
  if constexpr (EPI == EPI_PARTIAL) {
    split = blockIdx.y;
    int s0 = (split * g.totSteps) / g.nSplits;
    int s1 = ((split + 1) * g.totSteps) / g.nSplits;
    kb0 = s0 * BK;
    kb1 = s1 * BK; if (kb1 > g.K) kb1 = g.K;
  } else {
    n0 = blockIdx.y * BN;
  }
  const int tid  = threadIdx.x;
  const int lane = tid & 63;
  const int wv   = tid >> 6;
  const int wr   = wv % WR;
  const int wc   = wv / WR;

  f32x4 acc[2][4];
  #pragma unroll
  for (int i = 0; i < 2; ++i)
    #pragma unroll
    for (int j = 0; j < 4; ++j) acc[i][j] = f32x4{0.f, 0.f, 0.f, 0.f};

  for (int kb = kb0; kb < kb1; kb += BK) {
    {   // stage A (f32 -> bf16)
      constexpr int NV = BM * BK / 4;
      #pragma unroll
      for (int i = 0; i < NV / NT; ++i) {
        int idx = tid + NT * i;
        int r = idx >> 4, q = idx & 15;
        int k = kb + 4 * q;
        f32x4 v = f32x4{0.f, 0.f, 0.f, 0.f};
        if (k < kb1) v = *(const f32x4*)(g.Af + (size_t)(m0 + r) * g.lda + k);
        s16x4 s;
        s.x = f2bf(v.x); s.y = f2bf(v.y); s.z = f2bf(v.z); s.w = f2bf(v.w);
        *(s16x4*)&As[r * BKP + 4 * q] = s;
      }
    }
    {   // stage B (bf16 [N][K])
      constexpr int NV = BN * BK / 8;
      #pragma unroll
      for (int i = 0; i < NV / NT; ++i) {
        int idx = tid + NT * i;
        int r = idx >> 3, q = idx & 7;
        int k = kb + 8 * q;
        s16x8 v{};
        if ((n0 + r) < g.N && k < kb1)
          v = *(const s16x8*)(g.Bt + (size_t)(n0 + r) * g.ldbt + k);
        *(s16x8*)&Bs[r * BKP + 8 * q] = v;
      }
    }
    __syncthreads();
    #pragma unroll
    for (int s = 0; s < 2; ++s) {
      const int ko = 32 * s + 8 * (lane >> 4);
      bf16x8 a0 = *(const bf16x8*)&As[(wr * 32 +      (lane & 15)) * BKP + ko];
      bf16x8 a1 = *(const bf16x8*)&As[(wr * 32 + 16 + (lane & 15)) * BKP + ko];
      #pragma unroll
      for (int fn = 0; fn < 4; ++fn) {
        bf16x8 b = *(const bf16x8*)&Bs[(wc * 64 + fn * 16 + (lane & 15)) * BKP + ko];
        acc[0][fn] = mfma16(a0, b, acc[0][fn]);
        acc[1][fn] = mfma16(a1, b, acc[1][fn]);
      }
    }
    __syncthreads();
  }

  #pragma unroll
  for (int fm = 0; fm < 2; ++fm) {
    #pragma unroll
    for (int fn = 0; fn < 4; ++fn) {
      #pragma unroll
      for (int p = 0; p < 4; ++p) {
        int gm = m0 + wr * 32 + fm * 16 + (lane >> 4) * 4 + p;
        int gn = n0 + wc * 64 + fn * 16 + (lane & 15);
        float v = acc[fm][fn][p];
        if constexpr (EPI == EPI_PARTIAL) {
          g.partials[((size_t)split * g.M + gm) * 256 + gn] = v;
        } else {
          if (gn < g.N) g.outF[(size_t)gm * g.ldc + gn] = v + g.bias[gn];
        }
      }
    }
  }
}

struct Q4 { GemmArgs g[4]; };

template<int BM, int BN, int WR, int WC, int EPI>
__global__ __launch_bounds__(WR*WC*64)
void k_gemmN(Q4 q)
{
  GemmArgs g = q.g[blockIdx.z];
  if constexpr (EPI == EPI_BIAS) {
    if ((int)(blockIdx.y * BN) >= g.N) return;
  }
  gemm_body<BM, BN, WR, WC, EPI>(g);
}

// ---------------------------------------------------------------------------
// FGW GEMM1': U[m][n] = bscale * sum_k bf16(cpost[m][k]*dinv[k]) * bf16(KT[n][k])
// 64x64 tile, 4 waves, 256 blocks (R7-proven shape: 1 block/CU).
// ---------------------------------------------------------------------------
struct G1Args {
  const unsigned short* A;
  const float* KT;
  const float* dinv;
  const float* braw;
  unsigned short* U;
  const unsigned* nflag;
  int mode;   // 0: uniform  1: factors  2: factors unless nanflag
};

__global__ __launch_bounds__(256)
void k_fgw_g1(G1Args a)
{
  __shared__ short As[64 * 72];
  __shared__ short Bs[64 * 72];
  const bool uni = (a.mode == 0) || (a.mode == 2 && *a.nflag != 0u);

  const int bid = blockIdx.x, tid = threadIdx.x;
  const int lane = tid & 63, wv = tid >> 6;
  const int wr = wv & 1, wc = wv >> 1;
  const int m0 = (bid >> 4) * 64, n0 = (bid & 15) * 64;

  f32x4 acc[2][2];
  #pragma unroll
  for (int i = 0; i < 2; ++i)
    #pragma unroll
    for (int j = 0; j < 2; ++j) acc[i][j] = f32x4{0.f, 0.f, 0.f, 0.f};

  const short ub = f2bf(UNIF);

  for (int kb = 0; kb < 1024; kb += 64) {
    #pragma unroll
    for (int i = 0; i < 2; ++i) {
      int idx = tid + 256 * i;
      int r = idx >> 3, q = idx & 7;
      s16x8 av = *(const s16x8*)&a.A[(size_t)(m0 + r) * 1024 + kb + 8 * q];
      if (!uni) {
        f32x4 d0 = *(const f32x4*)&a.dinv[kb + 8 * q];
        f32x4 d1 = *(const f32x4*)&a.dinv[kb + 8 * q + 4];
        s16x8 o;
        o[0] = f2bf(bf2f((unsigned short)av[0]) * d0.x);
        o[1] = f2bf(bf2f((unsigned short)av[1]) * d0.y);
        o[2] = f2bf(bf2f((unsigned short)av[2]) * d0.z);
        o[3] = f2bf(bf2f((unsigned short)av[3]) * d0.w);
        o[4] = f2bf(bf2f((unsigned short)av[4]) * d1.x);
        o[5] = f2bf(bf2f((unsigned short)av[5]) * d1.y);
        o[6] = f2bf(bf2f((unsigned short)av[6]) * d1.z);
        o[7] = f2bf(bf2f((unsigned short)av[7]) * d1.w);
        av = o;
      }
      *(s16x8*)&As[r * 72 + 8 * q] = av;
      s16x8 bv;
      if (uni) {
        #pragma unroll
        for (int j = 0; j < 8; ++j) bv[j] = ub;
      } else {
        f32x4 k0 = *(const f32x4*)&a.KT[(size_t)(n0 + r) * 1024 + kb + 8 * q];
        f32x4 k1 = *(const f32x4*)&a.KT[(size_t)(n0 + r) * 1024 + kb + 8 * q + 4];
        bv[0] = f2bf(k0.x); bv[1] = f2bf(k0.y); bv[2] = f2bf(k0.z); bv[3] = f2bf(k0.w);
        bv[4] = f2bf(k1.x); bv[5] = f2bf(k1.y); bv[6] = f2bf(k1.z); bv[7] = f2bf(k1.w);
      }
      *(s16x8*)&Bs[r * 72 + 8 * q] = bv;
    }
    __syncthreads();
    #pragma unroll
    for (int s = 0; s < 2; ++s) {
      const int ko = 32 * s + 8 * (lane >> 4);
      bf16x8 a0 = *(const bf16x8*)&As[(wr * 32 +      (lane & 15)) * 72 + ko];
      bf16x8 a1 = *(const bf16x8*)&As[(wr * 32 + 16 + (lane & 15)) * 72 + ko];
      bf16x8 b0 = *(const bf16x8*)&Bs[(wc * 32 +      (lane & 15)) * 72 + ko];
      bf16x8 b1 = *(const bf16x8*)&Bs[(wc * 32 + 16 + (lane & 15)) * 72 + ko];
      acc[0][0] = mfma16(a0, b0, acc[0][0]);
      acc[1][0] = mfma16(a1, b0, acc[1][0]);
      acc[0][1] = mfma16(a0, b1, acc[0][1]);
      acc[1][1] = mfma16(a1, b1, acc[1][1]);
    }
    __syncthreads();
  }

  #pragma unroll
  for (int fm = 0; fm < 2; ++fm) {
    #pragma unroll
    for (int fn = 0; fn < 2; ++fn) {
      int gn = n0 + wc * 32 + fn * 16 + (lane & 15);
      float bs = uni ? 1.f : (PS / a.braw[gn]);
      #pragma unroll
      for (int p = 0; p < 4; ++p) {
        int gm = m0 + wr * 32 + fm * 16 + (lane >> 4) * 4 + p;
        float v = acc[fm][fn][p];
        a.U[(size_t)gm * 1024 + gn] = (unsigned short)f2bf(uni ? v : bs * v);
      }
    }
  }
}

// ---------------------------------------------------------------------------
// FGW GEMM (COST / LOSS), 64x64 tile, 4 waves, 256 blocks (R7-proven).
// ---------------------------------------------------------------------------
struct FgwGemmArgs {
  const unsigned short* A;
  const unsigned short* Bt;
  float* cost;
  const float* f1;
  const float* f2;
  const float* cpp;
  unsigned* mx;
  float* loss;
  float* braw2;
  const float* Kf;
  const float* dinv;
  const float* brawv;
  const unsigned* nflag;
};

template<int EPI>
__global__ __launch_bounds__(256)
void k_fgw_gemm(FgwGemmArgs a)
{
  __shared__ short As[64 * 72];
  __shared__ short Bs[64 * 72];
  __shared__ float red[4];

  const int bid = blockIdx.x, tid = threadIdx.x;
  const int lane = tid & 63, wv = tid >> 6;
  const int wr = wv & 1, wc = wv >> 1;
  const int m0 = (bid >> 4) * 64, n0 = (bid & 15) * 64;

  if constexpr (EPI == EPI_COST) {
    if (bid == 0) {
      #pragma unroll
      for (int i = 0; i < 4; ++i) a.braw2[tid + 256 * i] = 0.f;
    }
  }

  f32x4 acc[2][2];
  #pragma unroll
  for (int i = 0; i < 2; ++i)
    #pragma unroll
    for (int j = 0; j < 2; ++j) acc[i][j] = f32x4{0.f, 0.f, 0.f, 0.f};

  for (int kb = 0; kb < 1024; kb += 64) {
    #pragma unroll
    for (int i = 0; i < 2; ++i) {
      int idx = tid + 256 * i;
      int r = idx >> 3, q = idx & 7;
      *(s16x8*)&As[r * 72 + 8 * q] = *(const s16x8*)&a.A [(size_t)(m0 + r) * 1024 + kb + 8 * q];
      *(s16x8*)&Bs[r * 72 + 8 * q] = *(const s16x8*)&a.Bt[(size_t)(n0 + r) * 1024 + kb + 8 * q];
    }
    __syncthreads();
    #pragma unroll
    for (int s = 0; s < 2; ++s) {
      const int ko = 32 * s + 8 * (lane >> 4);
      bf16x8 a0 = *(const bf16x8*)&As[(wr * 32 +      (lane & 15)) * 72 + ko];
      bf16x8 a1 = *(const bf16x8*)&As[(wr * 32 + 16 + (lane & 15)) * 72 + ko];
      bf16x8 b0 = *(const bf16x8*)&Bs[(wc * 32 +      (lane & 15)) * 72 + ko];
      bf16x8 b1 = *(const bf16x8*)&Bs[(wc * 32 + 16 + (lane & 15)) * 72 + ko];
      acc[0][0] = mfma16(a0, b0, acc[0][0]);
      acc[1][0] = mfma16(a1, b0, acc[1][0]);
      acc[0][1] = mfma16(a0, b1, acc[0][1]);
      acc[1][1] = mfma16(a1, b1, acc[1][1]);
    }
    __syncthreads();
  }

  bool uni = false;
  if constexpr (EPI == EPI_LOSS) uni = (*a.nflag != 0u);

  float lred = 0.f;
  #pragma unroll
  for (int fm = 0; fm < 2; ++fm) {
    #pragma unroll
    for (int fn = 0; fn < 2; ++fn) {
      int gn = n0 + wc * 32 + fn * 16 + (lane & 15);
      float bs = 0.f;
      if constexpr (EPI == EPI_LOSS) bs = uni ? 0.f : (PS / a.brawv[gn]);
      #pragma unroll
      for (int p = 0; p < 4; ++p) {
        int gm = m0 + wr * 32 + fm * 16 + (lane >> 4) * 4 + p;
        float v = acc[fm][fn][p];
        size_t o = (size_t)gm * 1024 + gn;
        float c = 0.1f * (a.f1[gm] + a.f2[gn] - 2.f * v) + 0.9f * a.cpp[o];
        if constexpr (EPI == EPI_COST) {
          a.cost[o] = c;
          lred = fmaxf(lred, fabsf(c));
        } else {
          float trec = uni ? UNIF : (a.dinv[gm] * bs) * a.Kf[o];
          lred += c * trec;
        }
      }
    }
  }
  #pragma unroll
  for (int off = 32; off; off >>= 1) {
    float t = __shfl_xor(lred, off, 64);
    lred = (EPI == EPI_COST) ? fmaxf(lred, t) : (lred + t);
  }
  if (lane == 0) red[wv] = lred;
  __syncthreads();
  if (tid == 0) {
    if constexpr (EPI == EPI_COST) {
      float t = fmaxf(fmaxf(red[0], red[1]), fmaxf(red[2], red[3]));
      atomicMax(a.mx, __float_as_uint(t));
    } else {
      atomicAdd(a.loss, red[0] + red[1] + red[2] + red[3]);
    }
  }
}

// ---------------------------------------------------------------------------
// kbuild: tran reconstructed from (K_old, dinv, braw_old) bit-identically,
// K_new = exp(-cost/mx)*tran (in place), KT, braw2 seed.  Grid (16,16)x256.
// ---------------------------------------------------------------------------
__global__ __launch_bounds__(256)
void k_kbuild(const float* cost, const unsigned* mxbits, float* K, float* KT,
              const float* dinv, const float* brawOld, float* braw2, int uniform)
{
  __shared__ float tt[64 * 65];
  __shared__ float dS[64];
  __shared__ float bS[64];
  __shared__ float csum[4][64];
  const int r0 = blockIdx.x * 64, c0 = blockIdx.y * 64;
  const int tid = threadIdx.x;
  const float inv = 1.f / __uint_as_float(*mxbits);
  if (tid < 64) dS[tid] = dinv[r0 + tid];
  else if (tid >= 64 && tid < 128 && !uniform) bS[tid - 64] = PS / brawOld[c0 + tid - 64];
  __syncthreads();
  float colp = 0.f;
  #pragma unroll
  for (int i = 0; i < 16; ++i) {
    int idx = tid + 256 * i;
    int r = idx >> 6, c = idx & 63;
    size_t o = (size_t)(r0 + r) * 1024 + (c0 + c);
    float trec = uniform ? UNIF : (dS[r] * bS[c]) * K[o];
    float v = expf(-cost[o] * inv) * trec;
    K[o] = v;
    tt[r * 65 + c] = v;
    colp += v * dS[r];
  }
  csum[tid >> 6][tid & 63] = colp;
  __syncthreads();
  #pragma unroll
  for (int i = 0; i < 16; ++i) {
    int idx = tid + 256 * i;
    int c = idx >> 6, r = idx & 63;
    KT[(size_t)(c0 + c) * 1024 + (r0 + r)] = tt[r * 65 + c];
  }
  if (tid < 64)
    atomicAdd(&braw2[c0 + tid],
              csum[0][tid] + csum[1][tid] + csum[2][tid] + csum[3][tid]);
}

// y_raw[r] = M[r,:].(PS/x_raw); optionally emits invOut = PS/x (last matvec).
__global__ __launch_bounds__(256)
void k_matvec(const float* M, const float* xraw, float* yraw, float* invOut)
{
  const int r = blockIdx.x * 4 + (threadIdx.x >> 6);
  const int lane = threadIdx.x & 63;
  const int wv = threadIdx.x >> 6;
  const f32x4* row = (const f32x4*)(M + (size_t)r * 1024);
  const f32x4* xv  = (const f32x4*)xraw;
  float s = 0.f;
  #pragma unroll
  for (int q = 0; q < 4; ++q) {
    f32x4 a = row[lane + 64 * q];
    f32x4 x = xv [lane + 64 * q];
    f32x4 iv;
    iv.x = PS / x.x; iv.y = PS / x.y; iv.z = PS / x.z; iv.w = PS / x.w;
    if (invOut && blockIdx.x == 0 && wv == 0)
      *(f32x4*)&invOut[4 * (lane + 64 * q)] = iv;
    s += a.x * iv.x + a.y * iv.y + a.z * iv.z + a.w * iv.w;
  }
  #pragma unroll
  for (int o = 32; o; o >>= 1) s += __shfl_xor(s, o, 64);
  if (lane == 0) yraw[r] = s;
}

// NaN scan over reconstructed tran.
__global__ __launch_bounds__(256)
void k_nanscan(const float* K, const float* dinv, const float* braw, unsigned* flag)
{
  unsigned bad = 0;
  const int base = blockIdx.x * 256 + threadIdx.x;
  #pragma unroll
  for (int i = 0; i < 16; ++i) {
    int idx = base + 65536 * i;
    int r = idx >> 10, c = idx & 1023;
    float v = (dinv[r] * (PS / braw[c])) * K[idx];
    if (v != v) bad = 1u;
  }
  if (bad) atomicOr(flag, 1u);
}

// ---------------------------------------------------------------------------
// Distance via MFMA expanded form (verified R5).
// ---------------------------------------------------------------------------
struct DistMMArgs {
  const unsigned short* Fx[3]; const unsigned short* Fy[3];
  const float* nx[3]; const float* ny[3];
  unsigned short* outB[2]; float* outF; float* frow[2];
};
__global__ __launch_bounds__(256)
void k_distmm(DistMMArgs a)
{
  __shared__ short As[64 * 72];
  __shared__ short Bs[64 * 72];
  const int z = blockIdx.y;
  const int bid = blockIdx.x, tid = threadIdx.x;
  const int lane = tid & 63, wv = tid >> 6;
  const int wr = wv & 1, wc = wv >> 1;
  const int m0 = (bid >> 4) * 64, n0 = (bid & 15) * 64;
  const unsigned short* X = a.Fx[z];
  const unsigned short* Y = a.Fy[z];

  f32x4 acc[2][2];
  #pragma unroll
  for (int i = 0; i < 2; ++i)
    #pragma unroll
    for (int j = 0; j < 2; ++j) acc[i][j] = f32x4{0.f, 0.f, 0.f, 0.f};

  #pragma unroll
  for (int kb = 0; kb < 128; kb += 64) {
    #pragma unroll
    for (int i = 0; i < 2; ++i) {
      int idx = tid + 256 * i;
      int r = idx >> 3, q = idx & 7;
      *(s16x8*)&As[r * 72 + 8 * q] = *(const s16x8*)&X[(size_t)(m0 + r) * 128 + kb + 8 * q];
      *(s16x8*)&Bs[r * 72 + 8 * q] = *(const s16x8*)&Y[(size_t)(n0 + r) * 128 + kb + 8 * q];
    }
    __syncthreads();
    #pragma unroll
    for (int s = 0; s < 2; ++s) {
      const int ko = 32 * s + 8 * (lane >> 4);
      bf16x8 a0 = *(const bf16x8*)&As[(wr * 32 +      (lane & 15)) * 72 + ko];
      bf16x8 a1 = *(const bf16x8*)&As[(wr * 32 + 16 + (lane & 15)) * 72 + ko];
      bf16x8 b0 = *(const bf16x8*)&Bs[(wc * 32 +      (lane & 15)) * 72 + ko];
      bf16x8 b1 = *(const bf16x8*)&Bs[(wc * 32 + 16 + (lane & 15)) * 72 + ko];
      acc[0][0] = mfma16(a0, b0, acc[0][0]);
      acc[1][0] = mfma16(a1, b0, acc[1][0]);
      acc[0][1] = mfma16(a0, b1, acc[0][1]);
      acc[1][1] = mfma16(a1, b1, acc[1][1]);
    }
    __syncthreads();
  }

  const float* nxp = a.nx[z];
  const float* nyp = a.ny[z];
  float rp[2][4];
  #pragma unroll
  for (int fm = 0; fm < 2; ++fm)
    #pragma unroll
    for (int p = 0; p < 4; ++p) rp[fm][p] = 0.f;

  #pragma unroll
  for (int fm = 0; fm < 2; ++fm) {
    #pragma unroll
    for (int fn = 0; fn < 2; ++fn) {
      #pragma unroll
      for (int p = 0; p < 4; ++p) {
        int gm = m0 + wr * 32 + fm * 16 + (lane >> 4) * 4 + p;
        int gn = n0 + wc * 32 + fn * 16 + (lane & 15);
        float val = nxp[gm] + nyp[gn] - 2.f * acc[fm][fn][p] + 1e-6f;
        if (z == 2) a.outF[(size_t)gm * 1024 + gn] = val;
        else {
          a.outB[z][(size_t)gm * 1024 + gn] = (unsigned short)f2bf(val);
          rp[fm][p] += val * val;
        }
      }
    }
  }
  if (z < 2) {
    #pragma unroll
    for (int fm = 0; fm < 2; ++fm)
      #pragma unroll
      for (int p = 0; p < 4; ++p) {
        float v = rp[fm][p];
        v += __shfl_xor(v, 1, 64);
        v += __shfl_xor(v, 2, 64);
        v += __shfl_xor(v, 4, 64);
        v += __shfl_xor(v, 8, 64);
        rp[fm][p] = v;
      }
    if ((lane & 15) == 0) {
      #pragma unroll
      for (int fm = 0; fm < 2; ++fm)
        #pragma unroll
        for (int p = 0; p < 4; ++p) {
          int gm = m0 + wr * 32 + fm * 16 + (lane >> 4) * 4 + p;
          atomicAdd(&a.frow[z][gm], rp[fm][p] * (1.f / 1024.f));
        }
    }
  }
}

// ---------------------------------------------------------------------------
// batched transpose (4 weight matrices) + init slice (z==4)
// ---------------------------------------------------------------------------
struct T4 {
  const float* in[4]; unsigned short* out[4]; int R[4], C[4], nx[4], nt[4];
  float* dinv; float* f1; float* f2; unsigned* mx; unsigned* nanflag;
  float* cyc; float* ga; float* gb; float* al;
};
__global__ void k_transpose4(T4 d)
{
  const int z = blockIdx.y;
  const int tid = threadIdx.x;
  if (z == 4) {
    if (blockIdx.x == 0) {
      #pragma unroll
      for (int i = 0; i < 4; ++i) {
        int k = tid + 256 * i;
        d.dinv[k] = PS; d.f1[k] = 0.f; d.f2[k] = 0.f;
      }
      if (tid < 16) d.mx[tid] = 0u;
      if (tid == 0) {
        *d.nanflag = 0u; d.cyc[0] = 0.f; d.cyc[1] = 0.f;
        *d.ga = 0.f; *d.gb = 0.f; *d.al = 0.f;
      }
    }
    return;
  }
  __shared__ float t[64][65];
  const int tile = blockIdx.x;
  if (tile >= d.nt[z]) return;
  const int R = d.R[z], C = d.C[z];
  const int r0 = (tile % d.nx[z]) * 64, c0 = (tile / d.nx[z]) * 64;
  const float* in = d.in[z];
  unsigned short* out = d.out[z];
  #pragma unroll
  for (int i = 0; i < 16; ++i) {
    int idx = tid + 256 * i;
    int r = idx >> 6, c = idx & 63;
    float v = 0.f;
    if ((r0 + r) < R && (c0 + c) < C) v = in[(size_t)(r0 + r) * C + (c0 + c)];
    t[r][c] = v;
  }
  __syncthreads();
  #pragma unroll
  for (int i = 0; i < 16; ++i) {
    int idx = tid + 256 * i;
    int c = idx >> 6, r = idx & 63;
    if ((c0 + c) < C && (r0 + r) < R)
      out[(size_t)(c0 + c) * R + (r0 + r)] = (unsigned short)f2bf(t[r][c]);
  }
}

// Wcomb partial reduce + transpose
__global__ void k_wcomb_reduce(const float* partials, unsigned short* WcTa,
                               unsigned short* WcTb)
{
  __shared__ float t[64][65];
  const int z = blockIdx.z;
  const float* P = partials + (size_t)z * 32 * 256 * 256;
  unsigned short* WcT = z ? WcTb : WcTa;
  const int u0 = blockIdx.x * 64, v0 = blockIdx.y * 64;
  const int tid = threadIdx.x;
  #pragma unroll
  for (int i = 0; i < 16; ++i) {
    int idx = tid + 256 * i;
    int u = idx >> 6, v = idx & 63;
    float s = 0.f;
    for (int p = 0; p < 32; ++p)
      s += P[(size_t)p * 65536 + (u0 + u) * 256 + (v0 + v)];
    t[u][v] = s;
  }
  __syncthreads();
  #pragma unroll
  for (int i = 0; i < 16; ++i) {
    int idx = tid + 256 * i;
    int v = idx >> 6, u = idx & 63;
    WcT[(size_t)(v0 + v) * 256 + (u0 + u)] = (unsigned short)f2bf(t[u][v]);
  }
}

// bc[c] = b4 . Wt1[c,:] + b1[c]
struct BcArgs {
  const float* b4[2]; const unsigned short* Wt1[2]; const float* b1[2];
  float* bc[2]; int K[2];
};
__global__ void k_bcvec(BcArgs a)
{
  const int y = blockIdx.y;
  const int c = blockIdx.x * 4 + (threadIdx.x >> 6);
  const int lane = threadIdx.x & 63;
  const int K = a.K[y];
  const unsigned short* wrow = a.Wt1[y] + (size_t)c * K;
  const float* b4 = a.b4[y];
  float s = 0.f;
  for (int k = lane * 8; k < K; k += 512) {
    s16x8 w = *(const s16x8*)&wrow[k];
    f32x4 v0 = *(const f32x4*)&b4[k];
    f32x4 v1 = *(const f32x4*)&b4[k + 4];
    s += v0.x * bf2f((unsigned short)w[0]) + v0.y * bf2f((unsigned short)w[1])
       + v0.z * bf2f((unsigned short)w[2]) + v0.w * bf2f((unsigned short)w[3])
       + v1.x * bf2f((unsigned short)w[4]) + v1.y * bf2f((unsigned short)w[5])
       + v1.z * bf2f((unsigned short)w[6]) + v1.w * bf2f((unsigned short)w[7]);
  }
  #pragma unroll
  for (int o = 32; o; o >>= 1) s += __shfl_xor(s, o, 64);
  if (lane == 0) a.bc[y][c] = s + a.b1[y][c];
}

// ---------------------------------------------------------------------------
// fused: split-K reduce + relu + enc head + reparam + featprep + GMM KL
// grid (1024, 2), 256 threads
// ---------------------------------------------------------------------------
struct EF {
  const float* partials[2]; const float* bias[2];
  const float* W21[2]; const float* b21[2];
  const float* W22[2]; const float* b22[2]; const float* eps[2];
  const float* pmu[2]; const float* plv[2]; float* gmmO[2];
  float* mu[2]; float* lv[2]; float* zO[2];
  unsigned short* F[2]; float* n[2];
};
__global__ __launch_bounds__(256)
void k_enc_fused(EF a)
{
  __shared__ float hrow[256];
  __shared__ float res[128];
  const int y = blockIdx.y;
  const int i = blockIdx.x;
  const int t = threadIdx.x;
  {
    float s = a.bias[y][t];
    const float* P = a.partials[y] + (size_t)i * 256 + t;
    #pragma unroll
    for (int p = 0; p < 16; ++p) s += P[(size_t)p * 262144];
    hrow[t] = fmaxf(s, 0.f);
  }
  __syncthreads();
  if (t < 128) {
    const int c = t & 63;
    const float* W = (t < 64) ? a.W21[y] : a.W22[y];
    float acc = (t < 64) ? a.b21[y][c] : a.b22[y][c];
    #pragma unroll 8
    for (int j = 0; j < 256; ++j) acc += hrow[j] * W[j * 64 + c];
    res[t] = acc;
  }
  __syncthreads();
  if (t < 64) {
    float mu = res[t], lv = res[64 + t];
    a.mu[y][(size_t)i * 64 + t] = mu;
    a.lv[y][(size_t)i * 64 + t] = lv;
    float sig = expf(0.5f * lv);
    float zd = mu + a.eps[y][(size_t)i * 64 + t] * sig;
    a.zO[y][(size_t)i * 64 + t] = zd;
    unsigned short u0 = (unsigned short)f2bf(mu);
    unsigned short u1 = (unsigned short)f2bf(sig);
    unsigned short* Fr = a.F[y] + (size_t)i * 128;
    Fr[t] = u0;
    Fr[64 + t] = u1;
    float r0 = bf2f(u0), r1 = bf2f(u1);
    float p = r0 * r0 + r1 * r1;
    #pragma unroll
    for (int o = 32; o; o >>= 1) p += __shfl_xor(p, o, 64);
    if (t == 0) a.n[y][i] = p;
    // ---- GMM KL (fused; z/mu/lv in registers)
    float tq = lv + (zd - mu) * (zd - mu) * expf(-lv);
    #pragma unroll
    for (int o = 32; o; o >>= 1) tq += __shfl_xor(tq, o, 64);
    const float C0 = 64.f * 1.8378770664093453f;
    float logq = -0.5f * (C0 + tq);
    float lp[20];
    #pragma unroll
    for (int k = 0; k < 20; ++k) {
      float pm = a.pmu[y][k * 64 + t], pl = a.plv[y][k * 64 + t];
      float u = pl + (zd - pm) * (zd - pm) * expf(-pl);
      #pragma unroll
      for (int o = 32; o; o >>= 1) u += __shfl_xor(u, o, 64);
      lp[k] = -0.5f * (C0 + u);
    }
    float mxv = lp[0];
    #pragma unroll
    for (int k = 1; k < 20; ++k) mxv = fmaxf(mxv, lp[k]);
    float se = 0.f;
    #pragma unroll
    for (int k = 0; k < 20; ++k) se += expf(lp[k] - mxv);
    float logp = mxv + logf(se) - 2.9957322735539909f;
    if (t == 0) atomicAdd(a.gmmO[y], logq - logp);
  }
}

// fused re-encode + cycle-loss partial
struct RencArgs {
  const float* hd[2]; const unsigned short* WcT[2]; const float* bc[2];
  const float* W21[2]; const float* b21[2]; const float* W22[2]; const float* b22[2];
  const float* eps[2]; float* fout[2];
  const float* zin[2]; float* cyc;
};
__global__ void k_renc_head(RencArgs a)
{
  __shared__ float hdrow[256];
  __shared__ float hr[256];
  __shared__ float res[128];
  const int y = blockIdx.y;
  const int i = blockIdx.x;
  const int t = threadIdx.x;                  // 256
  hdrow[t] = a.hd[y][(size_t)i * 256 + t];
  __syncthreads();
  {
    const s16x8* wr = (const s16x8*)(a.WcT[y] + (size_t)t * 256);
    float s = a.bc[y][t];
    #pragma unroll 4
    for (int j = 0; j < 32; ++j) {
      s16x8 w = wr[j];
      const float* hp = &hdrow[j * 8];
      s += hp[0] * bf2f((unsigned short)w[0]) + hp[1] * bf2f((unsigned short)w[1])
         + hp[2] * bf2f((unsigned short)w[2]) + hp[3] * bf2f((unsigned short)w[3])
         + hp[4] * bf2f((unsigned short)w[4]) + hp[5] * bf2f((unsigned short)w[5])
         + hp[6] * bf2f((unsigned short)w[6]) + hp[7] * bf2f((unsigned short)w[7]);
    }
    hr[t] = fmaxf(s, 0.f);
  }
  __syncthreads();
  if (t < 128) {
    const int c = t & 63;
    const float* W = (t < 64) ? a.W21[y] : a.W22[y];
    float acc = (t < 64) ? a.b21[y][c] : a.b22[y][c];
    #pragma unroll 8
    for (int j = 0; j < 256; ++j) acc += hr[j] * W[j * 64 + c];
    res[t] = acc;
  }
  __syncthreads();
  if (t < 64) {
    float mu = res[t], lv = res[64 + t];
    float f = mu + a.eps[y][(size_t)i * 64 + t] * expf(0.5f * lv);
    a.fout[y][(size_t)i * 64 + t] = f;
    float d = a.zin[y][(size_t)i * 64 + t] - f;
    d = d * d;
    #pragma unroll
    for (int o = 32; o; o >>= 1) d += __shfl_xor(d, o, 64);
    if (t == 0) atomicAdd(a.cyc + y, d);
  }
}

// batched decoder heads
struct DH4 { const float* z[4]; const float* W3[4]; const float* b3[4]; float* hd[4]; };
__global__ void k_dec_head4(DH4 a)
{
  __shared__ float zrow[64];
  const int y = blockIdx.y;
  const int i = blockIdx.x;
  const int t = threadIdx.x;                  // 256
  if (t < 64) zrow[t] = a.z[y][(size_t)i * 64 + t];
  __syncthreads();
  const float* W3 = a.W3[y];
  float acc = a.b3[y][t];
  #pragma unroll
  for (int d = 0; d < 64; ++d) acc += zrow[d] * W3[d * 256 + t];
  a.hd[y][(size_t)i * 256 + t] = fmaxf(acc, 0.f);
}

__global__ void k_finish(const float* slots, float* o1, float* o2)
{
  if (threadIdx.x == 0) { *o1 = sqrtf(slots[0]); *o2 = sqrtf(slots[1]); }
}

// ---------------------------------------------------------------------------
extern "C" void kernel_launch(void* const* d_in, const int* in_sizes, int n_in,
                              void* d_out, int out_size, void* d_ws, size_t ws_size,
                              hipStream_t stream)
{
  (void)in_sizes; (void)n_in; (void)out_size; (void)ws_size;

  const float* X     = (const float*)d_in[2];
  const float* Y     = (const float*)d_in[3];
  const float* pmua  = (const float*)d_in[4];
  const float* plva  = (const float*)d_in[5];
  const float* pmub  = (const float*)d_in[6];
  const float* plvb  = (const float*)d_in[7];
  const float* epsx  = (const float*)d_in[8];
  const float* epsy  = (const float*)d_in[9];
  const float* epsxr = (const float*)d_in[10];
  const float* epsyr = (const float*)d_in[11];
  const float* W1a = (const float*)d_in[12];  const float* b1a = (const float*)d_in[13];
  const float* W21a= (const float*)d_in[14];  const float* b21a= (const float*)d_in[15];
  const float* W22a= (const float*)d_in[16];  const float* b22a= (const float*)d_in[17];
  const float* W3a = (const float*)d_in[18];  const float* b3a = (const float*)d_in[19];
  const float* W4a = (const float*)d_in[20];  const float* b4a = (const float*)d_in[21];
  const float* W1b = (const float*)d_in[22];  const float* b1b = (const float*)d_in[23];
  const float* W21b= (const float*)d_in[24];  const float* b21b= (const float*)d_in[25];
  const float* W22b= (const float*)d_in[26];  const float* b22b= (const float*)d_in[27];
  const float* W3b = (const float*)d_in[28];  const float* b3b = (const float*)d_in[29];
  const float* W4b = (const float*)d_in[30];  const float* b4b = (const float*)d_in[31];

  float* out = (float*)d_out;
  const size_t P_X = 0, P_Y = 20480000, P_X2Y = 46080000, P_Y2X = 71680000;
  const size_t Z_X = 92160000, Z_Y = 92225536;
  const size_t GMM_A = 92291072, GMM_B = 92291073;
  const size_t F_XR = 92291074, F_YR = 92356610;
  const size_t ALIGN = 92422146, CYC_X = 92422147, CYC_Y = 92422148;

  // ---- workspace carve
  char* w = (char*)d_ws;
  size_t off = 0;
  auto alloc = [&](size_t bytes) -> void* {
    void* p = w + off;
    off += (bytes + 255) & ~(size_t)255;
    return p;
  };
  unsigned short* Wt1a = (unsigned short*)alloc((size_t)256 * 20000 * 2);
  unsigned short* Wt1b = (unsigned short*)alloc((size_t)256 * 25000 * 2);
  unsigned short* W4ta = (unsigned short*)alloc((size_t)20000 * 256 * 2);
  unsigned short* W4tb = (unsigned short*)alloc((size_t)25000 * 256 * 2);
  unsigned short* WcTa = (unsigned short*)alloc((size_t)256 * 256 * 2);
  unsigned short* WcTb = (unsigned short*)alloc((size_t)256 * 256 * 2);
  float* bca  = (float*)alloc(256 * 4);
  float* bcb  = (float*)alloc(256 * 4);
  float* mu_a = (float*)alloc(1024 * 64 * 4);
  float* lv_a = (float*)alloc(1024 * 64 * 4);
  float* mu_b = (float*)alloc(1024 * 64 * 4);
  float* lv_b = (float*)alloc(1024 * 64 * 4);
  float* f1   = (float*)alloc(1024 * 4);
  float* f2   = (float*)alloc(1024 * 4);
  unsigned* mx      = (unsigned*)alloc(16 * 4);
  unsigned* nanflag = (unsigned*)alloc(256);
  float* cyc  = (float*)alloc(256);
  float* draw = (float*)alloc(1024 * 4);
  float* braw = (float*)alloc(1024 * 4);
  float* braw2 = (float*)alloc(1024 * 4);
  float* dinv = (float*)alloc(1024 * 4);
  unsigned short* Fb = (unsigned short*)alloc((size_t)1024 * 128 * 2);
  unsigned short* Fa = (unsigned short*)alloc((size_t)1024 * 128 * 2);
  float* nb = (float*)alloc(1024 * 4);
  float* na = (float*)alloc(1024 * 4);
  char* arena = (char*)alloc((size_t)32 * 1024 * 1024);
  float* partials = (float*)arena;
  size_t ao = 0;
  auto aalloc = [&](size_t bytes) -> void* {
    void* p = arena + ao;
    ao += (bytes + 255) & ~(size_t)255;
    return p;
  };
  unsigned short* cpostB  = (unsigned short*)aalloc((size_t)1024 * 1024 * 2);
  unsigned short* cpriorB = (unsigned short*)aalloc((size_t)1024 * 1024 * 2);
  float* cpp  = (float*)aalloc((size_t)1024 * 1024 * 4);
  unsigned short* Umat  = (unsigned short*)aalloc((size_t)1024 * 1024 * 2);
  float* cost  = (float*)aalloc((size_t)1024 * 1024 * 4);
  float* Kmat  = (float*)aalloc((size_t)1024 * 1024 * 4);
  float* KTmat = (float*)aalloc((size_t)1024 * 1024 * 4);
  float* hd0 = (float*)(arena);
  float* hd1 = (float*)(arena + (size_t)1024 * 256 * 4);
  float* hd2 = (float*)(arena + (size_t)2 * 1024 * 256 * 4);
  float* hd3 = (float*)(arena + (size_t)3 * 1024 * 256 * 4);

  // ---- 1. weight transposes + init (z=4)
  {
    T4 d{};
    d.in[0] = W1a; d.out[0] = Wt1a; d.R[0] = 20000; d.C[0] = 256;
    d.in[1] = W1b; d.out[1] = Wt1b; d.R[1] = 25000; d.C[1] = 256;
    d.in[2] = W4a; d.out[2] = W4ta; d.R[2] = 256;   d.C[2] = 20000;
    d.in[3] = W4b; d.out[3] = W4tb; d.R[3] = 256;   d.C[3] = 25000;
    for (int z = 0; z < 4; ++z) {
      d.nx[z] = (d.R[z] + 63) / 64;
      d.nt[z] = d.nx[z] * ((d.C[z] + 63) / 64);
    }
    d.dinv = dinv; d.f1 = f1; d.f2 = f2; d.mx = mx; d.nanflag = nanflag;
    d.cyc = cyc; d.ga = out + GMM_A; d.gb = out + GMM_B; d.al = out + ALIGN;
    k_transpose4<<<dim3(1564, 5), 256, 0, stream>>>(d);
  }

  // ---- 2. Wcomb = W4 @ W1 -> WcT bf16 + combined bias
  {
    Q4 q{};
    q.g[0].Af = W4a; q.g[0].Bt = Wt1a; q.g[0].partials = partials;
    q.g[0].M = 256; q.g[0].N = 256; q.g[0].K = 20000;
    q.g[0].lda = 20000; q.g[0].ldbt = 20000;
    q.g[0].totSteps = 313; q.g[0].nSplits = 32;
    q.g[1] = q.g[0];
    q.g[1].Af = W4b; q.g[1].Bt = Wt1b;
    q.g[1].partials = partials + (size_t)32 * 65536;
    q.g[1].K = 25000; q.g[1].lda = 25000; q.g[1].ldbt = 25000; q.g[1].totSteps = 391;
    k_gemmN<128, 256, 4, 4, EPI_PARTIAL><<<dim3(2, 32, 2), 1024, 0, stream>>>(q);
    k_wcomb_reduce<<<dim3(4, 4, 2), 256, 0, stream>>>(partials, WcTa, WcTb);
    BcArgs bc{};
    bc.b4[0] = b4a; bc.Wt1[0] = Wt1a; bc.b1[0] = b1a; bc.bc[0] = bca; bc.K[0] = 20000;
    bc.b4[1] = b4b; bc.Wt1[1] = Wt1b; bc.b1[1] = b1b; bc.bc[1] = bcb; bc.K[1] = 25000;
    k_bcvec<<<dim3(64, 2), 256, 0, stream>>>(bc);
  }

  // ---- 3. encoders (batched GEMM + fused reduce/head/featprep/GMM)
  {
    Q4 q{};
    q.g[0].Af = X; q.g[0].Bt = Wt1a; q.g[0].partials = partials;
    q.g[0].M = 1024; q.g[0].N = 256; q.g[0].K = 20000;
    q.g[0].lda = 20000; q.g[0].ldbt = 20000;
    q.g[0].totSteps = 313; q.g[0].nSplits = 16;
    q.g[1] = q.g[0];
    q.g[1].Af = Y; q.g[1].Bt = Wt1b;
    q.g[1].partials = partials + (size_t)16 * 1024 * 256;
    q.g[1].K = 25000; q.g[1].lda = 25000; q.g[1].ldbt = 25000; q.g[1].totSteps = 391;
    k_gemmN<128, 256, 4, 4, EPI_PARTIAL><<<dim3(8, 16, 2), 1024, 0, stream>>>(q);
    EF e{};
    e.partials[0] = partials; e.partials[1] = partials + (size_t)16 * 1024 * 256;
    e.bias[0] = b1a; e.bias[1] = b1b;
    e.W21[0] = W21a; e.b21[0] = b21a; e.W22[0] = W22a; e.b22[0] = b22a;
    e.eps[0] = epsx; e.mu[0] = mu_a; e.lv[0] = lv_a; e.zO[0] = out + Z_X;
    e.F[0] = Fa; e.n[0] = na;
    e.pmu[0] = pmua; e.plv[0] = plva; e.gmmO[0] = out + GMM_A;
    e.W21[1] = W21b; e.b21[1] = b21b; e.W22[1] = W22b; e.b22[1] = b22b;
    e.eps[1] = epsy; e.mu[1] = mu_b; e.lv[1] = lv_b; e.zO[1] = out + Z_Y;
    e.F[1] = Fb; e.n[1] = nb;
    e.pmu[1] = pmub; e.plv[1] = plvb; e.gmmO[1] = out + GMM_B;
    k_enc_fused<<<dim3(1024, 2), 256, 0, stream>>>(e);
  }

  // ---- 4. FGW(mu_b, mu_a, lv_b, lv_a)
  {
    DistMMArgs dm{};
    dm.Fx[0] = Fb; dm.Fy[0] = Fb; dm.nx[0] = nb; dm.ny[0] = nb;
    dm.Fx[1] = Fa; dm.Fy[1] = Fa; dm.nx[1] = na; dm.ny[1] = na;
    dm.Fx[2] = Fb; dm.Fy[2] = Fa; dm.nx[2] = nb; dm.ny[2] = na;
    dm.outB[0] = cpostB; dm.outB[1] = cpriorB; dm.outF = cpp;
    dm.frow[0] = f1; dm.frow[1] = f2;
    k_distmm<<<dim3(256, 3), 256, 0, stream>>>(dm);
  }
  G1Args g1{};
  g1.A = cpostB; g1.KT = KTmat; g1.dinv = dinv; g1.braw = braw;
  g1.U = Umat; g1.nflag = nanflag;
  FgwGemmArgs fg{};
  fg.A = Umat; fg.Bt = cpriorB;
  fg.f1 = f1; fg.f2 = f2; fg.cpp = cpp; fg.cost = cost;
  fg.loss = out + ALIGN; fg.braw2 = braw2;
  fg.Kf = Kmat; fg.dinv = dinv; fg.brawv = braw; fg.nflag = nanflag;
  for (int it = 0; it < 10; ++it) {
    g1.mode = (it == 0) ? 0 : 1;
    k_fgw_g1<<<256, 256, 0, stream>>>(g1);
    fg.mx = mx + it;
    k_fgw_gemm<EPI_COST><<<256, 256, 0, stream>>>(fg);
    k_kbuild<<<dim3(16, 16), 256, 0, stream>>>(cost, mx + it, Kmat, KTmat,
                                               dinv, braw, braw2, it == 0 ? 1 : 0);
    for (int r = 0; r < 5; ++r) {
      k_matvec<<<256, 256, 0, stream>>>(Kmat, r == 0 ? braw2 : braw, draw, nullptr);
      k_matvec<<<256, 256, 0, stream>>>(KTmat, draw, braw, r == 4 ? dinv : nullptr);
    }
  }
  k_nanscan<<<256, 256, 0, stream>>>(Kmat, dinv, braw, nanflag);
  g1.mode = 2;
  k_fgw_g1<<<256, 256, 0, stream>>>(g1);
  k_fgw_gemm<EPI_LOSS><<<256, 256, 0, stream>>>(fg);

  // ---- 5. decoder heads
  {
    DH4 d{};
    d.z[0] = out + Z_X; d.W3[0] = W3a; d.b3[0] = b3a; d.hd[0] = hd0;   // P_X
    d.z[1] = out + Z_Y; d.W3[1] = W3a; d.b3[1] = b3a; d.hd[1] = hd1;   // P_Y2X
    d.z[2] = out + Z_Y; d.W3[2] = W3b; d.b3[2] = b3b; d.hd[2] = hd2;   // P_Y
    d.z[3] = out + Z_X; d.W3[3] = W3b; d.b3[3] = b3b; d.hd[3] = hd3;   // P_X2Y
    k_dec_head4<<<dim3(1024, 4), 256, 0, stream>>>(d);
  }

  // ---- 6. fused re-encoders (+cycle partials)
  {
    RencArgs r{};
    r.hd[0] = hd3; r.WcT[0] = WcTb; r.bc[0] = bcb;                     // enc_b(dec_b(z_x))
    r.W21[0] = W21b; r.b21[0] = b21b; r.W22[0] = W22b; r.b22[0] = b22b;
    r.eps[0] = epsxr; r.fout[0] = out + F_XR; r.zin[0] = out + Z_X;
    r.hd[1] = hd1; r.WcT[1] = WcTa; r.bc[1] = bca;                     // enc_a(dec_a(z_y))
    r.W21[1] = W21a; r.b21[1] = b21a; r.W22[1] = W22a; r.b22[1] = b22a;
    r.eps[1] = epsyr; r.fout[1] = out + F_YR; r.zin[1] = out + Z_Y;
    r.cyc = cyc;
    k_renc_head<<<dim3(1024, 2), 256, 0, stream>>>(r);
  }
  k_finish<<<1, 64, 0, stream>>>(cyc, out + CYC_X, out + CYC_Y);

  // ---- 7. decoder GEMMs (one launch, z=0..3, 128x128 tiles, 100% occupancy)
  {
    Q4 q{};
    q.g[0].Af = hd0; q.g[0].Bt = W4ta; q.g[0].outF = out + P_X; q.g[0].bias = b4a;
    q.g[0].M = 1024; q.g[0].N = 20000; q.g[0].K = 256;
    q.g[0].lda = 256; q.g[0].ldbt = 256; q.g[0].ldc = 20000;
    q.g[1] = q.g[0]; q.g[1].Af = hd1; q.g[1].outF = out + P_Y2X;
    q.g[2] = q.g[0];
    q.g[2].Af = hd2; q.g[2].Bt = W4tb; q.g[2].outF = out + P_Y; q.g[2].bias = b4b;
    q.g[2].N = 25000; q.g[2].ldc = 25000;
    q.g[3] = q.g[2]; q.g[3].Af = hd3; q.g[3].outF = out + P_X2Y;
    k_gemmN<128, 128, 4, 2, EPI_BIAS><<<dim3(8, 196, 4), 512, 0, stream>>>(q);
  }
}

// Round 10
// 1453.187 us; speedup vs baseline: 1.1987x; 1.0658x over previous
//
#include <hip/hip_runtime.h>

// ============================================================================
// MUCRP_17265768530653 — cross-domain VAE forward on MI355X (gfx950)
// Round 10 (R9 base):
//  - decoder GEMM epilogue: LDS-bounce -> lane-contiguous float4 stores
//    (256B segments vs 64B; R8 profile showed 2.77TB/s on a write-bound kernel)
//  - kbuild additionally emits bf16 KT (KTb); G1 stages B as plain s16x8 copy
//    (bit-identical: same f2bf of same values, half the bytes, no cvt VALU)
// ============================================================================

#define DEVI __device__ __forceinline__

typedef __attribute__((ext_vector_type(4))) float  f32x4;
typedef __attribute__((ext_vector_type(4))) short  s16x4;
typedef __attribute__((ext_vector_type(8))) short  s16x8;
typedef __attribute__((ext_vector_type(8))) __bf16 bf16x8;

#define PS (1.f / 1024.f)
#define UNIF (1.f / (1024.f * 1024.f))

DEVI short f2bf(float f) {              // RNE f32 -> bf16 (bits)
  unsigned u = __float_as_uint(f);
  u += 0x7fffu + ((u >> 16) & 1u);
  return (short)(u >> 16);
}
DEVI float bf2f(unsigned short u) { return __uint_as_float(((unsigned)u) << 16); }

DEVI f32x4 mfma16(bf16x8 a, bf16x8 b, f32x4 c) {
  return __builtin_amdgcn_mfma_f32_16x16x32_bf16(a, b, c, 0, 0, 0);
}

// ---------------------------------------------------------------------------
// Generic tiled MFMA GEMM body (verified R1-R9).
// ---------------------------------------------------------------------------
struct GemmArgs {
  const float* Af;
  const unsigned short* Bt;
  float* outF;
  const float* bias;
  float* partials;
  int M, N, K;
  int lda, ldbt, ldc;
  int totSteps, nSplits;
};

enum { EPI_PARTIAL, EPI_BIAS, EPI_COST, EPI_LOSS };

template<int BM, int BN, int WR, int WC, int EPI>
DEVI void gemm_body(const GemmArgs g)
{
  constexpr int BK = 64, BKP = 72;
  constexpr int NT = WR * WC * 64;
  __shared__ short SM[(BM + BN) * BKP];
  short* As = SM;
  short* Bs = SM + BM * BKP;

  const int m0 = blockIdx.x * BM;
  int n0 = 0, kb0 = 0, kb1 = g.K, split = 0;
  if constexpr (EPI == EPI_PARTIAL) {
    split = blockIdx.y;
    int s0 = (split * g.totSteps) / g.nSplits;
    int s1 = ((split + 1) * g.totSteps) / g.nSplits;
    kb0 = s0 * BK;
    kb1 = s1 * BK; if (kb1 > g.K) kb1 = g.K;
  } else {
    n0 = blockIdx.y * BN;
  }
  const int tid  = threadIdx.x;
  const int lane = tid & 63;
  const int wv   = tid >> 6;
  const int wr   = wv % WR;
  const int wc   = wv / WR;

  f32x4 acc[2][4];
  #pragma unroll
  for (int i = 0; i < 2; ++i)
    #pragma unroll
    for (int j = 0; j < 4; ++j) acc[i][j] = f32x4{0.f, 0.f, 0.f, 0.f};

  for (int kb = kb0; kb < kb1; kb += BK) {
    {   // stage A (f32 -> bf16)
      constexpr int NV = BM * BK / 4;
      #pragma unroll
      for (int i = 0; i < NV / NT; ++i) {
        int idx = tid + NT * i;
        int r = idx >> 4, q = idx & 15;
        int k = kb + 4 * q;
        f32x4 v = f32x4{0.f, 0.f, 0.f, 0.f};
        if (k < kb1) v = *(const f32x4*)(g.Af + (size_t)(m0 + r) * g.lda + k);
        s16x4 s;
        s.x = f2bf(v.x); s.y = f2bf(v.y); s.z = f2bf(v.z); s.w = f2bf(v.w);
        *(s16x4*)&As[r * BKP + 4 * q] = s;
      }
    }
    {   // stage B (bf16 [N][K])
      constexpr int NV = BN * BK / 8;
      #pragma unroll
      for (int i = 0; i < NV / NT; ++i) {
        int idx = tid + NT * i;
        int r = idx >> 3, q = idx & 7;
        int k = kb + 8 * q;
        s16x8 v{};
        if ((n0 + r) < g.N && k < kb1)
          v = *(const s16x8*)(g.Bt + (size_t)(n0 + r) * g.ldbt + k);
        *(s16x8*)&Bs[r * BKP + 8 * q] = v;
      }
    }
    __syncthreads();
    #pragma unroll
    for (int s = 0; s < 2; ++s) {
      const int ko = 32 * s + 8 * (lane >> 4);
      bf16x8 a0 = *(const bf16x8*)&As[(wr * 32 +      (lane & 15)) * BKP + ko];
      bf16x8 a1 = *(const bf16x8*)&As[(wr * 32 + 16 + (lane & 15)) * BKP + ko];
      #pragma unroll
      for (int fn = 0; fn < 4; ++fn) {
        bf16x8 b = *(const bf16x8*)&Bs[(wc * 64 + fn * 16 + (lane & 15)) * BKP + ko];
        acc[0][fn] = mfma16(a0, b, acc[0][fn]);
        acc[1][fn] = mfma16(a1, b, acc[1][fn]);
      }
    }
    __syncthreads();
  }

  if constexpr (EPI == EPI_PARTIAL) {
    #pragma unroll
    for (int fm = 0; fm < 2; ++fm) {
      #pragma unroll
      for (int fn = 0; fn < 4; ++fn) {
        #pragma unroll
        for (int p = 0; p < 4; ++p) {
          int gm = m0 + wr * 32 + fm * 16 + (lane >> 4) * 4 + p;
          int gn = n0 + wc * 64 + fn * 16 + (lane & 15);
          g.partials[((size_t)split * g.M + gm) * 256 + gn] = acc[fm][fn][p];
        }
      }
    }
  } else {
    // LDS-bounce: stage each 64-col half, store lane-contiguous float4 (+bias)
    float* Cs = (float*)SM;                 // BM*65*4 <= (BM+BN)*BKP*2
    #pragma unroll
    for (int h = 0; h < WC; ++h) {
      __syncthreads();
      if (wc == h) {
        #pragma unroll
        for (int fm = 0; fm < 2; ++fm)
          #pragma unroll
          for (int fn = 0; fn < 4; ++fn)
            #pragma unroll
            for (int p = 0; p < 4; ++p)
              Cs[(wr * 32 + fm * 16 + (lane >> 4) * 4 + p) * 65
                 + fn * 16 + (lane & 15)] = acc[fm][fn][p];
      }
      __syncthreads();
      const int n0h = n0 + 64 * h;
      #pragma unroll
      for (int j = tid; j < BM * 16; j += NT) {
        int r = j >> 4, c4 = j & 15;
        int gn = n0h + 4 * c4;
        if (gn < g.N) {
          f32x4 v = *(f32x4*)&Cs[r * 65 + 4 * c4];
          f32x4 b = *(const f32x4*)&g.bias[gn];
          v.x += b.x; v.y += b.y; v.z += b.z; v.w += b.w;
          *(f32x4*)(g.outF + (size_t)(m0 + r) * g.ldc + gn) = v;
        }
      }
    }
  }
}

struct Q4 { GemmArgs g[4]; };

template<int BM, int BN, int WR, int WC, int EPI>
__global__ __launch_bounds__(WR*WC*64)
void k_gemmN(Q4 q)
{
  GemmArgs g = q.g[blockIdx.z];
  if constexpr (EPI == EPI_BIAS) {
    if ((int)(blockIdx.y * BN) >= g.N) return;
  }
  gemm_body<BM, BN, WR, WC, EPI>(g);
}

// ---------------------------------------------------------------------------
// FGW GEMM1': U[m][n] = bscale * sum_k bf16(cpost[m][k]*dinv[k]) * KTb[n][k]
// 64x64 tile, 4 waves, 256 blocks (R7-proven shape: 1 block/CU).
// ---------------------------------------------------------------------------
struct G1Args {
  const unsigned short* A;
  const unsigned short* KTb;   // bf16 KT (written by kbuild)
  const float* dinv;
  const float* braw;
  unsigned short* U;
  const unsigned* nflag;
  int mode;   // 0: uniform  1: factors  2: factors unless nanflag
};

__global__ __launch_bounds__(256)
void k_fgw_g1(G1Args a)
{
  __shared__ short As[64 * 72];
  __shared__ short Bs[64 * 72];
  const bool uni = (a.mode == 0) || (a.mode == 2 && *a.nflag != 0u);

  const int bid = blockIdx.x, tid = threadIdx.x;
  const int lane = tid & 63, wv = tid >> 6;
  const int wr = wv & 1, wc = wv >> 1;
  const int m0 = (bid >> 4) * 64, n0 = (bid & 15) * 64;

  f32x4 acc[2][2];
  #pragma unroll
  for (int i = 0; i < 2; ++i)
    #pragma unroll
    for (int j = 0; j < 2; ++j) acc[i][j] = f32x4{0.f, 0.f, 0.f, 0.f};

  const short ub = f2bf(UNIF);

  for (int kb = 0; kb < 1024; kb += 64) {
    #pragma unroll
    for (int i = 0; i < 2; ++i) {
      int idx = tid + 256 * i;
      int r = idx >> 3, q = idx & 7;
      s16x8 av = *(const s16x8*)&a.A[(size_t)(m0 + r) * 1024 + kb + 8 * q];
      if (!uni) {
        f32x4 d0 = *(const f32x4*)&a.dinv[kb + 8 * q];
        f32x4 d1 = *(const f32x4*)&a.dinv[kb + 8 * q + 4];
        s16x8 o;
        o[0] = f2bf(bf2f((unsigned short)av[0]) * d0.x);
        o[1] = f2bf(bf2f((unsigned short)av[1]) * d0.y);
        o[2] = f2bf(bf2f((unsigned short)av[2]) * d0.z);
        o[3] = f2bf(bf2f((unsigned short)av[3]) * d0.w);
        o[4] = f2bf(bf2f((unsigned short)av[4]) * d1.x);
        o[5] = f2bf(bf2f((unsigned short)av[5]) * d1.y);
        o[6] = f2bf(bf2f((unsigned short)av[6]) * d1.z);
        o[7] = f2bf(bf2f((unsigned short)av[7]) * d1.w);
        av = o;
      }
      *(s16x8*)&As[r * 72 + 8 * q] = av;
      s16x8 bv;
      if (uni) {
        #pragma unroll
        for (int j = 0; j < 8; ++j) bv[j] = ub;
      } else {
        bv = *(const s16x8*)&a.KTb[(size_t)(n0 + r) * 1024 + kb + 8 * q];
      }
      *(s16x8*)&Bs[r * 72 + 8 * q] = bv;
    }
    __syncthreads();
    #pragma unroll
    for (int s = 0; s < 2; ++s) {
      const int ko = 32 * s + 8 * (lane >> 4);
      bf16x8 a0 = *(const bf16x8*)&As[(wr * 32 +      (lane & 15)) * 72 + ko];
      bf16x8 a1 = *(const bf16x8*)&As[(wr * 32 + 16 + (lane & 15)) * 72 + ko];
      bf16x8 b0 = *(const bf16x8*)&Bs[(wc * 32 +      (lane & 15)) * 72 + ko];
      bf16x8 b1 = *(const bf16x8*)&Bs[(wc * 32 + 16 + (lane & 15)) * 72 + ko];
      acc[0][0] = mfma16(a0, b0, acc[0][0]);
      acc[1][0] = mfma16(a1, b0, acc[1][0]);
      acc[0][1] = mfma16(a0, b1, acc[0][1]);
      acc[1][1] = mfma16(a1, b1, acc[1][1]);
    }
    __syncthreads();
  }

  #pragma unroll
  for (int fm = 0; fm < 2; ++fm) {
    #pragma unroll
    for (int fn = 0; fn < 2; ++fn) {
      int gn = n0 + wc * 32 + fn * 16 + (lane & 15);
      float bs = uni ? 1.f : (PS / a.braw[gn]);
      #pragma unroll
      for (int p = 0; p < 4; ++p) {
        int gm = m0 + wr * 32 + fm * 16 + (lane >> 4) * 4 + p;
        float v = acc[fm][fn][p];
        a.U[(size_t)gm * 1024 + gn] = (unsigned short)f2bf(uni ? v : bs * v);
      }
    }
  }
}

// ---------------------------------------------------------------------------
// FGW GEMM (COST / LOSS), 64x64 tile, 4 waves, 256 blocks (R7-proven).
// ---------------------------------------------------------------------------
struct FgwGemmArgs {
  const unsigned short* A;
  const unsigned short* Bt;
  float* cost;
  const float* f1;
  const float* f2;
  const float* cpp;
  unsigned* mx;
  float* loss;
  float* braw2;
  const float* Kf;
  const float* dinv;
  const float* brawv;
  const unsigned* nflag;
};

template<int EPI>
__global__ __launch_bounds__(256)
void k_fgw_gemm(FgwGemmArgs a)
{
  __shared__ short As[64 * 72];
  __shared__ short Bs[64 * 72];
  __shared__ float red[4];

  const int bid = blockIdx.x, tid = threadIdx.x;
  const int lane = tid & 63, wv = tid >> 6;
  const int wr = wv & 1, wc = wv >> 1;
  const int m0 = (bid >> 4) * 64, n0 = (bid & 15) * 64;

  if constexpr (EPI == EPI_COST) {
    if (bid == 0) {
      #pragma unroll
      for (int i = 0; i < 4; ++i) a.braw2[tid + 256 * i] = 0.f;
    }
  }

  f32x4 acc[2][2];
  #pragma unroll
  for (int i = 0; i < 2; ++i)
    #pragma unroll
    for (int j = 0; j < 2; ++j) acc[i][j] = f32x4{0.f, 0.f, 0.f, 0.f};

  for (int kb = 0; kb < 1024; kb += 64) {
    #pragma unroll
    for (int i = 0; i < 2; ++i) {
      int idx = tid + 256 * i;
      int r = idx >> 3, q = idx & 7;
      *(s16x8*)&As[r * 72 + 8 * q] = *(const s16x8*)&a.A [(size_t)(m0 + r) * 1024 + kb + 8 * q];
      *(s16x8*)&Bs[r * 72 + 8 * q] = *(const s16x8*)&a.Bt[(size_t)(n0 + r) * 1024 + kb + 8 * q];
    }
    __syncthreads();
    #pragma unroll
    for (int s = 0; s < 2; ++s) {
      const int ko = 32 * s + 8 * (lane >> 4);
      bf16x8 a0 = *(const bf16x8*)&As[(wr * 32 +      (lane & 15)) * 72 + ko];
      bf16x8 a1 = *(const bf16x8*)&As[(wr * 32 + 16 + (lane & 15)) * 72 + ko];
      bf16x8 b0 = *(const bf16x8*)&Bs[(wc * 32 +      (lane & 15)) * 72 + ko];
      bf16x8 b1 = *(const bf16x8*)&Bs[(wc * 32 + 16 + (lane & 15)) * 72 + ko];
      acc[0][0] = mfma16(a0, b0, acc[0][0]);
      acc[1][0] = mfma16(a1, b0, acc[1][0]);
      acc[0][1] = mfma16(a0, b1, acc[0][1]);
      acc[1][1] = mfma16(a1, b1, acc[1][1]);
    }
    __syncthreads();
  }

  bool uni = false;
  if constexpr (EPI == EPI_LOSS) uni = (*a.nflag != 0u);

  float lred = 0.f;
  #pragma unroll
  for (int fm = 0; fm < 2; ++fm) {
    #pragma unroll
    for (int fn = 0; fn < 2; ++fn) {
      int gn = n0 + wc * 32 + fn * 16 + (lane & 15);
      float bs = 0.f;
      if constexpr (EPI == EPI_LOSS) bs = uni ? 0.f : (PS / a.brawv[gn]);
      #pragma unroll
      for (int p = 0; p < 4; ++p) {
        int gm = m0 + wr * 32 + fm * 16 + (lane >> 4) * 4 + p;
        float v = acc[fm][fn][p];
        size_t o = (size_t)gm * 1024 + gn;
        float c = 0.1f * (a.f1[gm] + a.f2[gn] - 2.f * v) + 0.9f * a.cpp[o];
        if constexpr (EPI == EPI_COST) {
          a.cost[o] = c;
          lred = fmaxf(lred, fabsf(c));
        } else {
          float trec = uni ? UNIF : (a.dinv[gm] * bs) * a.Kf[o];
          lred += c * trec;
        }
      }
    }
  }
  #pragma unroll
  for (int off = 32; off; off >>= 1) {
    float t = __shfl_xor(lred, off, 64);
    lred = (EPI == EPI_COST) ? fmaxf(lred, t) : (lred + t);
  }
  if (lane == 0) red[wv] = lred;
  __syncthreads();
  if (tid == 0) {
    if constexpr (EPI == EPI_COST) {
      float t = fmaxf(fmaxf(red[0], red[1]), fmaxf(red[2], red[3]));
      atomicMax(a.mx, __float_as_uint(t));
    } else {
      atomicAdd(a.loss, red[0] + red[1] + red[2] + red[3]);
    }
  }
}

// ---------------------------------------------------------------------------
// kbuild: tran reconstructed from (K_old, dinv, braw_old) bit-identically,
// K_new = exp(-cost/mx)*tran (in place), KT f32 + KTb bf16, braw2 seed.
// ---------------------------------------------------------------------------
__global__ __launch_bounds__(256)
void k_kbuild(const float* cost, const unsigned* mxbits, float* K, float* KT,
              unsigned short* KTb, const float* dinv, const float* brawOld,
              float* braw2, int uniform)
{
  __shared__ float tt[64 * 65];
  __shared__ float dS[64];
  __shared__ float bS[64];
  __shared__ float csum[4][64];
  const int r0 = blockIdx.x * 64, c0 = blockIdx.y * 64;
  const int tid = threadIdx.x;
  const float inv = 1.f / __uint_as_float(*mxbits);
  if (tid < 64) dS[tid] = dinv[r0 + tid];
  else if (tid >= 64 && tid < 128 && !uniform) bS[tid - 64] = PS / brawOld[c0 + tid - 64];
  __syncthreads();
  float colp = 0.f;
  #pragma unroll
  for (int i = 0; i < 16; ++i) {
    int idx = tid + 256 * i;
    int r = idx >> 6, c = idx & 63;
    size_t o = (size_t)(r0 + r) * 1024 + (c0 + c);
    float trec = uniform ? UNIF : (dS[r] * bS[c]) * K[o];
    float v = expf(-cost[o] * inv) * trec;
    K[o] = v;
    tt[r * 65 + c] = v;
    colp += v * dS[r];
  }
  csum[tid >> 6][tid & 63] = colp;
  __syncthreads();
  #pragma unroll
  for (int i = 0; i < 16; ++i) {
    int idx = tid + 256 * i;
    int c = idx >> 6, r = idx & 63;
    float v = tt[r * 65 + c];
    size_t o = (size_t)(c0 + c) * 1024 + (r0 + r);
    KT[o] = v;
    KTb[o] = (unsigned short)f2bf(v);
  }
  if (tid < 64)
    atomicAdd(&braw2[c0 + tid],
              csum[0][tid] + csum[1][tid] + csum[2][tid] + csum[3][tid]);
}

// y_raw[r] = M[r,:].(PS/x_raw); optionally emits invOut = PS/x (last matvec).
__global__ __launch_bounds__(256)
void k_matvec(const float* M, const float* xraw, float* yraw, float* invOut)
{
  const int r = blockIdx.x * 4 + (threadIdx.x >> 6);
  const int lane = threadIdx.x & 63;
  const int wv = threadIdx.x >> 6;
  const f32x4* row = (const f32x4*)(M + (size_t)r * 1024);
  const f32x4* xv  = (const f32x4*)xraw;
  float s = 0.f;
  #pragma unroll
  for (int q = 0; q < 4; ++q) {
    f32x4 a = row[lane + 64 * q];
    f32x4 x = xv [lane + 64 * q];
    f32x4 iv;
    iv.x = PS / x.x; iv.y = PS / x.y; iv.z = PS / x.z; iv.w = PS / x.w;
    if (invOut && blockIdx.x == 0 && wv == 0)
      *(f32x4*)&invOut[4 * (lane + 64 * q)] = iv;
    s += a.x * iv.x + a.y * iv.y + a.z * iv.z + a.w * iv.w;
  }
  #pragma unroll
  for (int o = 32; o; o >>= 1) s += __shfl_xor(s, o, 64);
  if (lane == 0) yraw[r] = s;
}

// NaN scan over reconstructed tran.
__global__ __launch_bounds__(256)
void k_nanscan(const float* K, const float* dinv, const float* braw, unsigned* flag)
{
  unsigned bad = 0;
  const int base = blockIdx.x * 256 + threadIdx.x;
  #pragma unroll
  for (int i = 0; i < 16; ++i) {
    int idx = base + 65536 * i;
    int r = idx >> 10, c = idx & 1023;
    float v = (dinv[r] * (PS / braw[c])) * K[idx];
    if (v != v) bad = 1u;
  }
  if (bad) atomicOr(flag, 1u);
}

// ---------------------------------------------------------------------------
// Distance via MFMA expanded form (verified R5).
// ---------------------------------------------------------------------------
struct DistMMArgs {
  const unsigned short* Fx[3]; const unsigned short* Fy[3];
  const float* nx[3]; const float* ny[3];
  unsigned short* outB[2]; float* outF; float* frow[2];
};
__global__ __launch_bounds__(256)
void k_distmm(DistMMArgs a)
{
  __shared__ short As[64 * 72];
  __shared__ short Bs[64 * 72];
  const int z = blockIdx.y;
  const int bid = blockIdx.x, tid = threadIdx.x;
  const int lane = tid & 63, wv = tid >> 6;
  const int wr = wv & 1, wc = wv >> 1;
  const int m0 = (bid >> 4) * 64, n0 = (bid & 15) * 64;
  const unsigned short* X = a.Fx[z];
  const unsigned short* Y = a.Fy[z];

  f32x4 acc[2][2];
  #pragma unroll
  for (int i = 0; i < 2; ++i)
    #pragma unroll
    for (int j = 0; j < 2; ++j) acc[i][j] = f32x4{0.f, 0.f, 0.f, 0.f};

  #pragma unroll
  for (int kb = 0; kb < 128; kb += 64) {
    #pragma unroll
    for (int i = 0; i < 2; ++i) {
      int idx = tid + 256 * i;
      int r = idx >> 3, q = idx & 7;
      *(s16x8*)&As[r * 72 + 8 * q] = *(const s16x8*)&X[(size_t)(m0 + r) * 128 + kb + 8 * q];
      *(s16x8*)&Bs[r * 72 + 8 * q] = *(const s16x8*)&Y[(size_t)(n0 + r) * 128 + kb + 8 * q];
    }
    __syncthreads();
    #pragma unroll
    for (int s = 0; s < 2; ++s) {
      const int ko = 32 * s + 8 * (lane >> 4);
      bf16x8 a0 = *(const bf16x8*)&As[(wr * 32 +      (lane & 15)) * 72 + ko];
      bf16x8 a1 = *(const bf16x8*)&As[(wr * 32 + 16 + (lane & 15)) * 72 + ko];
      bf16x8 b0 = *(const bf16x8*)&Bs[(wc * 32 +      (lane & 15)) * 72 + ko];
      bf16x8 b1 = *(const bf16x8*)&Bs[(wc * 32 + 16 + (lane & 15)) * 72 + ko];
      acc[0][0] = mfma16(a0, b0, acc[0][0]);
      acc[1][0] = mfma16(a1, b0, acc[1][0]);
      acc[0][1] = mfma16(a0, b1, acc[0][1]);
      acc[1][1] = mfma16(a1, b1, acc[1][1]);
    }
    __syncthreads();
  }

  const float* nxp = a.nx[z];
  const float* nyp = a.ny[z];
  float rp[2][4];
  #pragma unroll
  for (int fm = 0; fm < 2; ++fm)
    #pragma unroll
    for (int p = 0; p < 4; ++p) rp[fm][p] = 0.f;

  #pragma unroll
  for (int fm = 0; fm < 2; ++fm) {
    #pragma unroll
    for (int fn = 0; fn < 2; ++fn) {
      #pragma unroll
      for (int p = 0; p < 4; ++p) {
        int gm = m0 + wr * 32 + fm * 16 + (lane >> 4) * 4 + p;
        int gn = n0 + wc * 32 + fn * 16 + (lane & 15);
        float val = nxp[gm] + nyp[gn] - 2.f * acc[fm][fn][p] + 1e-6f;
        if (z == 2) a.outF[(size_t)gm * 1024 + gn] = val;
        else {
          a.outB[z][(size_t)gm * 1024 + gn] = (unsigned short)f2bf(val);
          rp[fm][p] += val * val;
        }
      }
    }
  }
  if (z < 2) {
    #pragma unroll
    for (int fm = 0; fm < 2; ++fm)
      #pragma unroll
      for (int p = 0; p < 4; ++p) {
        float v = rp[fm][p];
        v += __shfl_xor(v, 1, 64);
        v += __shfl_xor(v, 2, 64);
        v += __shfl_xor(v, 4, 64);
        v += __shfl_xor(v, 8, 64);
        rp[fm][p] = v;
      }
    if ((lane & 15) == 0) {
      #pragma unroll
      for (int fm = 0; fm < 2; ++fm)
        #pragma unroll
        for (int p = 0; p < 4; ++p) {
          int gm = m0 + wr * 32 + fm * 16 + (lane >> 4) * 4 + p;
          atomicAdd(&a.frow[z][gm], rp[fm][p] * (1.f / 1024.f));
        }
    }
  }
}

// ---------------------------------------------------------------------------
// batched transpose (4 weight matrices) + init slice (z==4)
// ---------------------------------------------------------------------------
struct T4 {
  const float* in[4]; unsigned short* out[4]; int R[4], C[4], nx[4], nt[4];
  float* dinv; float* f1; float* f2; unsigned* mx; unsigned* nanflag;
  float* cyc; float* ga; float* gb; float* al;
};
__global__ void k_transpose4(T4 d)
{
  const int z = blockIdx.y;
  const int tid = threadIdx.x;
  if (z == 4) {
    if (blockIdx.x == 0) {
      #pragma unroll
      for (int i = 0; i < 4; ++i) {
        int k = tid + 256 * i;
        d.dinv[k] = PS; d.f1[k] = 0.f; d.f2[k] = 0.f;
      }
      if (tid < 16) d.mx[tid] = 0u;
      if (tid == 0) {
        *d.nanflag = 0u; d.cyc[0] = 0.f; d.cyc[1] = 0.f;
        *d.ga = 0.f; *d.gb = 0.f; *d.al = 0.f;
      }
    }
    return;
  }
  __shared__ float t[64][65];
  const int tile = blockIdx.x;
  if (tile >= d.nt[z]) return;
  const int R = d.R[z], C = d.C[z];
  const int r0 = (tile % d.nx[z]) * 64, c0 = (tile / d.nx[z]) * 64;
  const float* in = d.in[z];
  unsigned short* out = d.out[z];
  #pragma unroll
  for (int i = 0; i < 16; ++i) {
    int idx = tid + 256 * i;
    int r = idx >> 6, c = idx & 63;
    float v = 0.f;
    if ((r0 + r) < R && (c0 + c) < C) v = in[(size_t)(r0 + r) * C + (c0 + c)];
    t[r][c] = v;
  }
  __syncthreads();
  #pragma unroll
  for (int i = 0; i < 16; ++i) {
    int idx = tid + 256 * i;
    int c = idx >> 6, r = idx & 63;
    if ((c0 + c) < C && (r0 + r) < R)
      out[(size_t)(c0 + c) * R + (r0 + r)] = (unsigned short)f2bf(t[r][c]);
  }
}

// Wcomb partial reduce + transpose
__global__ void k_wcomb_reduce(const float* partials, unsigned short* WcTa,
                               unsigned short* WcTb)
{
  __shared__ float t[64][65];
  const int z = blockIdx.z;
  const float* P = partials + (size_t)z * 32 * 256 * 256;
  unsigned short* WcT = z ? WcTb : WcTa;
  const int u0 = blockIdx.x * 64, v0 = blockIdx.y * 64;
  const int tid = threadIdx.x;
  #pragma unroll
  for (int i = 0; i < 16; ++i) {
    int idx = tid + 256 * i;
    int u = idx >> 6, v = idx & 63;
    float s = 0.f;
    for (int p = 0; p < 32; ++p)
      s += P[(size_t)p * 65536 + (u0 + u) * 256 + (v0 + v)];
    t[u][v] = s;
  }
  __syncthreads();
  #pragma unroll
  for (int i = 0; i < 16; ++i) {
    int idx = tid + 256 * i;
    int v = idx >> 6, u = idx & 63;
    WcT[(size_t)(v0 + v) * 256 + (u0 + u)] = (unsigned short)f2bf(t[u][v]);
  }
}

// bc[c] = b4 . Wt1[c,:] + b1[c]
struct BcArgs {
  const float* b4[2]; const unsigned short* Wt1[2]; const float* b1[2];
  float* bc[2]; int K[2];
};
__global__ void k_bcvec(BcArgs a)
{
  const int y = blockIdx.y;
  const int c = blockIdx.x * 4 + (threadIdx.x >> 6);
  const int lane = threadIdx.x & 63;
  const int K = a.K[y];
  const unsigned short* wrow = a.Wt1[y] + (size_t)c * K;
  const float* b4 = a.b4[y];
  float s = 0.f;
  for (int k = lane * 8; k < K; k += 512) {
    s16x8 w = *(const s16x8*)&wrow[k];
    f32x4 v0 = *(const f32x4*)&b4[k];
    f32x4 v1 = *(const f32x4*)&b4[k + 4];
    s += v0.x * bf2f((unsigned short)w[0]) + v0.y * bf2f((unsigned short)w[1])
       + v0.z * bf2f((unsigned short)w[2]) + v0.w * bf2f((unsigned short)w[3])
       + v1.x * bf2f((unsigned short)w[4]) + v1.y * bf2f((unsigned short)w[5])
       + v1.z * bf2f((unsigned short)w[6]) + v1.w * bf2f((unsigned short)w[7]);
  }
  #pragma unroll
  for (int o = 32; o; o >>= 1) s += __shfl_xor(s, o, 64);
  if (lane == 0) a.bc[y][c] = s + a.b1[y][c];
}

// ---------------------------------------------------------------------------
// fused: split-K reduce + relu + enc head + reparam + featprep + GMM KL
// ---------------------------------------------------------------------------
struct EF {
  const float* partials[2]; const float* bias[2];
  const float* W21[2]; const float* b21[2];
  const float* W22[2]; const float* b22[2]; const float* eps[2];
  const float* pmu[2]; const float* plv[2]; float* gmmO[2];
  float* mu[2]; float* lv[2]; float* zO[2];
  unsigned short* F[2]; float* n[2];
};
__global__ __launch_bounds__(256)
void k_enc_fused(EF a)
{
  __shared__ float hrow[256];
  __shared__ float res[128];
  const int y = blockIdx.y;
  const int i = blockIdx.x;
  const int t = threadIdx.x;
  {
    float s = a.bias[y][t];
    const float* P = a.partials[y] + (size_t)i * 256 + t;
    #pragma unroll
    for (int p = 0; p < 16; ++p) s += P[(size_t)p * 262144];
    hrow[t] = fmaxf(s, 0.f);
  }
  __syncthreads();
  if (t < 128) {
    const int c = t & 63;
    const float* W = (t < 64) ? a.W21[y] : a.W22[y];
    float acc = (t < 64) ? a.b21[y][c] : a.b22[y][c];
    #pragma unroll 8
    for (int j = 0; j < 256; ++j) acc += hrow[j] * W[j * 64 + c];
    res[t] = acc;
  }
  __syncthreads();
  if (t < 64) {
    float mu = res[t], lv = res[64 + t];
    a.mu[y][(size_t)i * 64 + t] = mu;
    a.lv[y][(size_t)i * 64 + t] = lv;
    float sig = expf(0.5f * lv);
    float zd = mu + a.eps[y][(size_t)i * 64 + t] * sig;
    a.zO[y][(size_t)i * 64 + t] = zd;
    unsigned short u0 = (unsigned short)f2bf(mu);
    unsigned short u1 = (unsigned short)f2bf(sig);
    unsigned short* Fr = a.F[y] + (size_t)i * 128;
    Fr[t] = u0;
    Fr[64 + t] = u1;
    float r0 = bf2f(u0), r1 = bf2f(u1);
    float p = r0 * r0 + r1 * r1;
    #pragma unroll
    for (int o = 32; o; o >>= 1) p += __shfl_xor(p, o, 64);
    if (t == 0) a.n[y][i] = p;
    // ---- GMM KL (fused; z/mu/lv in registers)
    float tq = lv + (zd - mu) * (zd - mu) * expf(-lv);
    #pragma unroll
    for (int o = 32; o; o >>= 1) tq += __shfl_xor(tq, o, 64);
    const float C0 = 64.f * 1.8378770664093453f;
    float logq = -0.5f * (C0 + tq);
    float lp[20];
    #pragma unroll
    for (int k = 0; k < 20; ++k) {
      float pm = a.pmu[y][k * 64 + t], pl = a.plv[y][k * 64 + t];
      float u = pl + (zd - pm) * (zd - pm) * expf(-pl);
      #pragma unroll
      for (int o = 32; o; o >>= 1) u += __shfl_xor(u, o, 64);
      lp[k] = -0.5f * (C0 + u);
    }
    float mxv = lp[0];
    #pragma unroll
    for (int k = 1; k < 20; ++k) mxv = fmaxf(mxv, lp[k]);
    float se = 0.f;
    #pragma unroll
    for (int k = 0; k < 20; ++k) se += expf(lp[k] - mxv);
    float logp = mxv + logf(se) - 2.9957322735539909f;
    if (t == 0) atomicAdd(a.gmmO[y], logq - logp);
  }
}

// fused re-encode + cycle-loss partial
struct RencArgs {
  const float* hd[2]; const unsigned short* WcT[2]; const float* bc[2];
  const float* W21[2]; const float* b21[2]; const float* W22[2]; const float* b22[2];
  const float* eps[2]; float* fout[2];
  const float* zin[2]; float* cyc;
};
__global__ void k_renc_head(RencArgs a)
{
  __shared__ float hdrow[256];
  __shared__ float hr[256];
  __shared__ float res[128];
  const int y = blockIdx.y;
  const int i = blockIdx.x;
  const int t = threadIdx.x;                  // 256
  hdrow[t] = a.hd[y][(size_t)i * 256 + t];
  __syncthreads();
  {
    const s16x8* wr = (const s16x8*)(a.WcT[y] + (size_t)t * 256);
    float s = a.bc[y][t];
    #pragma unroll 4
    for (int j = 0; j < 32; ++j) {
      s16x8 w = wr[j];
      const float* hp = &hdrow[j * 8];
      s += hp[0] * bf2f((unsigned short)w[0]) + hp[1] * bf2f((unsigned short)w[1])
         + hp[2] * bf2f((unsigned short)w[2]) + hp[3] * bf2f((unsigned short)w[3])
         + hp[4] * bf2f((unsigned short)w[4]) + hp[5] * bf2f((unsigned short)w[5])
         + hp[6] * bf2f((unsigned short)w[6]) + hp[7] * bf2f((unsigned short)w[7]);
    }
    hr[t] = fmaxf(s, 0.f);
  }
  __syncthreads();
  if (t < 128) {
    const int c = t & 63;
    const float* W = (t < 64) ? a.W21[y] : a.W22[y];
    float acc = (t < 64) ? a.b21[y][c] : a.b22[y][c];
    #pragma unroll 8
    for (int j = 0; j < 256; ++j) acc += hr[j] * W[j * 64 + c];
    res[t] = acc;
  }
  __syncthreads();
  if (t < 64) {
    float mu = res[t], lv = res[64 + t];
    float f = mu + a.eps[y][(size_t)i * 64 + t] * expf(0.5f * lv);
    a.fout[y][(size_t)i * 64 + t] = f;
    float d = a.zin[y][(size_t)i * 64 + t] - f;
    d = d * d;
    #pragma unroll
    for (int o = 32; o; o >>= 1) d += __shfl_xor(d, o, 64);
    if (t == 0) atomicAdd(a.cyc + y, d);
  }
}

// batched decoder heads
struct DH4 { const float* z[4]; const float* W3[4]; const float* b3[4]; float* hd[4]; };
__global__ void k_dec_head4(DH4 a)
{
  __shared__ float zrow[64];
  const int y = blockIdx.y;
  const int i = blockIdx.x;
  const int t = threadIdx.x;                  // 256
  if (t < 64) zrow[t] = a.z[y][(size_t)i * 64 + t];
  __syncthreads();
  const float* W3 = a.W3[y];
  float acc = a.b3[y][t];
  #pragma unroll
  for (int d = 0; d < 64; ++d) acc += zrow[d] * W3[d * 256 + t];
  a.hd[y][(size_t)i * 256 + t] = fmaxf(acc, 0.f);
}

__global__ void k_finish(const float* slots, float* o1, float* o2)
{
  if (threadIdx.x == 0) { *o1 = sqrtf(slots[0]); *o2 = sqrtf(slots[1]); }
}

// ---------------------------------------------------------------------------
extern "C" void kernel_launch(void* const* d_in, const int* in_sizes, int n_in,
                              void* d_out, int out_size, void* d_ws, size_t ws_size,
                              hipStream_t stream)
{
  (void)in_sizes; (void)n_in; (void)out_size; (void)ws_size;

  const float* X     = (const float*)d_in[2];
  const float* Y     = (const float*)d_in[3];
  const float* pmua  = (const float*)d_in[4];
  const float* plva  = (const float*)d_in[5];
  const float* pmub  = (const float*)d_in[6];
  const float* plvb  = (const float*)d_in[7];
  const float* epsx  = (const float*)d_in[8];
  const float* epsy  = (const float*)d_in[9];
  const float* epsxr = (const float*)d_in[10];
  const float* epsyr = (const float*)d_in[11];
  const float* W1a = (const float*)d_in[12];  const float* b1a = (const float*)d_in[13];
  const float* W21a= (const float*)d_in[14];  const float* b21a= (const float*)d_in[15];
  const float* W22a= (const float*)d_in[16];  const float* b22a= (const float*)d_in[17];
  const float* W3a = (const float*)d_in[18];  const float* b3a = (const float*)d_in[19];
  const float* W4a = (const float*)d_in[20];  const float* b4a = (const float*)d_in[21];
  const float* W1b = (const float*)d_in[22];  const float* b1b = (const float*)d_in[23];
  const float* W21b= (const float*)d_in[24];  const float* b21b= (const float*)d_in[25];
  const float* W22b= (const float*)d_in[26];  const float* b22b= (const float*)d_in[27];
  const float* W3b = (const float*)d_in[28];  const float* b3b = (const float*)d_in[29];
  const float* W4b = (const float*)d_in[30];  const float* b4b = (const float*)d_in[31];

  float* out = (float*)d_out;
  const size_t P_X = 0, P_Y = 20480000, P_X2Y = 46080000, P_Y2X = 71680000;
  const size_t Z_X = 92160000, Z_Y = 92225536;
  const size_t GMM_A = 92291072, GMM_B = 92291073;
  const size_t F_XR = 92291074, F_YR = 92356610;
  const size_t ALIGN = 92422146, CYC_X = 92422147, CYC_Y = 92422148;

  // ---- workspace carve
  char* w = (char*)d_ws;
  size_t off = 0;
  auto alloc = [&](size_t bytes) -> void* {
    void* p = w + off;
    off += (bytes + 255) & ~(size_t)255;
    return p;
  };
  unsigned short* Wt1a = (unsigned short*)alloc((size_t)256 * 20000 * 2);
  unsigned short* Wt1b = (unsigned short*)alloc((size_t)256 * 25000 * 2);
  unsigned short* W4ta = (unsigned short*)alloc((size_t)20000 * 256 * 2);
  unsigned short* W4tb = (unsigned short*)alloc((size_t)25000 * 256 * 2);
  unsigned short* WcTa = (unsigned short*)alloc((size_t)256 * 256 * 2);
  unsigned short* WcTb = (unsigned short*)alloc((size_t)256 * 256 * 2);
  float* bca  = (float*)alloc(256 * 4);
  float* bcb  = (float*)alloc(256 * 4);
  float* mu_a = (float*)alloc(1024 * 64 * 4);
  float* lv_a = (float*)alloc(1024 * 64 * 4);
  float* mu_b = (float*)alloc(1024 * 64 * 4);
  float* lv_b = (float*)alloc(1024 * 64 * 4);
  float* f1   = (float*)alloc(1024 * 4);
  float* f2   = (float*)alloc(1024 * 4);
  unsigned* mx      = (unsigned*)alloc(16 * 4);
  unsigned* nanflag = (unsigned*)alloc(256);
  float* cyc  = (float*)alloc(256);
  float* draw = (float*)alloc(1024 * 4);
  float* braw = (float*)alloc(1024 * 4);
  float* braw2 = (float*)alloc(1024 * 4);
  float* dinv = (float*)alloc(1024 * 4);
  unsigned short* Fb = (unsigned short*)alloc((size_t)1024 * 128 * 2);
  unsigned short* Fa = (unsigned short*)alloc((size_t)1024 * 128 * 2);
  float* nb = (float*)alloc(1024 * 4);
  float* na = (float*)alloc(1024 * 4);
  char* arena = (char*)alloc((size_t)32 * 1024 * 1024);
  float* partials = (float*)arena;
  size_t ao = 0;
  auto aalloc = [&](size_t bytes) -> void* {
    void* p = arena + ao;
    ao += (bytes + 255) & ~(size_t)255;
    return p;
  };
  unsigned short* cpostB  = (unsigned short*)aalloc((size_t)1024 * 1024 * 2);
  unsigned short* cpriorB = (unsigned short*)aalloc((size_t)1024 * 1024 * 2);
  float* cpp  = (float*)aalloc((size_t)1024 * 1024 * 4);
  unsigned short* Umat  = (unsigned short*)aalloc((size_t)1024 * 1024 * 2);
  float* cost  = (float*)aalloc((size_t)1024 * 1024 * 4);
  float* Kmat  = (float*)aalloc((size_t)1024 * 1024 * 4);
  float* KTmat = (float*)aalloc((size_t)1024 * 1024 * 4);
  unsigned short* KTb = (unsigned short*)aalloc((size_t)1024 * 1024 * 2);
  float* hd0 = (float*)(arena);
  float* hd1 = (float*)(arena + (size_t)1024 * 256 * 4);
  float* hd2 = (float*)(arena + (size_t)2 * 1024 * 256 * 4);
  float* hd3 = (float*)(arena + (size_t)3 * 1024 * 256 * 4);

  // ---- 1. weight transposes + init (z=4)
  {
    T4 d{};
    d.in[0] = W1a; d.out[0] = Wt1a; d.R[0] = 20000; d.C[0] = 256;
    d.in[1] = W1b; d.out[1] = Wt1b; d.R[1] = 25000; d.C[1] = 256;
    d.in[2] = W4a; d.out[2] = W4ta; d.R[2] = 256;   d.C[2] = 20000;
    d.in[3] = W4b; d.out[3] = W4tb; d.R[3] = 256;   d.C[3] = 25000;
    for (int z = 0; z < 4; ++z) {
      d.nx[z] = (d.R[z] + 63) / 64;
      d.nt[z] = d.nx[z] * ((d.C[z] + 63) / 64);
    }
    d.dinv = dinv; d.f1 = f1; d.f2 = f2; d.mx = mx; d.nanflag = nanflag;
    d.cyc = cyc; d.ga = out + GMM_A; d.gb = out + GMM_B; d.al = out + ALIGN;
    k_transpose4<<<dim3(1564, 5), 256, 0, stream>>>(d);
  }

  // ---- 2. Wcomb = W4 @ W1 -> WcT bf16 + combined bias
  {
    Q4 q{};
    q.g[0].Af = W4a; q.g[0].Bt = Wt1a; q.g[0].partials = partials;
    q.g[0].M = 256; q.g[0].N = 256; q.g[0].K = 20000;
    q.g[0].lda = 20000; q.g[0].ldbt = 20000;
    q.g[0].totSteps = 313; q.g[0].nSplits = 32;
    q.g[1] = q.g[0];
    q.g[1].Af = W4b; q.g[1].Bt = Wt1b;
    q.g[1].partials = partials + (size_t)32 * 65536;
    q.g[1].K = 25000; q.g[1].lda = 25000; q.g[1].ldbt = 25000; q.g[1].totSteps = 391;
    k_gemmN<128, 256, 4, 4, EPI_PARTIAL><<<dim3(2, 32, 2), 1024, 0, stream>>>(q);
    k_wcomb_reduce<<<dim3(4, 4, 2), 256, 0, stream>>>(partials, WcTa, WcTb);
    BcArgs bc{};
    bc.b4[0] = b4a; bc.Wt1[0] = Wt1a; bc.b1[0] = b1a; bc.bc[0] = bca; bc.K[0] = 20000;
    bc.b4[1] = b4b; bc.Wt1[1] = Wt1b; bc.b1[1] = b1b; bc.bc[1] = bcb; bc.K[1] = 25000;
    k_bcvec<<<dim3(64, 2), 256, 0, stream>>>(bc);
  }

  // ---- 3. encoders (batched GEMM + fused reduce/head/featprep/GMM)
  {
    Q4 q{};
    q.g[0].Af = X; q.g[0].Bt = Wt1a; q.g[0].partials = partials;
    q.g[0].M = 1024; q.g[0].N = 256; q.g[0].K = 20000;
    q.g[0].lda = 20000; q.g[0].ldbt = 20000;
    q.g[0].totSteps = 313; q.g[0].nSplits = 16;
    q.g[1] = q.g[0];
    q.g[1].Af = Y; q.g[1].Bt = Wt1b;
    q.g[1].partials = partials + (size_t)16 * 1024 * 256;
    q.g[1].K = 25000; q.g[1].lda = 25000; q.g[1].ldbt = 25000; q.g[1].totSteps = 391;
    k_gemmN<128, 256, 4, 4, EPI_PARTIAL><<<dim3(8, 16, 2), 1024, 0, stream>>>(q);
    EF e{};
    e.partials[0] = partials; e.partials[1] = partials + (size_t)16 * 1024 * 256;
    e.bias[0] = b1a; e.bias[1] = b1b;
    e.W21[0] = W21a; e.b21[0] = b21a; e.W22[0] = W22a; e.b22[0] = b22a;
    e.eps[0] = epsx; e.mu[0] = mu_a; e.lv[0] = lv_a; e.zO[0] = out + Z_X;
    e.F[0] = Fa; e.n[0] = na;
    e.pmu[0] = pmua; e.plv[0] = plva; e.gmmO[0] = out + GMM_A;
    e.W21[1] = W21b; e.b21[1] = b21b; e.W22[1] = W22b; e.b22[1] = b22b;
    e.eps[1] = epsy; e.mu[1] = mu_b; e.lv[1] = lv_b; e.zO[1] = out + Z_Y;
    e.F[1] = Fb; e.n[1] = nb;
    e.pmu[1] = pmub; e.plv[1] = plvb; e.gmmO[1] = out + GMM_B;
    k_enc_fused<<<dim3(1024, 2), 256, 0, stream>>>(e);
  }

  // ---- 4. FGW(mu_b, mu_a, lv_b, lv_a)
  {
    DistMMArgs dm{};
    dm.Fx[0] = Fb; dm.Fy[0] = Fb; dm.nx[0] = nb; dm.ny[0] = nb;
    dm.Fx[1] = Fa; dm.Fy[1] = Fa; dm.nx[1] = na; dm.ny[1] = na;
    dm.Fx[2] = Fb; dm.Fy[2] = Fa; dm.nx[2] = nb; dm.ny[2] = na;
    dm.outB[0] = cpostB; dm.outB[1] = cpriorB; dm.outF = cpp;
    dm.frow[0] = f1; dm.frow[1] = f2;
    k_distmm<<<dim3(256, 3), 256, 0, stream>>>(dm);
  }
  G1Args g1{};
  g1.A = cpostB; g1.KTb = KTb; g1.dinv = dinv; g1.braw = braw;
  g1.U = Umat; g1.nflag = nanflag;
  FgwGemmArgs fg{};
  fg.A = Umat; fg.Bt = cpriorB;
  fg.f1 = f1; fg.f2 = f2; fg.cpp = cpp; fg.cost = cost;
  fg.loss = out + ALIGN; fg.braw2 = braw2;
  fg.Kf = Kmat; fg.dinv = dinv; fg.brawv = braw; fg.nflag = nanflag;
  for (int it = 0; it < 10; ++it) {
    g1.mode = (it == 0) ? 0 : 1;
    k_fgw_g1<<<256, 256, 0, stream>>>(g1);
    fg.mx = mx + it;
    k_fgw_gemm<EPI_COST><<<256, 256, 0, stream>>>(fg);
    k_kbuild<<<dim3(16, 16), 256, 0, stream>>>(cost, mx + it, Kmat, KTmat, KTb,
                                               dinv, braw, braw2, it == 0 ? 1 : 0);
    for (int r = 0; r < 5; ++r) {
      k_matvec<<<256, 256, 0, stream>>>(Kmat, r == 0 ? braw2 : braw, draw, nullptr);
      k_matvec<<<256, 256, 0, stream>>>(KTmat, draw, braw, r == 4 ? dinv : nullptr);
    }
  }
  k_nanscan<<<256, 256, 0, stream>>>(Kmat, dinv, braw, nanflag);
  g1.mode = 2;
  k_fgw_g1<<<256, 256, 0, stream>>>(g1);
  k_fgw_gemm<EPI_LOSS><<<256, 256, 0, stream>>>(fg);

  // ---- 5. decoder heads
  {
    DH4 d{};
    d.z[0] = out + Z_X; d.W3[0] = W3a; d.b3[0] = b3a; d.hd[0] = hd0;   // P_X
    d.z[1] = out + Z_Y; d.W3[1] = W3a; d.b3[1] = b3a; d.hd[1] = hd1;   // P_Y2X
    d.z[2] = out + Z_Y; d.W3[2] = W3b; d.b3[2] = b3b; d.hd[2] = hd2;   // P_Y
    d.z[3] = out + Z_X; d.W3[3] = W3b; d.b3[3] = b3b; d.hd[3] = hd3;   // P_X2Y
    k_dec_head4<<<dim3(1024, 4), 256, 0, stream>>>(d);
  }

  // ---- 6. fused re-encoders (+cycle partials)
  {
    RencArgs r{};
    r.hd[0] = hd3; r.WcT[0] = WcTb; r.bc[0] = bcb;                     // enc_b(dec_b(z_x))
    r.W21[0] = W21b; r.b21[0] = b21b; r.W22[0] = W22b; r.b22[0] = b22b;
    r.eps[0] = epsxr; r.fout[0] = out + F_XR; r.zin[0] = out + Z_X;
    r.hd[1] = hd1; r.WcT[1] = WcTa; r.bc[1] = bca;                     // enc_a(dec_a(z_y))
    r.W21[1] = W21a; r.b21[1] = b21a; r.W22[1] = W22a; r.b22[1] = b22a;
    r.eps[1] = epsyr; r.fout[1] = out + F_YR; r.zin[1] = out + Z_Y;
    r.cyc = cyc;
    k_renc_head<<<dim3(1024, 2), 256, 0, stream>>>(r);
  }
  k_finish<<<1, 64, 0, stream>>>(cyc, out + CYC_X, out + CYC_Y);

  // ---- 7. decoder GEMMs (one launch, z=0..3, coalesced LDS-bounce stores)
  {
    Q4 q{};
    q.g[0].Af = hd0; q.g[0].Bt = W4ta; q.g[0].outF = out + P_X; q.g[0].bias = b4a;
    q.g[0].M = 1024; q.g[0].N = 20000; q.g[0].K = 256;
    q.g[0].lda = 256; q.g[0].ldbt = 256; q.g[0].ldc = 20000;
    q.g[1] = q.g[0]; q.g[1].Af = hd1; q.g[1].outF = out + P_Y2X;
    q.g[2] = q.g[0];
    q.g[2].Af = hd2; q.g[2].Bt = W4tb; q.g[2].outF = out + P_Y; q.g[2].bias = b4b;
    q.g[2].N = 25000; q.g[2].ldc = 25000;
    q.g[3] = q.g[2]; q.g[3].Af = hd3; q.g[3].outF = out + P_X2Y;
    k_gemmN<128, 128, 4, 2, EPI_BIAS><<<dim3(8, 196, 4), 512, 0, stream>>>(q);
  }
}

// Round 11
// 1394.263 us; speedup vs baseline: 1.2493x; 1.0423x over previous
//
#include <hip/hip_runtime.h>

// ============================================================================
// MUCRP_17265768530653 — cross-domain VAE forward on MI355X (gfx950)
// Round 11 (R10 base):
//  - FGW 1024^3 GEMMs: 4 -> 8 waves per 64x64 block (512 thr, grid 256).
//    Same tile, same grid=1 block/CU, double the waves/CU (12.5% -> 25%
//    occupancy) to hide staging latency.  Bit-identical dataflow.
//  - Wcomb GEMM: nSplits 32 -> 64 (grid 256 blocks, was 128 = half idle).
// ============================================================================

#define DEVI __device__ __forceinline__

typedef __attribute__((ext_vector_type(4))) float  f32x4;
typedef __attribute__((ext_vector_type(4))) short  s16x4;
typedef __attribute__((ext_vector_type(8))) short  s16x8;
typedef __attribute__((ext_vector_type(8))) __bf16 bf16x8;

#define PS (1.f / 1024.f)
#define UNIF (1.f / (1024.f * 1024.f))

DEVI short f2bf(float f) {              // RNE f32 -> bf16 (bits)
  unsigned u = __float_as_uint(f);
  u += 0x7fffu + ((u >> 16) & 1u);
  return (short)(u >> 16);
}
DEVI float bf2f(unsigned short u) { return __uint_as_float(((unsigned)u) << 16); }

DEVI f32x4 mfma16(bf16x8 a, bf16x8 b, f32x4 c) {
  return __builtin_amdgcn_mfma_f32_16x16x32_bf16(a, b, c, 0, 0, 0);
}

// ---------------------------------------------------------------------------
// Generic tiled MFMA GEMM body (verified R1-R10).
// ---------------------------------------------------------------------------
struct GemmArgs {
  const float* Af;
  const unsigned short* Bt;
  float* outF;
  const float* bias;
  float* partials;
  int M, N, K;
  int lda, ldbt, ldc;
  int totSteps, nSplits;
};

enum { EPI_PARTIAL, EPI_BIAS, EPI_COST, EPI_LOSS };

template<int BM, int BN, int WR, int WC, int EPI>
DEVI void gemm_body(const GemmArgs g)
{
  constexpr int BK = 64, BKP = 72;
  constexpr int NT = WR * WC * 64;
  __shared__ short SM[(BM + BN) * BKP];
  short* As = SM;
  short* Bs = SM + BM * BKP;

  const int m0 = blockIdx.x * BM;
  int n0 = 0, kb0 = 0, kb1 = g.K, split = 0;
  if constexpr (EPI == EPI_PARTIAL) {
    split = blockIdx.y;
    int s0 = (split * g.totSteps) / g.nSplits;
    int s1 = ((split + 1) * g.totSteps) / g.nSplits;
    kb0 = s0 * BK;
    kb1 = s1 * BK; if (kb1 > g.K) kb1 = g.K;
  } else {
    n0 = blockIdx.y * BN;
  }
  const int tid  = threadIdx.x;
  const int lane = tid & 63;
  const int wv   = tid >> 6;
  const int wr   = wv % WR;
  const int wc   = wv / WR;

  f32x4 acc[2][4];
  #pragma unroll
  for (int i = 0; i < 2; ++i)
    #pragma unroll
    for (int j = 0; j < 4; ++j) acc[i][j] = f32x4{0.f, 0.f, 0.f, 0.f};

  for (int kb = kb0; kb < kb1; kb += BK) {
    {   // stage A (f32 -> bf16)
      constexpr int NV = BM * BK / 4;
      #pragma unroll
      for (int i = 0; i < NV / NT; ++i) {
        int idx = tid + NT * i;
        int r = idx >> 4, q = idx & 15;
        int k = kb + 4 * q;
        f32x4 v = f32x4{0.f, 0.f, 0.f, 0.f};
        if (k < kb1) v = *(const f32x4*)(g.Af + (size_t)(m0 + r) * g.lda + k);
        s16x4 s;
        s.x = f2bf(v.x); s.y = f2bf(v.y); s.z = f2bf(v.z); s.w = f2bf(v.w);
        *(s16x4*)&As[r * BKP + 4 * q] = s;
      }
    }
    {   // stage B (bf16 [N][K])
      constexpr int NV = BN * BK / 8;
      #pragma unroll
      for (int i = 0; i < NV / NT; ++i) {
        int idx = tid + NT * i;
        int r = idx >> 3, q = idx & 7;
        int k = kb + 8 * q;
        s16x8 v{};
        if ((n0 + r) < g.N && k < kb1)
          v = *(const s16x8*)(g.Bt + (size_t)(n0 + r) * g.ldbt + k);
        *(s16x8*)&Bs[r * BKP + 8 * q] = v;
      }
    }
    __syncthreads();
    #pragma unroll
    for (int s = 0; s < 2; ++s) {
      const int ko = 32 * s + 8 * (lane >> 4);
      bf16x8 a0 = *(const bf16x8*)&As[(wr * 32 +      (lane & 15)) * BKP + ko];
      bf16x8 a1 = *(const bf16x8*)&As[(wr * 32 + 16 + (lane & 15)) * BKP + ko];
      #pragma unroll
      for (int fn = 0; fn < 4; ++fn) {
        bf16x8 b = *(const bf16x8*)&Bs[(wc * 64 + fn * 16 + (lane & 15)) * BKP + ko];
        acc[0][fn] = mfma16(a0, b, acc[0][fn]);
        acc[1][fn] = mfma16(a1, b, acc[1][fn]);
      }
    }
    __syncthreads();
  }

  if constexpr (EPI == EPI_PARTIAL) {
    #pragma unroll
    for (int fm = 0; fm < 2; ++fm) {
      #pragma unroll
      for (int fn = 0; fn < 4; ++fn) {
        #pragma unroll
        for (int p = 0; p < 4; ++p) {
          int gm = m0 + wr * 32 + fm * 16 + (lane >> 4) * 4 + p;
          int gn = n0 + wc * 64 + fn * 16 + (lane & 15);
          g.partials[((size_t)split * g.M + gm) * 256 + gn] = acc[fm][fn][p];
        }
      }
    }
  } else {
    // LDS-bounce: stage each 64-col half, store lane-contiguous float4 (+bias)
    float* Cs = (float*)SM;
    #pragma unroll
    for (int h = 0; h < WC; ++h) {
      __syncthreads();
      if (wc == h) {
        #pragma unroll
        for (int fm = 0; fm < 2; ++fm)
          #pragma unroll
          for (int fn = 0; fn < 4; ++fn)
            #pragma unroll
            for (int p = 0; p < 4; ++p)
              Cs[(wr * 32 + fm * 16 + (lane >> 4) * 4 + p) * 65
                 + fn * 16 + (lane & 15)] = acc[fm][fn][p];
      }
      __syncthreads();
      const int n0h = n0 + 64 * h;
      #pragma unroll
      for (int j = tid; j < BM * 16; j += NT) {
        int r = j >> 4, c4 = j & 15;
        int gn = n0h + 4 * c4;
        if (gn < g.N) {
          f32x4 v = *(f32x4*)&Cs[r * 65 + 4 * c4];
          f32x4 b = *(const f32x4*)&g.bias[gn];
          v.x += b.x; v.y += b.y; v.z += b.z; v.w += b.w;
          *(f32x4*)(g.outF + (size_t)(m0 + r) * g.ldc + gn) = v;
        }
      }
    }
  }
}

struct Q4 { GemmArgs g[4]; };

template<int BM, int BN, int WR, int WC, int EPI>
__global__ __launch_bounds__(WR*WC*64)
void k_gemmN(Q4 q)
{
  GemmArgs g = q.g[blockIdx.z];
  if constexpr (EPI == EPI_BIAS) {
    if ((int)(blockIdx.y * BN) >= g.N) return;
  }
  gemm_body<BM, BN, WR, WC, EPI>(g);
}

// ---------------------------------------------------------------------------
// FGW GEMM1': U[m][n] = bscale * sum_k bf16(cpost[m][k]*dinv[k]) * KTb[n][k]
// 64x64 tile, 8 waves (2x4, wave tile 32x16), 256 blocks.
// ---------------------------------------------------------------------------
struct G1Args {
  const unsigned short* A;
  const unsigned short* KTb;
  const float* dinv;
  const float* braw;
  unsigned short* U;
  const unsigned* nflag;
  int mode;   // 0: uniform  1: factors  2: factors unless nanflag
};

__global__ __launch_bounds__(512)
void k_fgw_g1(G1Args a)
{
  __shared__ short As[64 * 72];
  __shared__ short Bs[64 * 72];
  const bool uni = (a.mode == 0) || (a.mode == 2 && *a.nflag != 0u);

  const int bid = blockIdx.x, tid = threadIdx.x;
  const int lane = tid & 63, wv = tid >> 6;
  const int wr = wv & 1, wc = wv >> 1;          // 2x4 waves, 32x16 each
  const int m0 = (bid >> 4) * 64, n0 = (bid & 15) * 64;

  f32x4 acc[2];
  acc[0] = f32x4{0.f, 0.f, 0.f, 0.f};
  acc[1] = f32x4{0.f, 0.f, 0.f, 0.f};

  const short ub = f2bf(UNIF);

  for (int kb = 0; kb < 1024; kb += 64) {
    {
      int r = tid >> 3, q = tid & 7;
      s16x8 av = *(const s16x8*)&a.A[(size_t)(m0 + r) * 1024 + kb + 8 * q];
      if (!uni) {
        f32x4 d0 = *(const f32x4*)&a.dinv[kb + 8 * q];
        f32x4 d1 = *(const f32x4*)&a.dinv[kb + 8 * q + 4];
        s16x8 o;
        o[0] = f2bf(bf2f((unsigned short)av[0]) * d0.x);
        o[1] = f2bf(bf2f((unsigned short)av[1]) * d0.y);
        o[2] = f2bf(bf2f((unsigned short)av[2]) * d0.z);
        o[3] = f2bf(bf2f((unsigned short)av[3]) * d0.w);
        o[4] = f2bf(bf2f((unsigned short)av[4]) * d1.x);
        o[5] = f2bf(bf2f((unsigned short)av[5]) * d1.y);
        o[6] = f2bf(bf2f((unsigned short)av[6]) * d1.z);
        o[7] = f2bf(bf2f((unsigned short)av[7]) * d1.w);
        av = o;
      }
      *(s16x8*)&As[r * 72 + 8 * q] = av;
      s16x8 bv;
      if (uni) {
        #pragma unroll
        for (int j = 0; j < 8; ++j) bv[j] = ub;
      } else {
        bv = *(const s16x8*)&a.KTb[(size_t)(n0 + r) * 1024 + kb + 8 * q];
      }
      *(s16x8*)&Bs[r * 72 + 8 * q] = bv;
    }
    __syncthreads();
    #pragma unroll
    for (int s = 0; s < 2; ++s) {
      const int ko = 32 * s + 8 * (lane >> 4);
      bf16x8 b0 = *(const bf16x8*)&Bs[(wc * 16 + (lane & 15)) * 72 + ko];
      bf16x8 a0 = *(const bf16x8*)&As[(wr * 32 +      (lane & 15)) * 72 + ko];
      bf16x8 a1 = *(const bf16x8*)&As[(wr * 32 + 16 + (lane & 15)) * 72 + ko];
      acc[0] = mfma16(a0, b0, acc[0]);
      acc[1] = mfma16(a1, b0, acc[1]);
    }
    __syncthreads();
  }

  const int gn = n0 + wc * 16 + (lane & 15);
  const float bs = uni ? 1.f : (PS / a.braw[gn]);
  #pragma unroll
  for (int fm = 0; fm < 2; ++fm) {
    #pragma unroll
    for (int p = 0; p < 4; ++p) {
      int gm = m0 + wr * 32 + fm * 16 + (lane >> 4) * 4 + p;
      float v = acc[fm][p];
      a.U[(size_t)gm * 1024 + gn] = (unsigned short)f2bf(uni ? v : bs * v);
    }
  }
}

// ---------------------------------------------------------------------------
// FGW GEMM (COST / LOSS), 64x64 tile, 8 waves, 256 blocks.
// ---------------------------------------------------------------------------
struct FgwGemmArgs {
  const unsigned short* A;
  const unsigned short* Bt;
  float* cost;
  const float* f1;
  const float* f2;
  const float* cpp;
  unsigned* mx;
  float* loss;
  float* braw2;
  const float* Kf;
  const float* dinv;
  const float* brawv;
  const unsigned* nflag;
};

template<int EPI>
__global__ __launch_bounds__(512)
void k_fgw_gemm(FgwGemmArgs a)
{
  __shared__ short As[64 * 72];
  __shared__ short Bs[64 * 72];
  __shared__ float red[8];

  const int bid = blockIdx.x, tid = threadIdx.x;
  const int lane = tid & 63, wv = tid >> 6;
  const int wr = wv & 1, wc = wv >> 1;
  const int m0 = (bid >> 4) * 64, n0 = (bid & 15) * 64;

  if constexpr (EPI == EPI_COST) {
    if (bid == 0) {
      #pragma unroll
      for (int i = 0; i < 2; ++i) a.braw2[tid + 512 * i] = 0.f;
    }
  }

  f32x4 acc[2];
  acc[0] = f32x4{0.f, 0.f, 0.f, 0.f};
  acc[1] = f32x4{0.f, 0.f, 0.f, 0.f};

  for (int kb = 0; kb < 1024; kb += 64) {
    {
      int r = tid >> 3, q = tid & 7;
      *(s16x8*)&As[r * 72 + 8 * q] = *(const s16x8*)&a.A [(size_t)(m0 + r) * 1024 + kb + 8 * q];
      *(s16x8*)&Bs[r * 72 + 8 * q] = *(const s16x8*)&a.Bt[(size_t)(n0 + r) * 1024 + kb + 8 * q];
    }
    __syncthreads();
    #pragma unroll
    for (int s = 0; s < 2; ++s) {
      const int ko = 32 * s + 8 * (lane >> 4);
      bf16x8 b0 = *(const bf16x8*)&Bs[(wc * 16 + (lane & 15)) * 72 + ko];
      bf16x8 a0 = *(const bf16x8*)&As[(wr * 32 +      (lane & 15)) * 72 + ko];
      bf16x8 a1 = *(const bf16x8*)&As[(wr * 32 + 16 + (lane & 15)) * 72 + ko];
      acc[0] = mfma16(a0, b0, acc[0]);
      acc[1] = mfma16(a1, b0, acc[1]);
    }
    __syncthreads();
  }

  bool uni = false;
  if constexpr (EPI == EPI_LOSS) uni = (*a.nflag != 0u);

  const int gn = n0 + wc * 16 + (lane & 15);
  float bs = 0.f;
  if constexpr (EPI == EPI_LOSS) bs = uni ? 0.f : (PS / a.brawv[gn]);

  float lred = 0.f;
  #pragma unroll
  for (int fm = 0; fm < 2; ++fm) {
    #pragma unroll
    for (int p = 0; p < 4; ++p) {
      int gm = m0 + wr * 32 + fm * 16 + (lane >> 4) * 4 + p;
      float v = acc[fm][p];
      size_t o = (size_t)gm * 1024 + gn;
      float c = 0.1f * (a.f1[gm] + a.f2[gn] - 2.f * v) + 0.9f * a.cpp[o];
      if constexpr (EPI == EPI_COST) {
        a.cost[o] = c;
        lred = fmaxf(lred, fabsf(c));
      } else {
        float trec = uni ? UNIF : (a.dinv[gm] * bs) * a.Kf[o];
        lred += c * trec;
      }
    }
  }
  #pragma unroll
  for (int off = 32; off; off >>= 1) {
    float t = __shfl_xor(lred, off, 64);
    lred = (EPI == EPI_COST) ? fmaxf(lred, t) : (lred + t);
  }
  if (lane == 0) red[wv] = lred;
  __syncthreads();
  if (tid == 0) {
    float t = red[0];
    #pragma unroll
    for (int i = 1; i < 8; ++i)
      t = (EPI == EPI_COST) ? fmaxf(t, red[i]) : (t + red[i]);
    if constexpr (EPI == EPI_COST) atomicMax(a.mx, __float_as_uint(t));
    else atomicAdd(a.loss, t);
  }
}

// ---------------------------------------------------------------------------
// kbuild: tran reconstructed from (K_old, dinv, braw_old) bit-identically,
// K_new = exp(-cost/mx)*tran (in place), KT f32 + KTb bf16, braw2 seed.
// ---------------------------------------------------------------------------
__global__ __launch_bounds__(256)
void k_kbuild(const float* cost, const unsigned* mxbits, float* K, float* KT,
              unsigned short* KTb, const float* dinv, const float* brawOld,
              float* braw2, int uniform)
{
  __shared__ float tt[64 * 65];
  __shared__ float dS[64];
  __shared__ float bS[64];
  __shared__ float csum[4][64];
  const int r0 = blockIdx.x * 64, c0 = blockIdx.y * 64;
  const int tid = threadIdx.x;
  const float inv = 1.f / __uint_as_float(*mxbits);
  if (tid < 64) dS[tid] = dinv[r0 + tid];
  else if (tid >= 64 && tid < 128 && !uniform) bS[tid - 64] = PS / brawOld[c0 + tid - 64];
  __syncthreads();
  float colp = 0.f;
  #pragma unroll
  for (int i = 0; i < 16; ++i) {
    int idx = tid + 256 * i;
    int r = idx >> 6, c = idx & 63;
    size_t o = (size_t)(r0 + r) * 1024 + (c0 + c);
    float trec = uniform ? UNIF : (dS[r] * bS[c]) * K[o];
    float v = expf(-cost[o] * inv) * trec;
    K[o] = v;
    tt[r * 65 + c] = v;
    colp += v * dS[r];
  }
  csum[tid >> 6][tid & 63] = colp;
  __syncthreads();
  #pragma unroll
  for (int i = 0; i < 16; ++i) {
    int idx = tid + 256 * i;
    int c = idx >> 6, r = idx & 63;
    float v = tt[r * 65 + c];
    size_t o = (size_t)(c0 + c) * 1024 + (r0 + r);
    KT[o] = v;
    KTb[o] = (unsigned short)f2bf(v);
  }
  if (tid < 64)
    atomicAdd(&braw2[c0 + tid],
              csum[0][tid] + csum[1][tid] + csum[2][tid] + csum[3][tid]);
}

// y_raw[r] = M[r,:].(PS/x_raw); optionally emits invOut = PS/x (last matvec).
__global__ __launch_bounds__(256)
void k_matvec(const float* M, const float* xraw, float* yraw, float* invOut)
{
  const int r = blockIdx.x * 4 + (threadIdx.x >> 6);
  const int lane = threadIdx.x & 63;
  const int wv = threadIdx.x >> 6;
  const f32x4* row = (const f32x4*)(M + (size_t)r * 1024);
  const f32x4* xv  = (const f32x4*)xraw;
  float s = 0.f;
  #pragma unroll
  for (int q = 0; q < 4; ++q) {
    f32x4 a = row[lane + 64 * q];
    f32x4 x = xv [lane + 64 * q];
    f32x4 iv;
    iv.x = PS / x.x; iv.y = PS / x.y; iv.z = PS / x.z; iv.w = PS / x.w;
    if (invOut && blockIdx.x == 0 && wv == 0)
      *(f32x4*)&invOut[4 * (lane + 64 * q)] = iv;
    s += a.x * iv.x + a.y * iv.y + a.z * iv.z + a.w * iv.w;
  }
  #pragma unroll
  for (int o = 32; o; o >>= 1) s += __shfl_xor(s, o, 64);
  if (lane == 0) yraw[r] = s;
}

// NaN scan over reconstructed tran.
__global__ __launch_bounds__(256)
void k_nanscan(const float* K, const float* dinv, const float* braw, unsigned* flag)
{
  unsigned bad = 0;
  const int base = blockIdx.x * 256 + threadIdx.x;
  #pragma unroll
  for (int i = 0; i < 16; ++i) {
    int idx = base + 65536 * i;
    int r = idx >> 10, c = idx & 1023;
    float v = (dinv[r] * (PS / braw[c])) * K[idx];
    if (v != v) bad = 1u;
  }
  if (bad) atomicOr(flag, 1u);
}

// ---------------------------------------------------------------------------
// Distance via MFMA expanded form (verified R5).
// ---------------------------------------------------------------------------
struct DistMMArgs {
  const unsigned short* Fx[3]; const unsigned short* Fy[3];
  const float* nx[3]; const float* ny[3];
  unsigned short* outB[2]; float* outF; float* frow[2];
};
__global__ __launch_bounds__(256)
void k_distmm(DistMMArgs a)
{
  __shared__ short As[64 * 72];
  __shared__ short Bs[64 * 72];
  const int z = blockIdx.y;
  const int bid = blockIdx.x, tid = threadIdx.x;
  const int lane = tid & 63, wv = tid >> 6;
  const int wr = wv & 1, wc = wv >> 1;
  const int m0 = (bid >> 4) * 64, n0 = (bid & 15) * 64;
  const unsigned short* X = a.Fx[z];
  const unsigned short* Y = a.Fy[z];

  f32x4 acc[2][2];
  #pragma unroll
  for (int i = 0; i < 2; ++i)
    #pragma unroll
    for (int j = 0; j < 2; ++j) acc[i][j] = f32x4{0.f, 0.f, 0.f, 0.f};

  #pragma unroll
  for (int kb = 0; kb < 128; kb += 64) {
    #pragma unroll
    for (int i = 0; i < 2; ++i) {
      int idx = tid + 256 * i;
      int r = idx >> 3, q = idx & 7;
      *(s16x8*)&As[r * 72 + 8 * q] = *(const s16x8*)&X[(size_t)(m0 + r) * 128 + kb + 8 * q];
      *(s16x8*)&Bs[r * 72 + 8 * q] = *(const s16x8*)&Y[(size_t)(n0 + r) * 128 + kb + 8 * q];
    }
    __syncthreads();
    #pragma unroll
    for (int s = 0; s < 2; ++s) {
      const int ko = 32 * s + 8 * (lane >> 4);
      bf16x8 a0 = *(const bf16x8*)&As[(wr * 32 +      (lane & 15)) * 72 + ko];
      bf16x8 a1 = *(const bf16x8*)&As[(wr * 32 + 16 + (lane & 15)) * 72 + ko];
      bf16x8 b0 = *(const bf16x8*)&Bs[(wc * 32 +      (lane & 15)) * 72 + ko];
      bf16x8 b1 = *(const bf16x8*)&Bs[(wc * 32 + 16 + (lane & 15)) * 72 + ko];
      acc[0][0] = mfma16(a0, b0, acc[0][0]);
      acc[1][0] = mfma16(a1, b0, acc[1][0]);
      acc[0][1] = mfma16(a0, b1, acc[0][1]);
      acc[1][1] = mfma16(a1, b1, acc[1][1]);
    }
    __syncthreads();
  }

  const float* nxp = a.nx[z];
  const float* nyp = a.ny[z];
  float rp[2][4];
  #pragma unroll
  for (int fm = 0; fm < 2; ++fm)
    #pragma unroll
    for (int p = 0; p < 4; ++p) rp[fm][p] = 0.f;

  #pragma unroll
  for (int fm = 0; fm < 2; ++fm) {
    #pragma unroll
    for (int fn = 0; fn < 2; ++fn) {
      #pragma unroll
      for (int p = 0; p < 4; ++p) {
        int gm = m0 + wr * 32 + fm * 16 + (lane >> 4) * 4 + p;
        int gn = n0 + wc * 32 + fn * 16 + (lane & 15);
        float val = nxp[gm] + nyp[gn] - 2.f * acc[fm][fn][p] + 1e-6f;
        if (z == 2) a.outF[(size_t)gm * 1024 + gn] = val;
        else {
          a.outB[z][(size_t)gm * 1024 + gn] = (unsigned short)f2bf(val);
          rp[fm][p] += val * val;
        }
      }
    }
  }
  if (z < 2) {
    #pragma unroll
    for (int fm = 0; fm < 2; ++fm)
      #pragma unroll
      for (int p = 0; p < 4; ++p) {
        float v = rp[fm][p];
        v += __shfl_xor(v, 1, 64);
        v += __shfl_xor(v, 2, 64);
        v += __shfl_xor(v, 4, 64);
        v += __shfl_xor(v, 8, 64);
        rp[fm][p] = v;
      }
    if ((lane & 15) == 0) {
      #pragma unroll
      for (int fm = 0; fm < 2; ++fm)
        #pragma unroll
        for (int p = 0; p < 4; ++p) {
          int gm = m0 + wr * 32 + fm * 16 + (lane >> 4) * 4 + p;
          atomicAdd(&a.frow[z][gm], rp[fm][p] * (1.f / 1024.f));
        }
    }
  }
}

// ---------------------------------------------------------------------------
// batched transpose (4 weight matrices) + init slice (z==4)
// ---------------------------------------------------------------------------
struct T4 {
  const float* in[4]; unsigned short* out[4]; int R[4], C[4], nx[4], nt[4];
  float* dinv; float* f1; float* f2; unsigned* mx; unsigned* nanflag;
  float* cyc; float* ga; float* gb; float* al;
};
__global__ void k_transpose4(T4 d)
{
  const int z = blockIdx.y;
  const int tid = threadIdx.x;
  if (z == 4) {
    if (blockIdx.x == 0) {
      #pragma unroll
      for (int i = 0; i < 4; ++i) {
        int k = tid + 256 * i;
        d.dinv[k] = PS; d.f1[k] = 0.f; d.f2[k] = 0.f;
      }
      if (tid < 16) d.mx[tid] = 0u;
      if (tid == 0) {
        *d.nanflag = 0u; d.cyc[0] = 0.f; d.cyc[1] = 0.f;
        *d.ga = 0.f; *d.gb = 0.f; *d.al = 0.f;
      }
    }
    return;
  }
  __shared__ float t[64][65];
  const int tile = blockIdx.x;
  if (tile >= d.nt[z]) return;
  const int R = d.R[z], C = d.C[z];
  const int r0 = (tile % d.nx[z]) * 64, c0 = (tile / d.nx[z]) * 64;
  const float* in = d.in[z];
  unsigned short* out = d.out[z];
  #pragma unroll
  for (int i = 0; i < 16; ++i) {
    int idx = tid + 256 * i;
    int r = idx >> 6, c = idx & 63;
    float v = 0.f;
    if ((r0 + r) < R && (c0 + c) < C) v = in[(size_t)(r0 + r) * C + (c0 + c)];
    t[r][c] = v;
  }
  __syncthreads();
  #pragma unroll
  for (int i = 0; i < 16; ++i) {
    int idx = tid + 256 * i;
    int c = idx >> 6, r = idx & 63;
    if ((c0 + c) < C && (r0 + r) < R)
      out[(size_t)(c0 + c) * R + (r0 + r)] = (unsigned short)f2bf(t[r][c]);
  }
}

// Wcomb partial reduce + transpose (64 splits)
__global__ void k_wcomb_reduce(const float* partials, unsigned short* WcTa,
                               unsigned short* WcTb)
{
  __shared__ float t[64][65];
  const int z = blockIdx.z;
  const float* P = partials + (size_t)z * 64 * 256 * 256;
  unsigned short* WcT = z ? WcTb : WcTa;
  const int u0 = blockIdx.x * 64, v0 = blockIdx.y * 64;
  const int tid = threadIdx.x;
  #pragma unroll
  for (int i = 0; i < 16; ++i) {
    int idx = tid + 256 * i;
    int u = idx >> 6, v = idx & 63;
    float s = 0.f;
    for (int p = 0; p < 64; ++p)
      s += P[(size_t)p * 65536 + (u0 + u) * 256 + (v0 + v)];
    t[u][v] = s;
  }
  __syncthreads();
  #pragma unroll
  for (int i = 0; i < 16; ++i) {
    int idx = tid + 256 * i;
    int v = idx >> 6, u = idx & 63;
    WcT[(size_t)(v0 + v) * 256 + (u0 + u)] = (unsigned short)f2bf(t[u][v]);
  }
}

// bc[c] = b4 . Wt1[c,:] + b1[c]
struct BcArgs {
  const float* b4[2]; const unsigned short* Wt1[2]; const float* b1[2];
  float* bc[2]; int K[2];
};
__global__ void k_bcvec(BcArgs a)
{
  const int y = blockIdx.y;
  const int c = blockIdx.x * 4 + (threadIdx.x >> 6);
  const int lane = threadIdx.x & 63;
  const int K = a.K[y];
  const unsigned short* wrow = a.Wt1[y] + (size_t)c * K;
  const float* b4 = a.b4[y];
  float s = 0.f;
  for (int k = lane * 8; k < K; k += 512) {
    s16x8 w = *(const s16x8*)&wrow[k];
    f32x4 v0 = *(const f32x4*)&b4[k];
    f32x4 v1 = *(const f32x4*)&b4[k + 4];
    s += v0.x * bf2f((unsigned short)w[0]) + v0.y * bf2f((unsigned short)w[1])
       + v0.z * bf2f((unsigned short)w[2]) + v0.w * bf2f((unsigned short)w[3])
       + v1.x * bf2f((unsigned short)w[4]) + v1.y * bf2f((unsigned short)w[5])
       + v1.z * bf2f((unsigned short)w[6]) + v1.w * bf2f((unsigned short)w[7]);
  }
  #pragma unroll
  for (int o = 32; o; o >>= 1) s += __shfl_xor(s, o, 64);
  if (lane == 0) a.bc[y][c] = s + a.b1[y][c];
}

// ---------------------------------------------------------------------------
// fused: split-K reduce + relu + enc head + reparam + featprep + GMM KL
// ---------------------------------------------------------------------------
struct EF {
  const float* partials[2]; const float* bias[2];
  const float* W21[2]; const float* b21[2];
  const float* W22[2]; const float* b22[2]; const float* eps[2];
  const float* pmu[2]; const float* plv[2]; float* gmmO[2];
  float* mu[2]; float* lv[2]; float* zO[2];
  unsigned short* F[2]; float* n[2];
};
__global__ __launch_bounds__(256)
void k_enc_fused(EF a)
{
  __shared__ float hrow[256];
  __shared__ float res[128];
  const int y = blockIdx.y;
  const int i = blockIdx.x;
  const int t = threadIdx.x;
  {
    float s = a.bias[y][t];
    const float* P = a.partials[y] + (size_t)i * 256 + t;
    #pragma unroll
    for (int p = 0; p < 16; ++p) s += P[(size_t)p * 262144];
    hrow[t] = fmaxf(s, 0.f);
  }
  __syncthreads();
  if (t < 128) {
    const int c = t & 63;
    const float* W = (t < 64) ? a.W21[y] : a.W22[y];
    float acc = (t < 64) ? a.b21[y][c] : a.b22[y][c];
    #pragma unroll 8
    for (int j = 0; j < 256; ++j) acc += hrow[j] * W[j * 64 + c];
    res[t] = acc;
  }
  __syncthreads();
  if (t < 64) {
    float mu = res[t], lv = res[64 + t];
    a.mu[y][(size_t)i * 64 + t] = mu;
    a.lv[y][(size_t)i * 64 + t] = lv;
    float sig = expf(0.5f * lv);
    float zd = mu + a.eps[y][(size_t)i * 64 + t] * sig;
    a.zO[y][(size_t)i * 64 + t] = zd;
    unsigned short u0 = (unsigned short)f2bf(mu);
    unsigned short u1 = (unsigned short)f2bf(sig);
    unsigned short* Fr = a.F[y] + (size_t)i * 128;
    Fr[t] = u0;
    Fr[64 + t] = u1;
    float r0 = bf2f(u0), r1 = bf2f(u1);
    float p = r0 * r0 + r1 * r1;
    #pragma unroll
    for (int o = 32; o; o >>= 1) p += __shfl_xor(p, o, 64);
    if (t == 0) a.n[y][i] = p;
    // ---- GMM KL (fused)
    float tq = lv + (zd - mu) * (zd - mu) * expf(-lv);
    #pragma unroll
    for (int o = 32; o; o >>= 1) tq += __shfl_xor(tq, o, 64);
    const float C0 = 64.f * 1.8378770664093453f;
    float logq = -0.5f * (C0 + tq);
    float lp[20];
    #pragma unroll
    for (int k = 0; k < 20; ++k) {
      float pm = a.pmu[y][k * 64 + t], pl = a.plv[y][k * 64 + t];
      float u = pl + (zd - pm) * (zd - pm) * expf(-pl);
      #pragma unroll
      for (int o = 32; o; o >>= 1) u += __shfl_xor(u, o, 64);
      lp[k] = -0.5f * (C0 + u);
    }
    float mxv = lp[0];
    #pragma unroll
    for (int k = 1; k < 20; ++k) mxv = fmaxf(mxv, lp[k]);
    float se = 0.f;
    #pragma unroll
    for (int k = 0; k < 20; ++k) se += expf(lp[k] - mxv);
    float logp = mxv + logf(se) - 2.9957322735539909f;
    if (t == 0) atomicAdd(a.gmmO[y], logq - logp);
  }
}

// fused re-encode + cycle-loss partial
struct RencArgs {
  const float* hd[2]; const unsigned short* WcT[2]; const float* bc[2];
  const float* W21[2]; const float* b21[2]; const float* W22[2]; const float* b22[2];
  const float* eps[2]; float* fout[2];
  const float* zin[2]; float* cyc;
};
__global__ void k_renc_head(RencArgs a)
{
  __shared__ float hdrow[256];
  __shared__ float hr[256];
  __shared__ float res[128];
  const int y = blockIdx.y;
  const int i = blockIdx.x;
  const int t = threadIdx.x;                  // 256
  hdrow[t] = a.hd[y][(size_t)i * 256 + t];
  __syncthreads();
  {
    const s16x8* wr = (const s16x8*)(a.WcT[y] + (size_t)t * 256);
    float s = a.bc[y][t];
    #pragma unroll 4
    for (int j = 0; j < 32; ++j) {
      s16x8 w = wr[j];
      const float* hp = &hdrow[j * 8];
      s += hp[0] * bf2f((unsigned short)w[0]) + hp[1] * bf2f((unsigned short)w[1])
         + hp[2] * bf2f((unsigned short)w[2]) + hp[3] * bf2f((unsigned short)w[3])
         + hp[4] * bf2f((unsigned short)w[4]) + hp[5] * bf2f((unsigned short)w[5])
         + hp[6] * bf2f((unsigned short)w[6]) + hp[7] * bf2f((unsigned short)w[7]);
    }
    hr[t] = fmaxf(s, 0.f);
  }
  __syncthreads();
  if (t < 128) {
    const int c = t & 63;
    const float* W = (t < 64) ? a.W21[y] : a.W22[y];
    float acc = (t < 64) ? a.b21[y][c] : a.b22[y][c];
    #pragma unroll 8
    for (int j = 0; j < 256; ++j) acc += hr[j] * W[j * 64 + c];
    res[t] = acc;
  }
  __syncthreads();
  if (t < 64) {
    float mu = res[t], lv = res[64 + t];
    float f = mu + a.eps[y][(size_t)i * 64 + t] * expf(0.5f * lv);
    a.fout[y][(size_t)i * 64 + t] = f;
    float d = a.zin[y][(size_t)i * 64 + t] - f;
    d = d * d;
    #pragma unroll
    for (int o = 32; o; o >>= 1) d += __shfl_xor(d, o, 64);
    if (t == 0) atomicAdd(a.cyc + y, d);
  }
}

// batched decoder heads
struct DH4 { const float* z[4]; const float* W3[4]; const float* b3[4]; float* hd[4]; };
__global__ void k_dec_head4(DH4 a)
{
  __shared__ float zrow[64];
  const int y = blockIdx.y;
  const int i = blockIdx.x;
  const int t = threadIdx.x;                  // 256
  if (t < 64) zrow[t] = a.z[y][(size_t)i * 64 + t];
  __syncthreads();
  const float* W3 = a.W3[y];
  float acc = a.b3[y][t];
  #pragma unroll
  for (int d = 0; d < 64; ++d) acc += zrow[d] * W3[d * 256 + t];
  a.hd[y][(size_t)i * 256 + t] = fmaxf(acc, 0.f);
}

__global__ void k_finish(const float* slots, float* o1, float* o2)
{
  if (threadIdx.x == 0) { *o1 = sqrtf(slots[0]); *o2 = sqrtf(slots[1]); }
}

// ---------------------------------------------------------------------------
extern "C" void kernel_launch(void* const* d_in, const int* in_sizes, int n_in,
                              void* d_out, int out_size, void* d_ws, size_t ws_size,
                              hipStream_t stream)
{
  (void)in_sizes; (void)n_in; (void)out_size; (void)ws_size;

  const float* X     = (const float*)d_in[2];
  const float* Y     = (const float*)d_in[3];
  const float* pmua  = (const float*)d_in[4];
  const float* plva  = (const float*)d_in[5];
  const float* pmub  = (const float*)d_in[6];
  const float* plvb  = (const float*)d_in[7];
  const float* epsx  = (const float*)d_in[8];
  const float* epsy  = (const float*)d_in[9];
  const float* epsxr = (const float*)d_in[10];
  const float* epsyr = (const float*)d_in[11];
  const float* W1a = (const float*)d_in[12];  const float* b1a = (const float*)d_in[13];
  const float* W21a= (const float*)d_in[14];  const float* b21a= (const float*)d_in[15];
  const float* W22a= (const float*)d_in[16];  const float* b22a= (const float*)d_in[17];
  const float* W3a = (const float*)d_in[18];  const float* b3a = (const float*)d_in[19];
  const float* W4a = (const float*)d_in[20];  const float* b4a = (const float*)d_in[21];
  const float* W1b = (const float*)d_in[22];  const float* b1b = (const float*)d_in[23];
  const float* W21b= (const float*)d_in[24];  const float* b21b= (const float*)d_in[25];
  const float* W22b= (const float*)d_in[26];  const float* b22b= (const float*)d_in[27];
  const float* W3b = (const float*)d_in[28];  const float* b3b = (const float*)d_in[29];
  const float* W4b = (const float*)d_in[30];  const float* b4b = (const float*)d_in[31];

  float* out = (float*)d_out;
  const size_t P_X = 0, P_Y = 20480000, P_X2Y = 46080000, P_Y2X = 71680000;
  const size_t Z_X = 92160000, Z_Y = 92225536;
  const size_t GMM_A = 92291072, GMM_B = 92291073;
  const size_t F_XR = 92291074, F_YR = 92356610;
  const size_t ALIGN = 92422146, CYC_X = 92422147, CYC_Y = 92422148;

  // ---- workspace carve
  char* w = (char*)d_ws;
  size_t off = 0;
  auto alloc = [&](size_t bytes) -> void* {
    void* p = w + off;
    off += (bytes + 255) & ~(size_t)255;
    return p;
  };
  unsigned short* Wt1a = (unsigned short*)alloc((size_t)256 * 20000 * 2);
  unsigned short* Wt1b = (unsigned short*)alloc((size_t)256 * 25000 * 2);
  unsigned short* W4ta = (unsigned short*)alloc((size_t)20000 * 256 * 2);
  unsigned short* W4tb = (unsigned short*)alloc((size_t)25000 * 256 * 2);
  unsigned short* WcTa = (unsigned short*)alloc((size_t)256 * 256 * 2);
  unsigned short* WcTb = (unsigned short*)alloc((size_t)256 * 256 * 2);
  float* bca  = (float*)alloc(256 * 4);
  float* bcb  = (float*)alloc(256 * 4);
  float* mu_a = (float*)alloc(1024 * 64 * 4);
  float* lv_a = (float*)alloc(1024 * 64 * 4);
  float* mu_b = (float*)alloc(1024 * 64 * 4);
  float* lv_b = (float*)alloc(1024 * 64 * 4);
  float* f1   = (float*)alloc(1024 * 4);
  float* f2   = (float*)alloc(1024 * 4);
  unsigned* mx      = (unsigned*)alloc(16 * 4);
  unsigned* nanflag = (unsigned*)alloc(256);
  float* cyc  = (float*)alloc(256);
  float* draw = (float*)alloc(1024 * 4);
  float* braw = (float*)alloc(1024 * 4);
  float* braw2 = (float*)alloc(1024 * 4);
  float* dinv = (float*)alloc(1024 * 4);
  unsigned short* Fb = (unsigned short*)alloc((size_t)1024 * 128 * 2);
  unsigned short* Fa = (unsigned short*)alloc((size_t)1024 * 128 * 2);
  float* nb = (float*)alloc(1024 * 4);
  float* na = (float*)alloc(1024 * 4);
  char* arena = (char*)alloc((size_t)32 * 1024 * 1024);
  float* partials = (float*)arena;
  size_t ao = 0;
  auto aalloc = [&](size_t bytes) -> void* {
    void* p = arena + ao;
    ao += (bytes + 255) & ~(size_t)255;
    return p;
  };
  unsigned short* cpostB  = (unsigned short*)aalloc((size_t)1024 * 1024 * 2);
  unsigned short* cpriorB = (unsigned short*)aalloc((size_t)1024 * 1024 * 2);
  float* cpp  = (float*)aalloc((size_t)1024 * 1024 * 4);
  unsigned short* Umat  = (unsigned short*)aalloc((size_t)1024 * 1024 * 2);
  float* cost  = (float*)aalloc((size_t)1024 * 1024 * 4);
  float* Kmat  = (float*)aalloc((size_t)1024 * 1024 * 4);
  float* KTmat = (float*)aalloc((size_t)1024 * 1024 * 4);
  unsigned short* KTb = (unsigned short*)aalloc((size_t)1024 * 1024 * 2);
  float* hd0 = (float*)(arena);
  float* hd1 = (float*)(arena + (size_t)1024 * 256 * 4);
  float* hd2 = (float*)(arena + (size_t)2 * 1024 * 256 * 4);
  float* hd3 = (float*)(arena + (size_t)3 * 1024 * 256 * 4);

  // ---- 1. weight transposes + init (z=4)
  {
    T4 d{};
    d.in[0] = W1a; d.out[0] = Wt1a; d.R[0] = 20000; d.C[0] = 256;
    d.in[1] = W1b; d.out[1] = Wt1b; d.R[1] = 25000; d.C[1] = 256;
    d.in[2] = W4a; d.out[2] = W4ta; d.R[2] = 256;   d.C[2] = 20000;
    d.in[3] = W4b; d.out[3] = W4tb; d.R[3] = 256;   d.C[3] = 25000;
    for (int z = 0; z < 4; ++z) {
      d.nx[z] = (d.R[z] + 63) / 64;
      d.nt[z] = d.nx[z] * ((d.C[z] + 63) / 64);
    }
    d.dinv = dinv; d.f1 = f1; d.f2 = f2; d.mx = mx; d.nanflag = nanflag;
    d.cyc = cyc; d.ga = out + GMM_A; d.gb = out + GMM_B; d.al = out + ALIGN;
    k_transpose4<<<dim3(1564, 5), 256, 0, stream>>>(d);
  }

  // ---- 2. Wcomb = W4 @ W1 -> WcT bf16 + combined bias (64 splits, grid 256)
  {
    Q4 q{};
    q.g[0].Af = W4a; q.g[0].Bt = Wt1a; q.g[0].partials = partials;
    q.g[0].M = 256; q.g[0].N = 256; q.g[0].K = 20000;
    q.g[0].lda = 20000; q.g[0].ldbt = 20000;
    q.g[0].totSteps = 313; q.g[0].nSplits = 64;
    q.g[1] = q.g[0];
    q.g[1].Af = W4b; q.g[1].Bt = Wt1b;
    q.g[1].partials = partials + (size_t)64 * 65536;
    q.g[1].K = 25000; q.g[1].lda = 25000; q.g[1].ldbt = 25000; q.g[1].totSteps = 391;
    k_gemmN<128, 256, 4, 4, EPI_PARTIAL><<<dim3(2, 64, 2), 1024, 0, stream>>>(q);
    k_wcomb_reduce<<<dim3(4, 4, 2), 256, 0, stream>>>(partials, WcTa, WcTb);
    BcArgs bc{};
    bc.b4[0] = b4a; bc.Wt1[0] = Wt1a; bc.b1[0] = b1a; bc.bc[0] = bca; bc.K[0] = 20000;
    bc.b4[1] = b4b; bc.Wt1[1] = Wt1b; bc.b1[1] = b1b; bc.bc[1] = bcb; bc.K[1] = 25000;
    k_bcvec<<<dim3(64, 2), 256, 0, stream>>>(bc);
  }

  // ---- 3. encoders (batched GEMM + fused reduce/head/featprep/GMM)
  {
    Q4 q{};
    q.g[0].Af = X; q.g[0].Bt = Wt1a; q.g[0].partials = partials;
    q.g[0].M = 1024; q.g[0].N = 256; q.g[0].K = 20000;
    q.g[0].lda = 20000; q.g[0].ldbt = 20000;
    q.g[0].totSteps = 313; q.g[0].nSplits = 16;
    q.g[1] = q.g[0];
    q.g[1].Af = Y; q.g[1].Bt = Wt1b;
    q.g[1].partials = partials + (size_t)16 * 1024 * 256;
    q.g[1].K = 25000; q.g[1].lda = 25000; q.g[1].ldbt = 25000; q.g[1].totSteps = 391;
    k_gemmN<128, 256, 4, 4, EPI_PARTIAL><<<dim3(8, 16, 2), 1024, 0, stream>>>(q);
    EF e{};
    e.partials[0] = partials; e.partials[1] = partials + (size_t)16 * 1024 * 256;
    e.bias[0] = b1a; e.bias[1] = b1b;
    e.W21[0] = W21a; e.b21[0] = b21a; e.W22[0] = W22a; e.b22[0] = b22a;
    e.eps[0] = epsx; e.mu[0] = mu_a; e.lv[0] = lv_a; e.zO[0] = out + Z_X;
    e.F[0] = Fa; e.n[0] = na;
    e.pmu[0] = pmua; e.plv[0] = plva; e.gmmO[0] = out + GMM_A;
    e.W21[1] = W21b; e.b21[1] = b21b; e.W22[1] = W22b; e.b22[1] = b22b;
    e.eps[1] = epsy; e.mu[1] = mu_b; e.lv[1] = lv_b; e.zO[1] = out + Z_Y;
    e.F[1] = Fb; e.n[1] = nb;
    e.pmu[1] = pmub; e.plv[1] = plvb; e.gmmO[1] = out + GMM_B;
    k_enc_fused<<<dim3(1024, 2), 256, 0, stream>>>(e);
  }

  // ---- 4. FGW(mu_b, mu_a, lv_b, lv_a)
  {
    DistMMArgs dm{};
    dm.Fx[0] = Fb; dm.Fy[0] = Fb; dm.nx[0] = nb; dm.ny[0] = nb;
    dm.Fx[1] = Fa; dm.Fy[1] = Fa; dm.nx[1] = na; dm.ny[1] = na;
    dm.Fx[2] = Fb; dm.Fy[2] = Fa; dm.nx[2] = nb; dm.ny[2] = na;
    dm.outB[0] = cpostB; dm.outB[1] = cpriorB; dm.outF = cpp;
    dm.frow[0] = f1; dm.frow[1] = f2;
    k_distmm<<<dim3(256, 3), 256, 0, stream>>>(dm);
  }
  G1Args g1{};
  g1.A = cpostB; g1.KTb = KTb; g1.dinv = dinv; g1.braw = braw;
  g1.U = Umat; g1.nflag = nanflag;
  FgwGemmArgs fg{};
  fg.A = Umat; fg.Bt = cpriorB;
  fg.f1 = f1; fg.f2 = f2; fg.cpp = cpp; fg.cost = cost;
  fg.loss = out + ALIGN; fg.braw2 = braw2;
  fg.Kf = Kmat; fg.dinv = dinv; fg.brawv = braw; fg.nflag = nanflag;
  for (int it = 0; it < 10; ++it) {
    g1.mode = (it == 0) ? 0 : 1;
    k_fgw_g1<<<256, 512, 0, stream>>>(g1);
    fg.mx = mx + it;
    k_fgw_gemm<EPI_COST><<<256, 512, 0, stream>>>(fg);
    k_kbuild<<<dim3(16, 16), 256, 0, stream>>>(cost, mx + it, Kmat, KTmat, KTb,
                                               dinv, braw, braw2, it == 0 ? 1 : 0);
    for (int r = 0; r < 5; ++r) {
      k_matvec<<<256, 256, 0, stream>>>(Kmat, r == 0 ? braw2 : braw, draw, nullptr);
      k_matvec<<<256, 256, 0, stream>>>(KTmat, draw, braw, r == 4 ? dinv : nullptr);
    }
  }
  k_nanscan<<<256, 256, 0, stream>>>(Kmat, dinv, braw, nanflag);
  g1.mode = 2;
  k_fgw_g1<<<256, 512, 0, stream>>>(g1);
  k_fgw_gemm<EPI_LOSS><<<256, 512, 0, stream>>>(fg);

  // ---- 5. decoder heads
  {
    DH4 d{};
    d.z[0] = out + Z_X; d.W3[0] = W3a; d.b3[0] = b3a; d.hd[0] = hd0;   // P_X
    d.z[1] = out + Z_Y; d.W3[1] = W3a; d.b3[1] = b3a; d.hd[1] = hd1;   // P_Y2X
    d.z[2] = out + Z_Y; d.W3[2] = W3b; d.b3[2] = b3b; d.hd[2] = hd2;   // P_Y
    d.z[3] = out + Z_X; d.W3[3] = W3b; d.b3[3] = b3b; d.hd[3] = hd3;   // P_X2Y
    k_dec_head4<<<dim3(1024, 4), 256, 0, stream>>>(d);
  }

  // ---- 6. fused re-encoders (+cycle partials)
  {
    RencArgs r{};
    r.hd[0] = hd3; r.WcT[0] = WcTb; r.bc[0] = bcb;                     // enc_b(dec_b(z_x))
    r.W21[0] = W21b; r.b21[0] = b21b; r.W22[0] = W22b; r.b22[0] = b22b;
    r.eps[0] = epsxr; r.fout[0] = out + F_XR; r.zin[0] = out + Z_X;
    r.hd[1] = hd1; r.WcT[1] = WcTa; r.bc[1] = bca;                     // enc_a(dec_a(z_y))
    r.W21[1] = W21a; r.b21[1] = b21a; r.W22[1] = W22a; r.b22[1] = b22a;
    r.eps[1] = epsyr; r.fout[1] = out + F_YR; r.zin[1] = out + Z_Y;
    r.cyc = cyc;
    k_renc_head<<<dim3(1024, 2), 256, 0, stream>>>(r);
  }
  k_finish<<<1, 64, 0, stream>>>(cyc, out + CYC_X, out + CYC_Y);

  // ---- 7. decoder GEMMs (one launch, z=0..3, coalesced LDS-bounce stores)
  {
    Q4 q{};
    q.g[0].Af = hd0; q.g[0].Bt = W4ta; q.g[0].outF = out + P_X; q.g[0].bias = b4a;
    q.g[0].M = 1024; q.g[0].N = 20000; q.g[0].K = 256;
    q.g[0].lda = 256; q.g[0].ldbt = 256; q.g[0].ldc = 20000;
    q.g[1] = q.g[0]; q.g[1].Af = hd1; q.g[1].outF = out + P_Y2X;
    q.g[2] = q.g[0];
    q.g[2].Af = hd2; q.g[2].Bt = W4tb; q.g[2].outF = out + P_Y; q.g[2].bias = b4b;
    q.g[2].N = 25000; q.g[2].ldc = 25000;
    q.g[3] = q.g[2]; q.g[3].Af = hd3; q.g[3].outF = out + P_X2Y;
    k_gemmN<128, 128, 4, 2, EPI_BIAS><<<dim3(8, 196, 4), 512, 0, stream>>>(q);
  }
}

// Round 12
// 1338.717 us; speedup vs baseline: 1.3012x; 1.0415x over previous
//
#include <hip/hip_runtime.h>

// ============================================================================
// MUCRP_17265768530653 — cross-domain VAE forward on MI355X (gfx950)
// Round 12 (R11 base):
//  - sinkhorn matvecs read bf16 (Kb/KTb); kbuild drops the f32 KT write
//    (-4MB/iter) and emits Kb bf16 (+2MB). draw/braw shift ~0.2% (used
//    consistently everywhere; threshold margin ~1000x). K stays f32 for the
//    tran-reconstruction feedback.
// ============================================================================

#define DEVI __device__ __forceinline__

typedef __attribute__((ext_vector_type(4))) float  f32x4;
typedef __attribute__((ext_vector_type(4))) short  s16x4;
typedef __attribute__((ext_vector_type(8))) short  s16x8;
typedef __attribute__((ext_vector_type(8))) __bf16 bf16x8;

#define PS (1.f / 1024.f)
#define UNIF (1.f / (1024.f * 1024.f))

DEVI short f2bf(float f) {              // RNE f32 -> bf16 (bits)
  unsigned u = __float_as_uint(f);
  u += 0x7fffu + ((u >> 16) & 1u);
  return (short)(u >> 16);
}
DEVI float bf2f(unsigned short u) { return __uint_as_float(((unsigned)u) << 16); }

DEVI f32x4 mfma16(bf16x8 a, bf16x8 b, f32x4 c) {
  return __builtin_amdgcn_mfma_f32_16x16x32_bf16(a, b, c, 0, 0, 0);
}

// ---------------------------------------------------------------------------
// Generic tiled MFMA GEMM body (verified R1-R11).
// ---------------------------------------------------------------------------
struct GemmArgs {
  const float* Af;
  const unsigned short* Bt;
  float* outF;
  const float* bias;
  float* partials;
  int M, N, K;
  int lda, ldbt, ldc;
  int totSteps, nSplits;
};

enum { EPI_PARTIAL, EPI_BIAS, EPI_COST, EPI_LOSS };

template<int BM, int BN, int WR, int WC, int EPI>
DEVI void gemm_body(const GemmArgs g)
{
  constexpr int BK = 64, BKP = 72;
  constexpr int NT = WR * WC * 64;
  __shared__ short SM[(BM + BN) * BKP];
  short* As = SM;
  short* Bs = SM + BM * BKP;

  const int m0 = blockIdx.x * BM;
  int n0 = 0, kb0 = 0, kb1 = g.K, split = 0;
  if constexpr (EPI == EPI_PARTIAL) {
    split = blockIdx.y;
    int s0 = (split * g.totSteps) / g.nSplits;
    int s1 = ((split + 1) * g.totSteps) / g.nSplits;
    kb0 = s0 * BK;
    kb1 = s1 * BK; if (kb1 > g.K) kb1 = g.K;
  } else {
    n0 = blockIdx.y * BN;
  }
  const int tid  = threadIdx.x;
  const int lane = tid & 63;
  const int wv   = tid >> 6;
  const int wr   = wv % WR;
  const int wc   = wv / WR;

  f32x4 acc[2][4];
  #pragma unroll
  for (int i = 0; i < 2; ++i)
    #pragma unroll
    for (int j = 0; j < 4; ++j) acc[i][j] = f32x4{0.f, 0.f, 0.f, 0.f};

  for (int kb = kb0; kb < kb1; kb += BK) {
    {   // stage A (f32 -> bf16)
      constexpr int NV = BM * BK / 4;
      #pragma unroll
      for (int i = 0; i < NV / NT; ++i) {
        int idx = tid + NT * i;
        int r = idx >> 4, q = idx & 15;
        int k = kb + 4 * q;
        f32x4 v = f32x4{0.f, 0.f, 0.f, 0.f};
        if (k < kb1) v = *(const f32x4*)(g.Af + (size_t)(m0 + r) * g.lda + k);
        s16x4 s;
        s.x = f2bf(v.x); s.y = f2bf(v.y); s.z = f2bf(v.z); s.w = f2bf(v.w);
        *(s16x4*)&As[r * BKP + 4 * q] = s;
      }
    }
    {   // stage B (bf16 [N][K])
      constexpr int NV = BN * BK / 8;
      #pragma unroll
      for (int i = 0; i < NV / NT; ++i) {
        int idx = tid + NT * i;
        int r = idx >> 3, q = idx & 7;
        int k = kb + 8 * q;
        s16x8 v{};
        if ((n0 + r) < g.N && k < kb1)
          v = *(const s16x8*)(g.Bt + (size_t)(n0 + r) * g.ldbt + k);
        *(s16x8*)&Bs[r * BKP + 8 * q] = v;
      }
    }
    __syncthreads();
    #pragma unroll
    for (int s = 0; s < 2; ++s) {
      const int ko = 32 * s + 8 * (lane >> 4);
      bf16x8 a0 = *(const bf16x8*)&As[(wr * 32 +      (lane & 15)) * BKP + ko];
      bf16x8 a1 = *(const bf16x8*)&As[(wr * 32 + 16 + (lane & 15)) * BKP + ko];
      #pragma unroll
      for (int fn = 0; fn < 4; ++fn) {
        bf16x8 b = *(const bf16x8*)&Bs[(wc * 64 + fn * 16 + (lane & 15)) * BKP + ko];
        acc[0][fn] = mfma16(a0, b, acc[0][fn]);
        acc[1][fn] = mfma16(a1, b, acc[1][fn]);
      }
    }
    __syncthreads();
  }

  if constexpr (EPI == EPI_PARTIAL) {
    #pragma unroll
    for (int fm = 0; fm < 2; ++fm) {
      #pragma unroll
      for (int fn = 0; fn < 4; ++fn) {
        #pragma unroll
        for (int p = 0; p < 4; ++p) {
          int gm = m0 + wr * 32 + fm * 16 + (lane >> 4) * 4 + p;
          int gn = n0 + wc * 64 + fn * 16 + (lane & 15);
          g.partials[((size_t)split * g.M + gm) * 256 + gn] = acc[fm][fn][p];
        }
      }
    }
  } else {
    // LDS-bounce: stage each 64-col half, store lane-contiguous float4 (+bias)
    float* Cs = (float*)SM;
    #pragma unroll
    for (int h = 0; h < WC; ++h) {
      __syncthreads();
      if (wc == h) {
        #pragma unroll
        for (int fm = 0; fm < 2; ++fm)
          #pragma unroll
          for (int fn = 0; fn < 4; ++fn)
            #pragma unroll
            for (int p = 0; p < 4; ++p)
              Cs[(wr * 32 + fm * 16 + (lane >> 4) * 4 + p) * 65
                 + fn * 16 + (lane & 15)] = acc[fm][fn][p];
      }
      __syncthreads();
      const int n0h = n0 + 64 * h;
      #pragma unroll
      for (int j = tid; j < BM * 16; j += NT) {
        int r = j >> 4, c4 = j & 15;
        int gn = n0h + 4 * c4;
        if (gn < g.N) {
          f32x4 v = *(f32x4*)&Cs[r * 65 + 4 * c4];
          f32x4 b = *(const f32x4*)&g.bias[gn];
          v.x += b.x; v.y += b.y; v.z += b.z; v.w += b.w;
          *(f32x4*)(g.outF + (size_t)(m0 + r) * g.ldc + gn) = v;
        }
      }
    }
  }
}

struct Q4 { GemmArgs g[4]; };

template<int BM, int BN, int WR, int WC, int EPI>
__global__ __launch_bounds__(WR*WC*64)
void k_gemmN(Q4 q)
{
  GemmArgs g = q.g[blockIdx.z];
  if constexpr (EPI == EPI_BIAS) {
    if ((int)(blockIdx.y * BN) >= g.N) return;
  }
  gemm_body<BM, BN, WR, WC, EPI>(g);
}

// ---------------------------------------------------------------------------
// FGW GEMM1': U[m][n] = bscale * sum_k bf16(cpost[m][k]*dinv[k]) * KTb[n][k]
// 64x64 tile, 8 waves (2x4, wave tile 32x16), 256 blocks.
// ---------------------------------------------------------------------------
struct G1Args {
  const unsigned short* A;
  const unsigned short* KTb;
  const float* dinv;
  const float* braw;
  unsigned short* U;
  const unsigned* nflag;
  int mode;   // 0: uniform  1: factors  2: factors unless nanflag
};

__global__ __launch_bounds__(512)
void k_fgw_g1(G1Args a)
{
  __shared__ short As[64 * 72];
  __shared__ short Bs[64 * 72];
  const bool uni = (a.mode == 0) || (a.mode == 2 && *a.nflag != 0u);

  const int bid = blockIdx.x, tid = threadIdx.x;
  const int lane = tid & 63, wv = tid >> 6;
  const int wr = wv & 1, wc = wv >> 1;          // 2x4 waves, 32x16 each
  const int m0 = (bid >> 4) * 64, n0 = (bid & 15) * 64;

  f32x4 acc[2];
  acc[0] = f32x4{0.f, 0.f, 0.f, 0.f};
  acc[1] = f32x4{0.f, 0.f, 0.f, 0.f};

  const short ub = f2bf(UNIF);

  for (int kb = 0; kb < 1024; kb += 64) {
    {
      int r = tid >> 3, q = tid & 7;
      s16x8 av = *(const s16x8*)&a.A[(size_t)(m0 + r) * 1024 + kb + 8 * q];
      if (!uni) {
        f32x4 d0 = *(const f32x4*)&a.dinv[kb + 8 * q];
        f32x4 d1 = *(const f32x4*)&a.dinv[kb + 8 * q + 4];
        s16x8 o;
        o[0] = f2bf(bf2f((unsigned short)av[0]) * d0.x);
        o[1] = f2bf(bf2f((unsigned short)av[1]) * d0.y);
        o[2] = f2bf(bf2f((unsigned short)av[2]) * d0.z);
        o[3] = f2bf(bf2f((unsigned short)av[3]) * d0.w);
        o[4] = f2bf(bf2f((unsigned short)av[4]) * d1.x);
        o[5] = f2bf(bf2f((unsigned short)av[5]) * d1.y);
        o[6] = f2bf(bf2f((unsigned short)av[6]) * d1.z);
        o[7] = f2bf(bf2f((unsigned short)av[7]) * d1.w);
        av = o;
      }
      *(s16x8*)&As[r * 72 + 8 * q] = av;
      s16x8 bv;
      if (uni) {
        #pragma unroll
        for (int j = 0; j < 8; ++j) bv[j] = ub;
      } else {
        bv = *(const s16x8*)&a.KTb[(size_t)(n0 + r) * 1024 + kb + 8 * q];
      }
      *(s16x8*)&Bs[r * 72 + 8 * q] = bv;
    }
    __syncthreads();
    #pragma unroll
    for (int s = 0; s < 2; ++s) {
      const int ko = 32 * s + 8 * (lane >> 4);
      bf16x8 b0 = *(const bf16x8*)&Bs[(wc * 16 + (lane & 15)) * 72 + ko];
      bf16x8 a0 = *(const bf16x8*)&As[(wr * 32 +      (lane & 15)) * 72 + ko];
      bf16x8 a1 = *(const bf16x8*)&As[(wr * 32 + 16 + (lane & 15)) * 72 + ko];
      acc[0] = mfma16(a0, b0, acc[0]);
      acc[1] = mfma16(a1, b0, acc[1]);
    }
    __syncthreads();
  }

  const int gn = n0 + wc * 16 + (lane & 15);
  const float bs = uni ? 1.f : (PS / a.braw[gn]);
  #pragma unroll
  for (int fm = 0; fm < 2; ++fm) {
    #pragma unroll
    for (int p = 0; p < 4; ++p) {
      int gm = m0 + wr * 32 + fm * 16 + (lane >> 4) * 4 + p;
      float v = acc[fm][p];
      a.U[(size_t)gm * 1024 + gn] = (unsigned short)f2bf(uni ? v : bs * v);
    }
  }
}

// ---------------------------------------------------------------------------
// FGW GEMM (COST / LOSS), 64x64 tile, 8 waves, 256 blocks.
// ---------------------------------------------------------------------------
struct FgwGemmArgs {
  const unsigned short* A;
  const unsigned short* Bt;
  float* cost;
  const float* f1;
  const float* f2;
  const float* cpp;
  unsigned* mx;
  float* loss;
  float* braw2;
  const float* Kf;
  const float* dinv;
  const float* brawv;
  const unsigned* nflag;
};

template<int EPI>
__global__ __launch_bounds__(512)
void k_fgw_gemm(FgwGemmArgs a)
{
  __shared__ short As[64 * 72];
  __shared__ short Bs[64 * 72];
  __shared__ float red[8];

  const int bid = blockIdx.x, tid = threadIdx.x;
  const int lane = tid & 63, wv = tid >> 6;
  const int wr = wv & 1, wc = wv >> 1;
  const int m0 = (bid >> 4) * 64, n0 = (bid & 15) * 64;

  if constexpr (EPI == EPI_COST) {
    if (bid == 0) {
      #pragma unroll
      for (int i = 0; i < 2; ++i) a.braw2[tid + 512 * i] = 0.f;
    }
  }

  f32x4 acc[2];
  acc[0] = f32x4{0.f, 0.f, 0.f, 0.f};
  acc[1] = f32x4{0.f, 0.f, 0.f, 0.f};

  for (int kb = 0; kb < 1024; kb += 64) {
    {
      int r = tid >> 3, q = tid & 7;
      *(s16x8*)&As[r * 72 + 8 * q] = *(const s16x8*)&a.A [(size_t)(m0 + r) * 1024 + kb + 8 * q];
      *(s16x8*)&Bs[r * 72 + 8 * q] = *(const s16x8*)&a.Bt[(size_t)(n0 + r) * 1024 + kb + 8 * q];
    }
    __syncthreads();
    #pragma unroll
    for (int s = 0; s < 2; ++s) {
      const int ko = 32 * s + 8 * (lane >> 4);
      bf16x8 b0 = *(const bf16x8*)&Bs[(wc * 16 + (lane & 15)) * 72 + ko];
      bf16x8 a0 = *(const bf16x8*)&As[(wr * 32 +      (lane & 15)) * 72 + ko];
      bf16x8 a1 = *(const bf16x8*)&As[(wr * 32 + 16 + (lane & 15)) * 72 + ko];
      acc[0] = mfma16(a0, b0, acc[0]);
      acc[1] = mfma16(a1, b0, acc[1]);
    }
    __syncthreads();
  }

  bool uni = false;
  if constexpr (EPI == EPI_LOSS) uni = (*a.nflag != 0u);

  const int gn = n0 + wc * 16 + (lane & 15);
  float bs = 0.f;
  if constexpr (EPI == EPI_LOSS) bs = uni ? 0.f : (PS / a.brawv[gn]);

  float lred = 0.f;
  #pragma unroll
  for (int fm = 0; fm < 2; ++fm) {
    #pragma unroll
    for (int p = 0; p < 4; ++p) {
      int gm = m0 + wr * 32 + fm * 16 + (lane >> 4) * 4 + p;
      float v = acc[fm][p];
      size_t o = (size_t)gm * 1024 + gn;
      float c = 0.1f * (a.f1[gm] + a.f2[gn] - 2.f * v) + 0.9f * a.cpp[o];
      if constexpr (EPI == EPI_COST) {
        a.cost[o] = c;
        lred = fmaxf(lred, fabsf(c));
      } else {
        float trec = uni ? UNIF : (a.dinv[gm] * bs) * a.Kf[o];
        lred += c * trec;
      }
    }
  }
  #pragma unroll
  for (int off = 32; off; off >>= 1) {
    float t = __shfl_xor(lred, off, 64);
    lred = (EPI == EPI_COST) ? fmaxf(lred, t) : (lred + t);
  }
  if (lane == 0) red[wv] = lred;
  __syncthreads();
  if (tid == 0) {
    float t = red[0];
    #pragma unroll
    for (int i = 1; i < 8; ++i)
      t = (EPI == EPI_COST) ? fmaxf(t, red[i]) : (t + red[i]);
    if constexpr (EPI == EPI_COST) atomicMax(a.mx, __float_as_uint(t));
    else atomicAdd(a.loss, t);
  }
}

// ---------------------------------------------------------------------------
// kbuild: tran reconstructed from (K_old f32, dinv, braw_old) bit-identically,
// K_new = exp(-cost/mx)*tran (in place, f32), Kb bf16 + KTb bf16, braw2 seed.
// ---------------------------------------------------------------------------
__global__ __launch_bounds__(256)
void k_kbuild(const float* cost, const unsigned* mxbits, float* K,
              unsigned short* Kb, unsigned short* KTb, const float* dinv,
              const float* brawOld, float* braw2, int uniform)
{
  __shared__ float tt[64 * 65];
  __shared__ float dS[64];
  __shared__ float bS[64];
  __shared__ float csum[4][64];
  const int r0 = blockIdx.x * 64, c0 = blockIdx.y * 64;
  const int tid = threadIdx.x;
  const float inv = 1.f / __uint_as_float(*mxbits);
  if (tid < 64) dS[tid] = dinv[r0 + tid];
  else if (tid >= 64 && tid < 128 && !uniform) bS[tid - 64] = PS / brawOld[c0 + tid - 64];
  __syncthreads();
  float colp = 0.f;
  #pragma unroll
  for (int i = 0; i < 16; ++i) {
    int idx = tid + 256 * i;
    int r = idx >> 6, c = idx & 63;
    size_t o = (size_t)(r0 + r) * 1024 + (c0 + c);
    float trec = uniform ? UNIF : (dS[r] * bS[c]) * K[o];
    float v = expf(-cost[o] * inv) * trec;
    K[o]  = v;
    Kb[o] = (unsigned short)f2bf(v);
    tt[r * 65 + c] = v;
    colp += v * dS[r];
  }
  csum[tid >> 6][tid & 63] = colp;
  __syncthreads();
  #pragma unroll
  for (int i = 0; i < 16; ++i) {
    int idx = tid + 256 * i;
    int c = idx >> 6, r = idx & 63;
    KTb[(size_t)(c0 + c) * 1024 + (r0 + r)] = (unsigned short)f2bf(tt[r * 65 + c]);
  }
  if (tid < 64)
    atomicAdd(&braw2[c0 + tid],
              csum[0][tid] + csum[1][tid] + csum[2][tid] + csum[3][tid]);
}

// y_raw[r] = M[r,:].(PS/x_raw), M bf16; optionally emits invOut = PS/x.
__global__ __launch_bounds__(256)
void k_matvec(const unsigned short* M, const float* xraw, float* yraw, float* invOut)
{
  const int r = blockIdx.x * 4 + (threadIdx.x >> 6);
  const int lane = threadIdx.x & 63;
  const int wv = threadIdx.x >> 6;
  const unsigned short* row = M + (size_t)r * 1024;
  float s = 0.f;
  #pragma unroll
  for (int q = 0; q < 2; ++q) {
    int base = (lane + 64 * q) * 8;
    s16x8 m = *(const s16x8*)&row[base];
    f32x4 x0 = *(const f32x4*)&xraw[base];
    f32x4 x1 = *(const f32x4*)&xraw[base + 4];
    f32x4 iv0, iv1;
    iv0.x = PS / x0.x; iv0.y = PS / x0.y; iv0.z = PS / x0.z; iv0.w = PS / x0.w;
    iv1.x = PS / x1.x; iv1.y = PS / x1.y; iv1.z = PS / x1.z; iv1.w = PS / x1.w;
    if (invOut && blockIdx.x == 0 && wv == 0) {
      *(f32x4*)&invOut[base]     = iv0;
      *(f32x4*)&invOut[base + 4] = iv1;
    }
    s += bf2f((unsigned short)m[0]) * iv0.x + bf2f((unsigned short)m[1]) * iv0.y
       + bf2f((unsigned short)m[2]) * iv0.z + bf2f((unsigned short)m[3]) * iv0.w
       + bf2f((unsigned short)m[4]) * iv1.x + bf2f((unsigned short)m[5]) * iv1.y
       + bf2f((unsigned short)m[6]) * iv1.z + bf2f((unsigned short)m[7]) * iv1.w;
  }
  #pragma unroll
  for (int o = 32; o; o >>= 1) s += __shfl_xor(s, o, 64);
  if (lane == 0) yraw[r] = s;
}

// NaN scan over reconstructed tran (f32 K).
__global__ __launch_bounds__(256)
void k_nanscan(const float* K, const float* dinv, const float* braw, unsigned* flag)
{
  unsigned bad = 0;
  const int base = blockIdx.x * 256 + threadIdx.x;
  #pragma unroll
  for (int i = 0; i < 16; ++i) {
    int idx = base + 65536 * i;
    int r = idx >> 10, c = idx & 1023;
    float v = (dinv[r] * (PS / braw[c])) * K[idx];
    if (v != v) bad = 1u;
  }
  if (bad) atomicOr(flag, 1u);
}

// ---------------------------------------------------------------------------
// Distance via MFMA expanded form (verified R5).
// ---------------------------------------------------------------------------
struct DistMMArgs {
  const unsigned short* Fx[3]; const unsigned short* Fy[3];
  const float* nx[3]; const float* ny[3];
  unsigned short* outB[2]; float* outF; float* frow[2];
};
__global__ __launch_bounds__(256)
void k_distmm(DistMMArgs a)
{
  __shared__ short As[64 * 72];
  __shared__ short Bs[64 * 72];
  const int z = blockIdx.y;
  const int bid = blockIdx.x, tid = threadIdx.x;
  const int lane = tid & 63, wv = tid >> 6;
  const int wr = wv & 1, wc = wv >> 1;
  const int m0 = (bid >> 4) * 64, n0 = (bid & 15) * 64;
  const unsigned short* X = a.Fx[z];
  const unsigned short* Y = a.Fy[z];

  f32x4 acc[2][2];
  #pragma unroll
  for (int i = 0; i < 2; ++i)
    #pragma unroll
    for (int j = 0; j < 2; ++j) acc[i][j] = f32x4{0.f, 0.f, 0.f, 0.f};

  #pragma unroll
  for (int kb = 0; kb < 128; kb += 64) {
    #pragma unroll
    for (int i = 0; i < 2; ++i) {
      int idx = tid + 256 * i;
      int r = idx >> 3, q = idx & 7;
      *(s16x8*)&As[r * 72 + 8 * q] = *(const s16x8*)&X[(size_t)(m0 + r) * 128 + kb + 8 * q];
      *(s16x8*)&Bs[r * 72 + 8 * q] = *(const s16x8*)&Y[(size_t)(n0 + r) * 128 + kb + 8 * q];
    }
    __syncthreads();
    #pragma unroll
    for (int s = 0; s < 2; ++s) {
      const int ko = 32 * s + 8 * (lane >> 4);
      bf16x8 a0 = *(const bf16x8*)&As[(wr * 32 +      (lane & 15)) * 72 + ko];
      bf16x8 a1 = *(const bf16x8*)&As[(wr * 32 + 16 + (lane & 15)) * 72 + ko];
      bf16x8 b0 = *(const bf16x8*)&Bs[(wc * 32 +      (lane & 15)) * 72 + ko];
      bf16x8 b1 = *(const bf16x8*)&Bs[(wc * 32 + 16 + (lane & 15)) * 72 + ko];
      acc[0][0] = mfma16(a0, b0, acc[0][0]);
      acc[1][0] = mfma16(a1, b0, acc[1][0]);
      acc[0][1] = mfma16(a0, b1, acc[0][1]);
      acc[1][1] = mfma16(a1, b1, acc[1][1]);
    }
    __syncthreads();
  }

  const float* nxp = a.nx[z];
  const float* nyp = a.ny[z];
  float rp[2][4];
  #pragma unroll
  for (int fm = 0; fm < 2; ++fm)
    #pragma unroll
    for (int p = 0; p < 4; ++p) rp[fm][p] = 0.f;

  #pragma unroll
  for (int fm = 0; fm < 2; ++fm) {
    #pragma unroll
    for (int fn = 0; fn < 2; ++fn) {
      #pragma unroll
      for (int p = 0; p < 4; ++p) {
        int gm = m0 + wr * 32 + fm * 16 + (lane >> 4) * 4 + p;
        int gn = n0 + wc * 32 + fn * 16 + (lane & 15);
        float val = nxp[gm] + nyp[gn] - 2.f * acc[fm][fn][p] + 1e-6f;
        if (z == 2) a.outF[(size_t)gm * 1024 + gn] = val;
        else {
          a.outB[z][(size_t)gm * 1024 + gn] = (unsigned short)f2bf(val);
          rp[fm][p] += val * val;
        }
      }
    }
  }
  if (z < 2) {
    #pragma unroll
    for (int fm = 0; fm < 2; ++fm)
      #pragma unroll
      for (int p = 0; p < 4; ++p) {
        float v = rp[fm][p];
        v += __shfl_xor(v, 1, 64);
        v += __shfl_xor(v, 2, 64);
        v += __shfl_xor(v, 4, 64);
        v += __shfl_xor(v, 8, 64);
        rp[fm][p] = v;
      }
    if ((lane & 15) == 0) {
      #pragma unroll
      for (int fm = 0; fm < 2; ++fm)
        #pragma unroll
        for (int p = 0; p < 4; ++p) {
          int gm = m0 + wr * 32 + fm * 16 + (lane >> 4) * 4 + p;
          atomicAdd(&a.frow[z][gm], rp[fm][p] * (1.f / 1024.f));
        }
    }
  }
}

// ---------------------------------------------------------------------------
// batched transpose (4 weight matrices) + init slice (z==4)
// ---------------------------------------------------------------------------
struct T4 {
  const float* in[4]; unsigned short* out[4]; int R[4], C[4], nx[4], nt[4];
  float* dinv; float* f1; float* f2; unsigned* mx; unsigned* nanflag;
  float* cyc; float* ga; float* gb; float* al;
};
__global__ void k_transpose4(T4 d)
{
  const int z = blockIdx.y;
  const int tid = threadIdx.x;
  if (z == 4) {
    if (blockIdx.x == 0) {
      #pragma unroll
      for (int i = 0; i < 4; ++i) {
        int k = tid + 256 * i;
        d.dinv[k] = PS; d.f1[k] = 0.f; d.f2[k] = 0.f;
      }
      if (tid < 16) d.mx[tid] = 0u;
      if (tid == 0) {
        *d.nanflag = 0u; d.cyc[0] = 0.f; d.cyc[1] = 0.f;
        *d.ga = 0.f; *d.gb = 0.f; *d.al = 0.f;
      }
    }
    return;
  }
  __shared__ float t[64][65];
  const int tile = blockIdx.x;
  if (tile >= d.nt[z]) return;
  const int R = d.R[z], C = d.C[z];
  const int r0 = (tile % d.nx[z]) * 64, c0 = (tile / d.nx[z]) * 64;
  const float* in = d.in[z];
  unsigned short* out = d.out[z];
  #pragma unroll
  for (int i = 0; i < 16; ++i) {
    int idx = tid + 256 * i;
    int r = idx >> 6, c = idx & 63;
    float v = 0.f;
    if ((r0 + r) < R && (c0 + c) < C) v = in[(size_t)(r0 + r) * C + (c0 + c)];
    t[r][c] = v;
  }
  __syncthreads();
  #pragma unroll
  for (int i = 0; i < 16; ++i) {
    int idx = tid + 256 * i;
    int c = idx >> 6, r = idx & 63;
    if ((c0 + c) < C && (r0 + r) < R)
      out[(size_t)(c0 + c) * R + (r0 + r)] = (unsigned short)f2bf(t[r][c]);
  }
}

// Wcomb partial reduce + transpose (64 splits)
__global__ void k_wcomb_reduce(const float* partials, unsigned short* WcTa,
                               unsigned short* WcTb)
{
  __shared__ float t[64][65];
  const int z = blockIdx.z;
  const float* P = partials + (size_t)z * 64 * 256 * 256;
  unsigned short* WcT = z ? WcTb : WcTa;
  const int u0 = blockIdx.x * 64, v0 = blockIdx.y * 64;
  const int tid = threadIdx.x;
  #pragma unroll
  for (int i = 0; i < 16; ++i) {
    int idx = tid + 256 * i;
    int u = idx >> 6, v = idx & 63;
    float s = 0.f;
    for (int p = 0; p < 64; ++p)
      s += P[(size_t)p * 65536 + (u0 + u) * 256 + (v0 + v)];
    t[u][v] = s;
  }
  __syncthreads();
  #pragma unroll
  for (int i = 0; i < 16; ++i) {
    int idx = tid + 256 * i;
    int v = idx >> 6, u = idx & 63;
    WcT[(size_t)(v0 + v) * 256 + (u0 + u)] = (unsigned short)f2bf(t[u][v]);
  }
}

// bc[c] = b4 . Wt1[c,:] + b1[c]
struct BcArgs {
  const float* b4[2]; const unsigned short* Wt1[2]; const float* b1[2];
  float* bc[2]; int K[2];
};
__global__ void k_bcvec(BcArgs a)
{
  const int y = blockIdx.y;
  const int c = blockIdx.x * 4 + (threadIdx.x >> 6);
  const int lane = threadIdx.x & 63;
  const int K = a.K[y];
  const unsigned short* wrow = a.Wt1[y] + (size_t)c * K;
  const float* b4 = a.b4[y];
  float s = 0.f;
  for (int k = lane * 8; k < K; k += 512) {
    s16x8 w = *(const s16x8*)&wrow[k];
    f32x4 v0 = *(const f32x4*)&b4[k];
    f32x4 v1 = *(const f32x4*)&b4[k + 4];
    s += v0.x * bf2f((unsigned short)w[0]) + v0.y * bf2f((unsigned short)w[1])
       + v0.z * bf2f((unsigned short)w[2]) + v0.w * bf2f((unsigned short)w[3])
       + v1.x * bf2f((unsigned short)w[4]) + v1.y * bf2f((unsigned short)w[5])
       + v1.z * bf2f((unsigned short)w[6]) + v1.w * bf2f((unsigned short)w[7]);
  }
  #pragma unroll
  for (int o = 32; o; o >>= 1) s += __shfl_xor(s, o, 64);
  if (lane == 0) a.bc[y][c] = s + a.b1[y][c];
}

// ---------------------------------------------------------------------------
// fused: split-K reduce + relu + enc head + reparam + featprep + GMM KL
// ---------------------------------------------------------------------------
struct EF {
  const float* partials[2]; const float* bias[2];
  const float* W21[2]; const float* b21[2];
  const float* W22[2]; const float* b22[2]; const float* eps[2];
  const float* pmu[2]; const float* plv[2]; float* gmmO[2];
  float* mu[2]; float* lv[2]; float* zO[2];
  unsigned short* F[2]; float* n[2];
};
__global__ __launch_bounds__(256)
void k_enc_fused(EF a)
{
  __shared__ float hrow[256];
  __shared__ float res[128];
  const int y = blockIdx.y;
  const int i = blockIdx.x;
  const int t = threadIdx.x;
  {
    float s = a.bias[y][t];
    const float* P = a.partials[y] + (size_t)i * 256 + t;
    #pragma unroll
    for (int p = 0; p < 16; ++p) s += P[(size_t)p * 262144];
    hrow[t] = fmaxf(s, 0.f);
  }
  __syncthreads();
  if (t < 128) {
    const int c = t & 63;
    const float* W = (t < 64) ? a.W21[y] : a.W22[y];
    float acc = (t < 64) ? a.b21[y][c] : a.b22[y][c];
    #pragma unroll 8
    for (int j = 0; j < 256; ++j) acc += hrow[j] * W[j * 64 + c];
    res[t] = acc;
  }
  __syncthreads();
  if (t < 64) {
    float mu = res[t], lv = res[64 + t];
    a.mu[y][(size_t)i * 64 + t] = mu;
    a.lv[y][(size_t)i * 64 + t] = lv;
    float sig = expf(0.5f * lv);
    float zd = mu + a.eps[y][(size_t)i * 64 + t] * sig;
    a.zO[y][(size_t)i * 64 + t] = zd;
    unsigned short u0 = (unsigned short)f2bf(mu);
    unsigned short u1 = (unsigned short)f2bf(sig);
    unsigned short* Fr = a.F[y] + (size_t)i * 128;
    Fr[t] = u0;
    Fr[64 + t] = u1;
    float r0 = bf2f(u0), r1 = bf2f(u1);
    float p = r0 * r0 + r1 * r1;
    #pragma unroll
    for (int o = 32; o; o >>= 1) p += __shfl_xor(p, o, 64);
    if (t == 0) a.n[y][i] = p;
    // ---- GMM KL (fused)
    float tq = lv + (zd - mu) * (zd - mu) * expf(-lv);
    #pragma unroll
    for (int o = 32; o; o >>= 1) tq += __shfl_xor(tq, o, 64);
    const float C0 = 64.f * 1.8378770664093453f;
    float logq = -0.5f * (C0 + tq);
    float lp[20];
    #pragma unroll
    for (int k = 0; k < 20; ++k) {
      float pm = a.pmu[y][k * 64 + t], pl = a.plv[y][k * 64 + t];
      float u = pl + (zd - pm) * (zd - pm) * expf(-pl);
      #pragma unroll
      for (int o = 32; o; o >>= 1) u += __shfl_xor(u, o, 64);
      lp[k] = -0.5f * (C0 + u);
    }
    float mxv = lp[0];
    #pragma unroll
    for (int k = 1; k < 20; ++k) mxv = fmaxf(mxv, lp[k]);
    float se = 0.f;
    #pragma unroll
    for (int k = 0; k < 20; ++k) se += expf(lp[k] - mxv);
    float logp = mxv + logf(se) - 2.9957322735539909f;
    if (t == 0) atomicAdd(a.gmmO[y], logq - logp);
  }
}

// fused re-encode + cycle-loss partial
struct RencArgs {
  const float* hd[2]; const unsigned short* WcT[2]; const float* bc[2];
  const float* W21[2]; const float* b21[2]; const float* W22[2]; const float* b22[2];
  const float* eps[2]; float* fout[2];
  const float* zin[2]; float* cyc;
};
__global__ void k_renc_head(RencArgs a)
{
  __shared__ float hdrow[256];
  __shared__ float hr[256];
  __shared__ float res[128];
  const int y = blockIdx.y;
  const int i = blockIdx.x;
  const int t = threadIdx.x;                  // 256
  hdrow[t] = a.hd[y][(size_t)i * 256 + t];
  __syncthreads();
  {
    const s16x8* wr = (const s16x8*)(a.WcT[y] + (size_t)t * 256);
    float s = a.bc[y][t];
    #pragma unroll 4
    for (int j = 0; j < 32; ++j) {
      s16x8 w = wr[j];
      const float* hp = &hdrow[j * 8];
      s += hp[0] * bf2f((unsigned short)w[0]) + hp[1] * bf2f((unsigned short)w[1])
         + hp[2] * bf2f((unsigned short)w[2]) + hp[3] * bf2f((unsigned short)w[3])
         + hp[4] * bf2f((unsigned short)w[4]) + hp[5] * bf2f((unsigned short)w[5])
         + hp[6] * bf2f((unsigned short)w[6]) + hp[7] * bf2f((unsigned short)w[7]);
    }
    hr[t] = fmaxf(s, 0.f);
  }
  __syncthreads();
  if (t < 128) {
    const int c = t & 63;
    const float* W = (t < 64) ? a.W21[y] : a.W22[y];
    float acc = (t < 64) ? a.b21[y][c] : a.b22[y][c];
    #pragma unroll 8
    for (int j = 0; j < 256; ++j) acc += hr[j] * W[j * 64 + c];
    res[t] = acc;
  }
  __syncthreads();
  if (t < 64) {
    float mu = res[t], lv = res[64 + t];
    float f = mu + a.eps[y][(size_t)i * 64 + t] * expf(0.5f * lv);
    a.fout[y][(size_t)i * 64 + t] = f;
    float d = a.zin[y][(size_t)i * 64 + t] - f;
    d = d * d;
    #pragma unroll
    for (int o = 32; o; o >>= 1) d += __shfl_xor(d, o, 64);
    if (t == 0) atomicAdd(a.cyc + y, d);
  }
}

// batched decoder heads
struct DH4 { const float* z[4]; const float* W3[4]; const float* b3[4]; float* hd[4]; };
__global__ void k_dec_head4(DH4 a)
{
  __shared__ float zrow[64];
  const int y = blockIdx.y;
  const int i = blockIdx.x;
  const int t = threadIdx.x;                  // 256
  if (t < 64) zrow[t] = a.z[y][(size_t)i * 64 + t];
  __syncthreads();
  const float* W3 = a.W3[y];
  float acc = a.b3[y][t];
  #pragma unroll
  for (int d = 0; d < 64; ++d) acc += zrow[d] * W3[d * 256 + t];
  a.hd[y][(size_t)i * 256 + t] = fmaxf(acc, 0.f);
}

__global__ void k_finish(const float* slots, float* o1, float* o2)
{
  if (threadIdx.x == 0) { *o1 = sqrtf(slots[0]); *o2 = sqrtf(slots[1]); }
}

// ---------------------------------------------------------------------------
extern "C" void kernel_launch(void* const* d_in, const int* in_sizes, int n_in,
                              void* d_out, int out_size, void* d_ws, size_t ws_size,
                              hipStream_t stream)
{
  (void)in_sizes; (void)n_in; (void)out_size; (void)ws_size;

  const float* X     = (const float*)d_in[2];
  const float* Y     = (const float*)d_in[3];
  const float* pmua  = (const float*)d_in[4];
  const float* plva  = (const float*)d_in[5];
  const float* pmub  = (const float*)d_in[6];
  const float* plvb  = (const float*)d_in[7];
  const float* epsx  = (const float*)d_in[8];
  const float* epsy  = (const float*)d_in[9];
  const float* epsxr = (const float*)d_in[10];
  const float* epsyr = (const float*)d_in[11];
  const float* W1a = (const float*)d_in[12];  const float* b1a = (const float*)d_in[13];
  const float* W21a= (const float*)d_in[14];  const float* b21a= (const float*)d_in[15];
  const float* W22a= (const float*)d_in[16];  const float* b22a= (const float*)d_in[17];
  const float* W3a = (const float*)d_in[18];  const float* b3a = (const float*)d_in[19];
  const float* W4a = (const float*)d_in[20];  const float* b4a = (const float*)d_in[21];
  const float* W1b = (const float*)d_in[22];  const float* b1b = (const float*)d_in[23];
  const float* W21b= (const float*)d_in[24];  const float* b21b= (const float*)d_in[25];
  const float* W22b= (const float*)d_in[26];  const float* b22b= (const float*)d_in[27];
  const float* W3b = (const float*)d_in[28];  const float* b3b = (const float*)d_in[29];
  const float* W4b = (const float*)d_in[30];  const float* b4b = (const float*)d_in[31];

  float* out = (float*)d_out;
  const size_t P_X = 0, P_Y = 20480000, P_X2Y = 46080000, P_Y2X = 71680000;
  const size_t Z_X = 92160000, Z_Y = 92225536;
  const size_t GMM_A = 92291072, GMM_B = 92291073;
  const size_t F_XR = 92291074, F_YR = 92356610;
  const size_t ALIGN = 92422146, CYC_X = 92422147, CYC_Y = 92422148;

  // ---- workspace carve
  char* w = (char*)d_ws;
  size_t off = 0;
  auto alloc = [&](size_t bytes) -> void* {
    void* p = w + off;
    off += (bytes + 255) & ~(size_t)255;
    return p;
  };
  unsigned short* Wt1a = (unsigned short*)alloc((size_t)256 * 20000 * 2);
  unsigned short* Wt1b = (unsigned short*)alloc((size_t)256 * 25000 * 2);
  unsigned short* W4ta = (unsigned short*)alloc((size_t)20000 * 256 * 2);
  unsigned short* W4tb = (unsigned short*)alloc((size_t)25000 * 256 * 2);
  unsigned short* WcTa = (unsigned short*)alloc((size_t)256 * 256 * 2);
  unsigned short* WcTb = (unsigned short*)alloc((size_t)256 * 256 * 2);
  float* bca  = (float*)alloc(256 * 4);
  float* bcb  = (float*)alloc(256 * 4);
  float* mu_a = (float*)alloc(1024 * 64 * 4);
  float* lv_a = (float*)alloc(1024 * 64 * 4);
  float* mu_b = (float*)alloc(1024 * 64 * 4);
  float* lv_b = (float*)alloc(1024 * 64 * 4);
  float* f1   = (float*)alloc(1024 * 4);
  float* f2   = (float*)alloc(1024 * 4);
  unsigned* mx      = (unsigned*)alloc(16 * 4);
  unsigned* nanflag = (unsigned*)alloc(256);
  float* cyc  = (float*)alloc(256);
  float* draw = (float*)alloc(1024 * 4);
  float* braw = (float*)alloc(1024 * 4);
  float* braw2 = (float*)alloc(1024 * 4);
  float* dinv = (float*)alloc(1024 * 4);
  unsigned short* Fb = (unsigned short*)alloc((size_t)1024 * 128 * 2);
  unsigned short* Fa = (unsigned short*)alloc((size_t)1024 * 128 * 2);
  float* nb = (float*)alloc(1024 * 4);
  float* na = (float*)alloc(1024 * 4);
  char* arena = (char*)alloc((size_t)32 * 1024 * 1024);
  float* partials = (float*)arena;
  size_t ao = 0;
  auto aalloc = [&](size_t bytes) -> void* {
    void* p = arena + ao;
    ao += (bytes + 255) & ~(size_t)255;
    return p;
  };
  unsigned short* cpostB  = (unsigned short*)aalloc((size_t)1024 * 1024 * 2);
  unsigned short* cpriorB = (unsigned short*)aalloc((size_t)1024 * 1024 * 2);
  float* cpp  = (float*)aalloc((size_t)1024 * 1024 * 4);
  unsigned short* Umat  = (unsigned short*)aalloc((size_t)1024 * 1024 * 2);
  float* cost  = (float*)aalloc((size_t)1024 * 1024 * 4);
  float* Kmat  = (float*)aalloc((size_t)1024 * 1024 * 4);
  unsigned short* Kb  = (unsigned short*)aalloc((size_t)1024 * 1024 * 2);
  unsigned short* KTb = (unsigned short*)aalloc((size_t)1024 * 1024 * 2);
  float* hd0 = (float*)(arena);
  float* hd1 = (float*)(arena + (size_t)1024 * 256 * 4);
  float* hd2 = (float*)(arena + (size_t)2 * 1024 * 256 * 4);
  float* hd3 = (float*)(arena + (size_t)3 * 1024 * 256 * 4);

  // ---- 1. weight transposes + init (z=4)
  {
    T4 d{};
    d.in[0] = W1a; d.out[0] = Wt1a; d.R[0] = 20000; d.C[0] = 256;
    d.in[1] = W1b; d.out[1] = Wt1b; d.R[1] = 25000; d.C[1] = 256;
    d.in[2] = W4a; d.out[2] = W4ta; d.R[2] = 256;   d.C[2] = 20000;
    d.in[3] = W4b; d.out[3] = W4tb; d.R[3] = 256;   d.C[3] = 25000;
    for (int z = 0; z < 4; ++z) {
      d.nx[z] = (d.R[z] + 63) / 64;
      d.nt[z] = d.nx[z] * ((d.C[z] + 63) / 64);
    }
    d.dinv = dinv; d.f1 = f1; d.f2 = f2; d.mx = mx; d.nanflag = nanflag;
    d.cyc = cyc; d.ga = out + GMM_A; d.gb = out + GMM_B; d.al = out + ALIGN;
    k_transpose4<<<dim3(1564, 5), 256, 0, stream>>>(d);
  }

  // ---- 2. Wcomb = W4 @ W1 -> WcT bf16 + combined bias (64 splits, grid 256)
  {
    Q4 q{};
    q.g[0].Af = W4a; q.g[0].Bt = Wt1a; q.g[0].partials = partials;
    q.g[0].M = 256; q.g[0].N = 256; q.g[0].K = 20000;
    q.g[0].lda = 20000; q.g[0].ldbt = 20000;
    q.g[0].totSteps = 313; q.g[0].nSplits = 64;
    q.g[1] = q.g[0];
    q.g[1].Af = W4b; q.g[1].Bt = Wt1b;
    q.g[1].partials = partials + (size_t)64 * 65536;
    q.g[1].K = 25000; q.g[1].lda = 25000; q.g[1].ldbt = 25000; q.g[1].totSteps = 391;
    k_gemmN<128, 256, 4, 4, EPI_PARTIAL><<<dim3(2, 64, 2), 1024, 0, stream>>>(q);
    k_wcomb_reduce<<<dim3(4, 4, 2), 256, 0, stream>>>(partials, WcTa, WcTb);
    BcArgs bc{};
    bc.b4[0] = b4a; bc.Wt1[0] = Wt1a; bc.b1[0] = b1a; bc.bc[0] = bca; bc.K[0] = 20000;
    bc.b4[1] = b4b; bc.Wt1[1] = Wt1b; bc.b1[1] = b1b; bc.bc[1] = bcb; bc.K[1] = 25000;
    k_bcvec<<<dim3(64, 2), 256, 0, stream>>>(bc);
  }

  // ---- 3. encoders (batched GEMM + fused reduce/head/featprep/GMM)
  {
    Q4 q{};
    q.g[0].Af = X; q.g[0].Bt = Wt1a; q.g[0].partials = partials;
    q.g[0].M = 1024; q.g[0].N = 256; q.g[0].K = 20000;
    q.g[0].lda = 20000; q.g[0].ldbt = 20000;
    q.g[0].totSteps = 313; q.g[0].nSplits = 16;
    q.g[1] = q.g[0];
    q.g[1].Af = Y; q.g[1].Bt = Wt1b;
    q.g[1].partials = partials + (size_t)16 * 1024 * 256;
    q.g[1].K = 25000; q.g[1].lda = 25000; q.g[1].ldbt = 25000; q.g[1].totSteps = 391;
    k_gemmN<128, 256, 4, 4, EPI_PARTIAL><<<dim3(8, 16, 2), 1024, 0, stream>>>(q);
    EF e{};
    e.partials[0] = partials; e.partials[1] = partials + (size_t)16 * 1024 * 256;
    e.bias[0] = b1a; e.bias[1] = b1b;
    e.W21[0] = W21a; e.b21[0] = b21a; e.W22[0] = W22a; e.b22[0] = b22a;
    e.eps[0] = epsx; e.mu[0] = mu_a; e.lv[0] = lv_a; e.zO[0] = out + Z_X;
    e.F[0] = Fa; e.n[0] = na;
    e.pmu[0] = pmua; e.plv[0] = plva; e.gmmO[0] = out + GMM_A;
    e.W21[1] = W21b; e.b21[1] = b21b; e.W22[1] = W22b; e.b22[1] = b22b;
    e.eps[1] = epsy; e.mu[1] = mu_b; e.lv[1] = lv_b; e.zO[1] = out + Z_Y;
    e.F[1] = Fb; e.n[1] = nb;
    e.pmu[1] = pmub; e.plv[1] = plvb; e.gmmO[1] = out + GMM_B;
    k_enc_fused<<<dim3(1024, 2), 256, 0, stream>>>(e);
  }

  // ---- 4. FGW(mu_b, mu_a, lv_b, lv_a)
  {
    DistMMArgs dm{};
    dm.Fx[0] = Fb; dm.Fy[0] = Fb; dm.nx[0] = nb; dm.ny[0] = nb;
    dm.Fx[1] = Fa; dm.Fy[1] = Fa; dm.nx[1] = na; dm.ny[1] = na;
    dm.Fx[2] = Fb; dm.Fy[2] = Fa; dm.nx[2] = nb; dm.ny[2] = na;
    dm.outB[0] = cpostB; dm.outB[1] = cpriorB; dm.outF = cpp;
    dm.frow[0] = f1; dm.frow[1] = f2;
    k_distmm<<<dim3(256, 3), 256, 0, stream>>>(dm);
  }
  G1Args g1{};
  g1.A = cpostB; g1.KTb = KTb; g1.dinv = dinv; g1.braw = braw;
  g1.U = Umat; g1.nflag = nanflag;
  FgwGemmArgs fg{};
  fg.A = Umat; fg.Bt = cpriorB;
  fg.f1 = f1; fg.f2 = f2; fg.cpp = cpp; fg.cost = cost;
  fg.loss = out + ALIGN; fg.braw2 = braw2;
  fg.Kf = Kmat; fg.dinv = dinv; fg.brawv = braw; fg.nflag = nanflag;
  for (int it = 0; it < 10; ++it) {
    g1.mode = (it == 0) ? 0 : 1;
    k_fgw_g1<<<256, 512, 0, stream>>>(g1);
    fg.mx = mx + it;
    k_fgw_gemm<EPI_COST><<<256, 512, 0, stream>>>(fg);
    k_kbuild<<<dim3(16, 16), 256, 0, stream>>>(cost, mx + it, Kmat, Kb, KTb,
                                               dinv, braw, braw2, it == 0 ? 1 : 0);
    for (int r = 0; r < 5; ++r) {
      k_matvec<<<256, 256, 0, stream>>>(Kb, r == 0 ? braw2 : braw, draw, nullptr);
      k_matvec<<<256, 256, 0, stream>>>(KTb, draw, braw, r == 4 ? dinv : nullptr);
    }
  }
  k_nanscan<<<256, 256, 0, stream>>>(Kmat, dinv, braw, nanflag);
  g1.mode = 2;
  k_fgw_g1<<<256, 512, 0, stream>>>(g1);
  k_fgw_gemm<EPI_LOSS><<<256, 512, 0, stream>>>(fg);

  // ---- 5. decoder heads
  {
    DH4 d{};
    d.z[0] = out + Z_X; d.W3[0] = W3a; d.b3[0] = b3a; d.hd[0] = hd0;   // P_X
    d.z[1] = out + Z_Y; d.W3[1] = W3a; d.b3[1] = b3a; d.hd[1] = hd1;   // P_Y2X
    d.z[2] = out + Z_Y; d.W3[2] = W3b; d.b3[2] = b3b; d.hd[2] = hd2;   // P_Y
    d.z[3] = out + Z_X; d.W3[3] = W3b; d.b3[3] = b3b; d.hd[3] = hd3;   // P_X2Y
    k_dec_head4<<<dim3(1024, 4), 256, 0, stream>>>(d);
  }

  // ---- 6. fused re-encoders (+cycle partials)
  {
    RencArgs r{};
    r.hd[0] = hd3; r.WcT[0] = WcTb; r.bc[0] = bcb;                     // enc_b(dec_b(z_x))
    r.W21[0] = W21b; r.b21[0] = b21b; r.W22[0] = W22b; r.b22[0] = b22b;
    r.eps[0] = epsxr; r.fout[0] = out + F_XR; r.zin[0] = out + Z_X;
    r.hd[1] = hd1; r.WcT[1] = WcTa; r.bc[1] = bca;                     // enc_a(dec_a(z_y))
    r.W21[1] = W21a; r.b21[1] = b21a; r.W22[1] = W22a; r.b22[1] = b22a;
    r.eps[1] = epsyr; r.fout[1] = out + F_YR; r.zin[1] = out + Z_Y;
    r.cyc = cyc;
    k_renc_head<<<dim3(1024, 2), 256, 0, stream>>>(r);
  }
  k_finish<<<1, 64, 0, stream>>>(cyc, out + CYC_X, out + CYC_Y);

  // ---- 7. decoder GEMMs (one launch, z=0..3, coalesced LDS-bounce stores)
  {
    Q4 q{};
    q.g[0].Af = hd0; q.g[0].Bt = W4ta; q.g[0].outF = out + P_X; q.g[0].bias = b4a;
    q.g[0].M = 1024; q.g[0].N = 20000; q.g[0].K = 256;
    q.g[0].lda = 256; q.g[0].ldbt = 256; q.g[0].ldc = 20000;
    q.g[1] = q.g[0]; q.g[1].Af = hd1; q.g[1].outF = out + P_Y2X;
    q.g[2] = q.g[0];
    q.g[2].Af = hd2; q.g[2].Bt = W4tb; q.g[2].outF = out + P_Y; q.g[2].bias = b4b;
    q.g[2].N = 25000; q.g[2].ldc = 25000;
    q.g[3] = q.g[2]; q.g[3].Af = hd3; q.g[3].outF = out + P_X2Y;
    k_gemmN<128, 128, 4, 2, EPI_BIAS><<<dim3(8, 196, 4), 512, 0, stream>>>(q);
  }
}

// Round 13
// 1265.856 us; speedup vs baseline: 1.3761x; 1.0576x over previous
//
#include <hip/hip_runtime.h>

// ============================================================================
// MUCRP_17265768530653 — cross-domain VAE forward on MI355X (gfx950)
// Round 13 (R12 base):
//  - LDS-bounce coalesced epilogue extended to EPI_PARTIAL (96MB of split-K
//    partial writes were still 64B-segment register stores)
//  - nontemporal stores for partials + decoder outputs (streaming, never
//    re-read by kernels); nontemporal loads for stream-once f32 A panels
//  - kbuild 256 -> 512 threads (8 waves, BW-bound)
// ============================================================================

#define DEVI __device__ __forceinline__

typedef __attribute__((ext_vector_type(4))) float  f32x4;
typedef __attribute__((ext_vector_type(4))) short  s16x4;
typedef __attribute__((ext_vector_type(8))) short  s16x8;
typedef __attribute__((ext_vector_type(8))) __bf16 bf16x8;

#define PS (1.f / 1024.f)
#define UNIF (1.f / (1024.f * 1024.f))

DEVI short f2bf(float f) {              // RNE f32 -> bf16 (bits)
  unsigned u = __float_as_uint(f);
  u += 0x7fffu + ((u >> 16) & 1u);
  return (short)(u >> 16);
}
DEVI float bf2f(unsigned short u) { return __uint_as_float(((unsigned)u) << 16); }

DEVI f32x4 mfma16(bf16x8 a, bf16x8 b, f32x4 c) {
  return __builtin_amdgcn_mfma_f32_16x16x32_bf16(a, b, c, 0, 0, 0);
}

// ---------------------------------------------------------------------------
// Generic tiled MFMA GEMM body (verified R1-R12).
// ---------------------------------------------------------------------------
struct GemmArgs {
  const float* Af;
  const unsigned short* Bt;
  float* outF;
  const float* bias;
  float* partials;
  int M, N, K;
  int lda, ldbt, ldc;
  int totSteps, nSplits;
};

enum { EPI_PARTIAL, EPI_BIAS, EPI_COST, EPI_LOSS };

template<int BM, int BN, int WR, int WC, int EPI>
DEVI void gemm_body(const GemmArgs g)
{
  constexpr int BK = 64, BKP = 72;
  constexpr int NT = WR * WC * 64;
  __shared__ short SM[(BM + BN) * BKP];
  short* As = SM;
  short* Bs = SM + BM * BKP;

  const int m0 = blockIdx.x * BM;
  int n0 = 0, kb0 = 0, kb1 = g.K, split = 0;
  if constexpr (EPI == EPI_PARTIAL) {
    split = blockIdx.y;
    int s0 = (split * g.totSteps) / g.nSplits;
    int s1 = ((split + 1) * g.totSteps) / g.nSplits;
    kb0 = s0 * BK;
    kb1 = s1 * BK; if (kb1 > g.K) kb1 = g.K;
  } else {
    n0 = blockIdx.y * BN;
  }
  const int tid  = threadIdx.x;
  const int lane = tid & 63;
  const int wv   = tid >> 6;
  const int wr   = wv % WR;
  const int wc   = wv / WR;

  f32x4 acc[2][4];
  #pragma unroll
  for (int i = 0; i < 2; ++i)
    #pragma unroll
    for (int j = 0; j < 4; ++j) acc[i][j] = f32x4{0.f, 0.f, 0.f, 0.f};

  for (int kb = kb0; kb < kb1; kb += BK) {
    {   // stage A (f32 -> bf16); NT load for stream-once panels
      constexpr int NV = BM * BK / 4;
      #pragma unroll
      for (int i = 0; i < NV / NT; ++i) {
        int idx = tid + NT * i;
        int r = idx >> 4, q = idx & 15;
        int k = kb + 4 * q;
        f32x4 v = f32x4{0.f, 0.f, 0.f, 0.f};
        if (k < kb1) {
          const f32x4* ap = (const f32x4*)(g.Af + (size_t)(m0 + r) * g.lda + k);
          if constexpr (EPI == EPI_PARTIAL) v = __builtin_nontemporal_load(ap);
          else                              v = *ap;
        }
        s16x4 s;
        s.x = f2bf(v.x); s.y = f2bf(v.y); s.z = f2bf(v.z); s.w = f2bf(v.w);
        *(s16x4*)&As[r * BKP + 4 * q] = s;
      }
    }
    {   // stage B (bf16 [N][K])
      constexpr int NV = BN * BK / 8;
      #pragma unroll
      for (int i = 0; i < NV / NT; ++i) {
        int idx = tid + NT * i;
        int r = idx >> 3, q = idx & 7;
        int k = kb + 8 * q;
        s16x8 v{};
        if ((n0 + r) < g.N && k < kb1)
          v = *(const s16x8*)(g.Bt + (size_t)(n0 + r) * g.ldbt + k);
        *(s16x8*)&Bs[r * BKP + 8 * q] = v;
      }
    }
    __syncthreads();
    #pragma unroll
    for (int s = 0; s < 2; ++s) {
      const int ko = 32 * s + 8 * (lane >> 4);
      bf16x8 a0 = *(const bf16x8*)&As[(wr * 32 +      (lane & 15)) * BKP + ko];
      bf16x8 a1 = *(const bf16x8*)&As[(wr * 32 + 16 + (lane & 15)) * BKP + ko];
      #pragma unroll
      for (int fn = 0; fn < 4; ++fn) {
        bf16x8 b = *(const bf16x8*)&Bs[(wc * 64 + fn * 16 + (lane & 15)) * BKP + ko];
        acc[0][fn] = mfma16(a0, b, acc[0][fn]);
        acc[1][fn] = mfma16(a1, b, acc[1][fn]);
      }
    }
    __syncthreads();
  }

  // unified LDS-bounce epilogue: lane-contiguous float4 nontemporal stores
  float* Cs = (float*)SM;
  #pragma unroll
  for (int h = 0; h < WC; ++h) {
    __syncthreads();
    if (wc == h) {
      #pragma unroll
      for (int fm = 0; fm < 2; ++fm)
        #pragma unroll
        for (int fn = 0; fn < 4; ++fn)
          #pragma unroll
          for (int p = 0; p < 4; ++p)
            Cs[(wr * 32 + fm * 16 + (lane >> 4) * 4 + p) * 65
               + fn * 16 + (lane & 15)] = acc[fm][fn][p];
    }
    __syncthreads();
    const int n0h = n0 + 64 * h;
    #pragma unroll
    for (int j = tid; j < BM * 16; j += NT) {
      int r = j >> 4, c4 = j & 15;
      int gn = n0h + 4 * c4;
      f32x4 v = *(f32x4*)&Cs[r * 65 + 4 * c4];
      if constexpr (EPI == EPI_PARTIAL) {
        __builtin_nontemporal_store(
            v, (f32x4*)(g.partials + ((size_t)split * g.M + m0 + r) * 256 + gn));
      } else {
        if (gn < g.N) {
          f32x4 b = *(const f32x4*)&g.bias[gn];
          v.x += b.x; v.y += b.y; v.z += b.z; v.w += b.w;
          __builtin_nontemporal_store(
              v, (f32x4*)(g.outF + (size_t)(m0 + r) * g.ldc + gn));
        }
      }
    }
  }
}

struct Q4 { GemmArgs g[4]; };

template<int BM, int BN, int WR, int WC, int EPI>
__global__ __launch_bounds__(WR*WC*64)
void k_gemmN(Q4 q)
{
  GemmArgs g = q.g[blockIdx.z];
  if constexpr (EPI == EPI_BIAS) {
    if ((int)(blockIdx.y * BN) >= g.N) return;
  }
  gemm_body<BM, BN, WR, WC, EPI>(g);
}

// ---------------------------------------------------------------------------
// FGW GEMM1': U[m][n] = bscale * sum_k bf16(cpost[m][k]*dinv[k]) * KTb[n][k]
// 64x64 tile, 8 waves (2x4, wave tile 32x16), 256 blocks.
// ---------------------------------------------------------------------------
struct G1Args {
  const unsigned short* A;
  const unsigned short* KTb;
  const float* dinv;
  const float* braw;
  unsigned short* U;
  const unsigned* nflag;
  int mode;   // 0: uniform  1: factors  2: factors unless nanflag
};

__global__ __launch_bounds__(512)
void k_fgw_g1(G1Args a)
{
  __shared__ short As[64 * 72];
  __shared__ short Bs[64 * 72];
  const bool uni = (a.mode == 0) || (a.mode == 2 && *a.nflag != 0u);

  const int bid = blockIdx.x, tid = threadIdx.x;
  const int lane = tid & 63, wv = tid >> 6;
  const int wr = wv & 1, wc = wv >> 1;          // 2x4 waves, 32x16 each
  const int m0 = (bid >> 4) * 64, n0 = (bid & 15) * 64;

  f32x4 acc[2];
  acc[0] = f32x4{0.f, 0.f, 0.f, 0.f};
  acc[1] = f32x4{0.f, 0.f, 0.f, 0.f};

  const short ub = f2bf(UNIF);

  for (int kb = 0; kb < 1024; kb += 64) {
    {
      int r = tid >> 3, q = tid & 7;
      s16x8 av = *(const s16x8*)&a.A[(size_t)(m0 + r) * 1024 + kb + 8 * q];
      if (!uni) {
        f32x4 d0 = *(const f32x4*)&a.dinv[kb + 8 * q];
        f32x4 d1 = *(const f32x4*)&a.dinv[kb + 8 * q + 4];
        s16x8 o;
        o[0] = f2bf(bf2f((unsigned short)av[0]) * d0.x);
        o[1] = f2bf(bf2f((unsigned short)av[1]) * d0.y);
        o[2] = f2bf(bf2f((unsigned short)av[2]) * d0.z);
        o[3] = f2bf(bf2f((unsigned short)av[3]) * d0.w);
        o[4] = f2bf(bf2f((unsigned short)av[4]) * d1.x);
        o[5] = f2bf(bf2f((unsigned short)av[5]) * d1.y);
        o[6] = f2bf(bf2f((unsigned short)av[6]) * d1.z);
        o[7] = f2bf(bf2f((unsigned short)av[7]) * d1.w);
        av = o;
      }
      *(s16x8*)&As[r * 72 + 8 * q] = av;
      s16x8 bv;
      if (uni) {
        #pragma unroll
        for (int j = 0; j < 8; ++j) bv[j] = ub;
      } else {
        bv = *(const s16x8*)&a.KTb[(size_t)(n0 + r) * 1024 + kb + 8 * q];
      }
      *(s16x8*)&Bs[r * 72 + 8 * q] = bv;
    }
    __syncthreads();
    #pragma unroll
    for (int s = 0; s < 2; ++s) {
      const int ko = 32 * s + 8 * (lane >> 4);
      bf16x8 b0 = *(const bf16x8*)&Bs[(wc * 16 + (lane & 15)) * 72 + ko];
      bf16x8 a0 = *(const bf16x8*)&As[(wr * 32 +      (lane & 15)) * 72 + ko];
      bf16x8 a1 = *(const bf16x8*)&As[(wr * 32 + 16 + (lane & 15)) * 72 + ko];
      acc[0] = mfma16(a0, b0, acc[0]);
      acc[1] = mfma16(a1, b0, acc[1]);
    }
    __syncthreads();
  }

  const int gn = n0 + wc * 16 + (lane & 15);
  const float bs = uni ? 1.f : (PS / a.braw[gn]);
  #pragma unroll
  for (int fm = 0; fm < 2; ++fm) {
    #pragma unroll
    for (int p = 0; p < 4; ++p) {
      int gm = m0 + wr * 32 + fm * 16 + (lane >> 4) * 4 + p;
      float v = acc[fm][p];
      a.U[(size_t)gm * 1024 + gn] = (unsigned short)f2bf(uni ? v : bs * v);
    }
  }
}

// ---------------------------------------------------------------------------
// FGW GEMM (COST / LOSS), 64x64 tile, 8 waves, 256 blocks.
// ---------------------------------------------------------------------------
struct FgwGemmArgs {
  const unsigned short* A;
  const unsigned short* Bt;
  float* cost;
  const float* f1;
  const float* f2;
  const float* cpp;
  unsigned* mx;
  float* loss;
  float* braw2;
  const float* Kf;
  const float* dinv;
  const float* brawv;
  const unsigned* nflag;
};

template<int EPI>
__global__ __launch_bounds__(512)
void k_fgw_gemm(FgwGemmArgs a)
{
  __shared__ short As[64 * 72];
  __shared__ short Bs[64 * 72];
  __shared__ float red[8];

  const int bid = blockIdx.x, tid = threadIdx.x;
  const int lane = tid & 63, wv = tid >> 6;
  const int wr = wv & 1, wc = wv >> 1;
  const int m0 = (bid >> 4) * 64, n0 = (bid & 15) * 64;

  if constexpr (EPI == EPI_COST) {
    if (bid == 0) {
      #pragma unroll
      for (int i = 0; i < 2; ++i) a.braw2[tid + 512 * i] = 0.f;
    }
  }

  f32x4 acc[2];
  acc[0] = f32x4{0.f, 0.f, 0.f, 0.f};
  acc[1] = f32x4{0.f, 0.f, 0.f, 0.f};

  for (int kb = 0; kb < 1024; kb += 64) {
    {
      int r = tid >> 3, q = tid & 7;
      *(s16x8*)&As[r * 72 + 8 * q] = *(const s16x8*)&a.A [(size_t)(m0 + r) * 1024 + kb + 8 * q];
      *(s16x8*)&Bs[r * 72 + 8 * q] = *(const s16x8*)&a.Bt[(size_t)(n0 + r) * 1024 + kb + 8 * q];
    }
    __syncthreads();
    #pragma unroll
    for (int s = 0; s < 2; ++s) {
      const int ko = 32 * s + 8 * (lane >> 4);
      bf16x8 b0 = *(const bf16x8*)&Bs[(wc * 16 + (lane & 15)) * 72 + ko];
      bf16x8 a0 = *(const bf16x8*)&As[(wr * 32 +      (lane & 15)) * 72 + ko];
      bf16x8 a1 = *(const bf16x8*)&As[(wr * 32 + 16 + (lane & 15)) * 72 + ko];
      acc[0] = mfma16(a0, b0, acc[0]);
      acc[1] = mfma16(a1, b0, acc[1]);
    }
    __syncthreads();
  }

  bool uni = false;
  if constexpr (EPI == EPI_LOSS) uni = (*a.nflag != 0u);

  const int gn = n0 + wc * 16 + (lane & 15);
  float bs = 0.f;
  if constexpr (EPI == EPI_LOSS) bs = uni ? 0.f : (PS / a.brawv[gn]);

  float lred = 0.f;
  #pragma unroll
  for (int fm = 0; fm < 2; ++fm) {
    #pragma unroll
    for (int p = 0; p < 4; ++p) {
      int gm = m0 + wr * 32 + fm * 16 + (lane >> 4) * 4 + p;
      float v = acc[fm][p];
      size_t o = (size_t)gm * 1024 + gn;
      float c = 0.1f * (a.f1[gm] + a.f2[gn] - 2.f * v) + 0.9f * a.cpp[o];
      if constexpr (EPI == EPI_COST) {
        a.cost[o] = c;
        lred = fmaxf(lred, fabsf(c));
      } else {
        float trec = uni ? UNIF : (a.dinv[gm] * bs) * a.Kf[o];
        lred += c * trec;
      }
    }
  }
  #pragma unroll
  for (int off = 32; off; off >>= 1) {
    float t = __shfl_xor(lred, off, 64);
    lred = (EPI == EPI_COST) ? fmaxf(lred, t) : (lred + t);
  }
  if (lane == 0) red[wv] = lred;
  __syncthreads();
  if (tid == 0) {
    float t = red[0];
    #pragma unroll
    for (int i = 1; i < 8; ++i)
      t = (EPI == EPI_COST) ? fmaxf(t, red[i]) : (t + red[i]);
    if constexpr (EPI == EPI_COST) atomicMax(a.mx, __float_as_uint(t));
    else atomicAdd(a.loss, t);
  }
}

// ---------------------------------------------------------------------------
// kbuild (512 thr, 8 waves): tran reconstructed bit-identically from
// (K_old f32, dinv, braw_old); K_new = exp(-cost/mx)*tran (f32, in place);
// Kb bf16 + KTb bf16; braw2 seed.
// ---------------------------------------------------------------------------
__global__ __launch_bounds__(512)
void k_kbuild(const float* cost, const unsigned* mxbits, float* K,
              unsigned short* Kb, unsigned short* KTb, const float* dinv,
              const float* brawOld, float* braw2, int uniform)
{
  __shared__ float tt[64 * 65];
  __shared__ float dS[64];
  __shared__ float bS[64];
  __shared__ float csum[8][64];
  const int r0 = blockIdx.x * 64, c0 = blockIdx.y * 64;
  const int tid = threadIdx.x;
  const float inv = 1.f / __uint_as_float(*mxbits);
  if (tid < 64) dS[tid] = dinv[r0 + tid];
  else if (tid >= 64 && tid < 128 && !uniform) bS[tid - 64] = PS / brawOld[c0 + tid - 64];
  __syncthreads();
  float colp = 0.f;
  #pragma unroll
  for (int i = 0; i < 8; ++i) {
    int idx = tid + 512 * i;
    int r = idx >> 6, c = idx & 63;
    size_t o = (size_t)(r0 + r) * 1024 + (c0 + c);
    float trec = uniform ? UNIF : (dS[r] * bS[c]) * K[o];
    float v = expf(-cost[o] * inv) * trec;
    K[o]  = v;
    Kb[o] = (unsigned short)f2bf(v);
    tt[r * 65 + c] = v;
    colp += v * dS[r];
  }
  csum[tid >> 6][tid & 63] = colp;
  __syncthreads();
  #pragma unroll
  for (int i = 0; i < 8; ++i) {
    int idx = tid + 512 * i;
    int c = idx >> 6, r = idx & 63;
    KTb[(size_t)(c0 + c) * 1024 + (r0 + r)] = (unsigned short)f2bf(tt[r * 65 + c]);
  }
  if (tid < 64) {
    float s = 0.f;
    #pragma unroll
    for (int k = 0; k < 8; ++k) s += csum[k][tid];
    atomicAdd(&braw2[c0 + tid], s);
  }
}

// y_raw[r] = M[r,:].(PS/x_raw), M bf16; optionally emits invOut = PS/x.
__global__ __launch_bounds__(256)
void k_matvec(const unsigned short* M, const float* xraw, float* yraw, float* invOut)
{
  const int r = blockIdx.x * 4 + (threadIdx.x >> 6);
  const int lane = threadIdx.x & 63;
  const int wv = threadIdx.x >> 6;
  const unsigned short* row = M + (size_t)r * 1024;
  float s = 0.f;
  #pragma unroll
  for (int q = 0; q < 2; ++q) {
    int base = (lane + 64 * q) * 8;
    s16x8 m = *(const s16x8*)&row[base];
    f32x4 x0 = *(const f32x4*)&xraw[base];
    f32x4 x1 = *(const f32x4*)&xraw[base + 4];
    f32x4 iv0, iv1;
    iv0.x = PS / x0.x; iv0.y = PS / x0.y; iv0.z = PS / x0.z; iv0.w = PS / x0.w;
    iv1.x = PS / x1.x; iv1.y = PS / x1.y; iv1.z = PS / x1.z; iv1.w = PS / x1.w;
    if (invOut && blockIdx.x == 0 && wv == 0) {
      *(f32x4*)&invOut[base]     = iv0;
      *(f32x4*)&invOut[base + 4] = iv1;
    }
    s += bf2f((unsigned short)m[0]) * iv0.x + bf2f((unsigned short)m[1]) * iv0.y
       + bf2f((unsigned short)m[2]) * iv0.z + bf2f((unsigned short)m[3]) * iv0.w
       + bf2f((unsigned short)m[4]) * iv1.x + bf2f((unsigned short)m[5]) * iv1.y
       + bf2f((unsigned short)m[6]) * iv1.z + bf2f((unsigned short)m[7]) * iv1.w;
  }
  #pragma unroll
  for (int o = 32; o; o >>= 1) s += __shfl_xor(s, o, 64);
  if (lane == 0) yraw[r] = s;
}

// NaN scan over reconstructed tran (f32 K).
__global__ __launch_bounds__(256)
void k_nanscan(const float* K, const float* dinv, const float* braw, unsigned* flag)
{
  unsigned bad = 0;
  const int base = blockIdx.x * 256 + threadIdx.x;
  #pragma unroll
  for (int i = 0; i < 16; ++i) {
    int idx = base + 65536 * i;
    int r = idx >> 10, c = idx & 1023;
    float v = (dinv[r] * (PS / braw[c])) * K[idx];
    if (v != v) bad = 1u;
  }
  if (bad) atomicOr(flag, 1u);
}

// ---------------------------------------------------------------------------
// Distance via MFMA expanded form (verified R5).
// ---------------------------------------------------------------------------
struct DistMMArgs {
  const unsigned short* Fx[3]; const unsigned short* Fy[3];
  const float* nx[3]; const float* ny[3];
  unsigned short* outB[2]; float* outF; float* frow[2];
};
__global__ __launch_bounds__(256)
void k_distmm(DistMMArgs a)
{
  __shared__ short As[64 * 72];
  __shared__ short Bs[64 * 72];
  const int z = blockIdx.y;
  const int bid = blockIdx.x, tid = threadIdx.x;
  const int lane = tid & 63, wv = tid >> 6;
  const int wr = wv & 1, wc = wv >> 1;
  const int m0 = (bid >> 4) * 64, n0 = (bid & 15) * 64;
  const unsigned short* X = a.Fx[z];
  const unsigned short* Y = a.Fy[z];

  f32x4 acc[2][2];
  #pragma unroll
  for (int i = 0; i < 2; ++i)
    #pragma unroll
    for (int j = 0; j < 2; ++j) acc[i][j] = f32x4{0.f, 0.f, 0.f, 0.f};

  #pragma unroll
  for (int kb = 0; kb < 128; kb += 64) {
    #pragma unroll
    for (int i = 0; i < 2; ++i) {
      int idx = tid + 256 * i;
      int r = idx >> 3, q = idx & 7;
      *(s16x8*)&As[r * 72 + 8 * q] = *(const s16x8*)&X[(size_t)(m0 + r) * 128 + kb + 8 * q];
      *(s16x8*)&Bs[r * 72 + 8 * q] = *(const s16x8*)&Y[(size_t)(n0 + r) * 128 + kb + 8 * q];
    }
    __syncthreads();
    #pragma unroll
    for (int s = 0; s < 2; ++s) {
      const int ko = 32 * s + 8 * (lane >> 4);
      bf16x8 a0 = *(const bf16x8*)&As[(wr * 32 +      (lane & 15)) * 72 + ko];
      bf16x8 a1 = *(const bf16x8*)&As[(wr * 32 + 16 + (lane & 15)) * 72 + ko];
      bf16x8 b0 = *(const bf16x8*)&Bs[(wc * 32 +      (lane & 15)) * 72 + ko];
      bf16x8 b1 = *(const bf16x8*)&Bs[(wc * 32 + 16 + (lane & 15)) * 72 + ko];
      acc[0][0] = mfma16(a0, b0, acc[0][0]);
      acc[1][0] = mfma16(a1, b0, acc[1][0]);
      acc[0][1] = mfma16(a0, b1, acc[0][1]);
      acc[1][1] = mfma16(a1, b1, acc[1][1]);
    }
    __syncthreads();
  }

  const float* nxp = a.nx[z];
  const float* nyp = a.ny[z];
  float rp[2][4];
  #pragma unroll
  for (int fm = 0; fm < 2; ++fm)
    #pragma unroll
    for (int p = 0; p < 4; ++p) rp[fm][p] = 0.f;

  #pragma unroll
  for (int fm = 0; fm < 2; ++fm) {
    #pragma unroll
    for (int fn = 0; fn < 2; ++fn) {
      #pragma unroll
      for (int p = 0; p < 4; ++p) {
        int gm = m0 + wr * 32 + fm * 16 + (lane >> 4) * 4 + p;
        int gn = n0 + wc * 32 + fn * 16 + (lane & 15);
        float val = nxp[gm] + nyp[gn] - 2.f * acc[fm][fn][p] + 1e-6f;
        if (z == 2) a.outF[(size_t)gm * 1024 + gn] = val;
        else {
          a.outB[z][(size_t)gm * 1024 + gn] = (unsigned short)f2bf(val);
          rp[fm][p] += val * val;
        }
      }
    }
  }
  if (z < 2) {
    #pragma unroll
    for (int fm = 0; fm < 2; ++fm)
      #pragma unroll
      for (int p = 0; p < 4; ++p) {
        float v = rp[fm][p];
        v += __shfl_xor(v, 1, 64);
        v += __shfl_xor(v, 2, 64);
        v += __shfl_xor(v, 4, 64);
        v += __shfl_xor(v, 8, 64);
        rp[fm][p] = v;
      }
    if ((lane & 15) == 0) {
      #pragma unroll
      for (int fm = 0; fm < 2; ++fm)
        #pragma unroll
        for (int p = 0; p < 4; ++p) {
          int gm = m0 + wr * 32 + fm * 16 + (lane >> 4) * 4 + p;
          atomicAdd(&a.frow[z][gm], rp[fm][p] * (1.f / 1024.f));
        }
    }
  }
}

// ---------------------------------------------------------------------------
// batched transpose (4 weight matrices) + init slice (z==4)
// ---------------------------------------------------------------------------
struct T4 {
  const float* in[4]; unsigned short* out[4]; int R[4], C[4], nx[4], nt[4];
  float* dinv; float* f1; float* f2; unsigned* mx; unsigned* nanflag;
  float* cyc; float* ga; float* gb; float* al;
};
__global__ void k_transpose4(T4 d)
{
  const int z = blockIdx.y;
  const int tid = threadIdx.x;
  if (z == 4) {
    if (blockIdx.x == 0) {
      #pragma unroll
      for (int i = 0; i < 4; ++i) {
        int k = tid + 256 * i;
        d.dinv[k] = PS; d.f1[k] = 0.f; d.f2[k] = 0.f;
      }
      if (tid < 16) d.mx[tid] = 0u;
      if (tid == 0) {
        *d.nanflag = 0u; d.cyc[0] = 0.f; d.cyc[1] = 0.f;
        *d.ga = 0.f; *d.gb = 0.f; *d.al = 0.f;
      }
    }
    return;
  }
  __shared__ float t[64][65];
  const int tile = blockIdx.x;
  if (tile >= d.nt[z]) return;
  const int R = d.R[z], C = d.C[z];
  const int r0 = (tile % d.nx[z]) * 64, c0 = (tile / d.nx[z]) * 64;
  const float* in = d.in[z];
  unsigned short* out = d.out[z];
  #pragma unroll
  for (int i = 0; i < 16; ++i) {
    int idx = tid + 256 * i;
    int r = idx >> 6, c = idx & 63;
    float v = 0.f;
    if ((r0 + r) < R && (c0 + c) < C) v = in[(size_t)(r0 + r) * C + (c0 + c)];
    t[r][c] = v;
  }
  __syncthreads();
  #pragma unroll
  for (int i = 0; i < 16; ++i) {
    int idx = tid + 256 * i;
    int c = idx >> 6, r = idx & 63;
    if ((c0 + c) < C && (r0 + r) < R)
      out[(size_t)(c0 + c) * R + (r0 + r)] = (unsigned short)f2bf(t[r][c]);
  }
}

// Wcomb partial reduce + transpose (64 splits)
__global__ void k_wcomb_reduce(const float* partials, unsigned short* WcTa,
                               unsigned short* WcTb)
{
  __shared__ float t[64][65];
  const int z = blockIdx.z;
  const float* P = partials + (size_t)z * 64 * 256 * 256;
  unsigned short* WcT = z ? WcTb : WcTa;
  const int u0 = blockIdx.x * 64, v0 = blockIdx.y * 64;
  const int tid = threadIdx.x;
  #pragma unroll
  for (int i = 0; i < 16; ++i) {
    int idx = tid + 256 * i;
    int u = idx >> 6, v = idx & 63;
    float s = 0.f;
    for (int p = 0; p < 64; ++p)
      s += P[(size_t)p * 65536 + (u0 + u) * 256 + (v0 + v)];
    t[u][v] = s;
  }
  __syncthreads();
  #pragma unroll
  for (int i = 0; i < 16; ++i) {
    int idx = tid + 256 * i;
    int v = idx >> 6, u = idx & 63;
    WcT[(size_t)(v0 + v) * 256 + (u0 + u)] = (unsigned short)f2bf(t[u][v]);
  }
}

// bc[c] = b4 . Wt1[c,:] + b1[c]
struct BcArgs {
  const float* b4[2]; const unsigned short* Wt1[2]; const float* b1[2];
  float* bc[2]; int K[2];
};
__global__ void k_bcvec(BcArgs a)
{
  const int y = blockIdx.y;
  const int c = blockIdx.x * 4 + (threadIdx.x >> 6);
  const int lane = threadIdx.x & 63;
  const int K = a.K[y];
  const unsigned short* wrow = a.Wt1[y] + (size_t)c * K;
  const float* b4 = a.b4[y];
  float s = 0.f;
  for (int k = lane * 8; k < K; k += 512) {
    s16x8 w = *(const s16x8*)&wrow[k];
    f32x4 v0 = *(const f32x4*)&b4[k];
    f32x4 v1 = *(const f32x4*)&b4[k + 4];
    s += v0.x * bf2f((unsigned short)w[0]) + v0.y * bf2f((unsigned short)w[1])
       + v0.z * bf2f((unsigned short)w[2]) + v0.w * bf2f((unsigned short)w[3])
       + v1.x * bf2f((unsigned short)w[4]) + v1.y * bf2f((unsigned short)w[5])
       + v1.z * bf2f((unsigned short)w[6]) + v1.w * bf2f((unsigned short)w[7]);
  }
  #pragma unroll
  for (int o = 32; o; o >>= 1) s += __shfl_xor(s, o, 64);
  if (lane == 0) a.bc[y][c] = s + a.b1[y][c];
}

// ---------------------------------------------------------------------------
// fused: split-K reduce + relu + enc head + reparam + featprep + GMM KL
// ---------------------------------------------------------------------------
struct EF {
  const float* partials[2]; const float* bias[2];
  const float* W21[2]; const float* b21[2];
  const float* W22[2]; const float* b22[2]; const float* eps[2];
  const float* pmu[2]; const float* plv[2]; float* gmmO[2];
  float* mu[2]; float* lv[2]; float* zO[2];
  unsigned short* F[2]; float* n[2];
};
__global__ __launch_bounds__(256)
void k_enc_fused(EF a)
{
  __shared__ float hrow[256];
  __shared__ float res[128];
  const int y = blockIdx.y;
  const int i = blockIdx.x;
  const int t = threadIdx.x;
  {
    float s = a.bias[y][t];
    const float* P = a.partials[y] + (size_t)i * 256 + t;
    #pragma unroll
    for (int p = 0; p < 16; ++p) s += P[(size_t)p * 262144];
    hrow[t] = fmaxf(s, 0.f);
  }
  __syncthreads();
  if (t < 128) {
    const int c = t & 63;
    const float* W = (t < 64) ? a.W21[y] : a.W22[y];
    float acc = (t < 64) ? a.b21[y][c] : a.b22[y][c];
    #pragma unroll 8
    for (int j = 0; j < 256; ++j) acc += hrow[j] * W[j * 64 + c];
    res[t] = acc;
  }
  __syncthreads();
  if (t < 64) {
    float mu = res[t], lv = res[64 + t];
    a.mu[y][(size_t)i * 64 + t] = mu;
    a.lv[y][(size_t)i * 64 + t] = lv;
    float sig = expf(0.5f * lv);
    float zd = mu + a.eps[y][(size_t)i * 64 + t] * sig;
    a.zO[y][(size_t)i * 64 + t] = zd;
    unsigned short u0 = (unsigned short)f2bf(mu);
    unsigned short u1 = (unsigned short)f2bf(sig);
    unsigned short* Fr = a.F[y] + (size_t)i * 128;
    Fr[t] = u0;
    Fr[64 + t] = u1;
    float r0 = bf2f(u0), r1 = bf2f(u1);
    float p = r0 * r0 + r1 * r1;
    #pragma unroll
    for (int o = 32; o; o >>= 1) p += __shfl_xor(p, o, 64);
    if (t == 0) a.n[y][i] = p;
    // ---- GMM KL (fused)
    float tq = lv + (zd - mu) * (zd - mu) * expf(-lv);
    #pragma unroll
    for (int o = 32; o; o >>= 1) tq += __shfl_xor(tq, o, 64);
    const float C0 = 64.f * 1.8378770664093453f;
    float logq = -0.5f * (C0 + tq);
    float lp[20];
    #pragma unroll
    for (int k = 0; k < 20; ++k) {
      float pm = a.pmu[y][k * 64 + t], pl = a.plv[y][k * 64 + t];
      float u = pl + (zd - pm) * (zd - pm) * expf(-pl);
      #pragma unroll
      for (int o = 32; o; o >>= 1) u += __shfl_xor(u, o, 64);
      lp[k] = -0.5f * (C0 + u);
    }
    float mxv = lp[0];
    #pragma unroll
    for (int k = 1; k < 20; ++k) mxv = fmaxf(mxv, lp[k]);
    float se = 0.f;
    #pragma unroll
    for (int k = 0; k < 20; ++k) se += expf(lp[k] - mxv);
    float logp = mxv + logf(se) - 2.9957322735539909f;
    if (t == 0) atomicAdd(a.gmmO[y], logq - logp);
  }
}

// fused re-encode + cycle-loss partial
struct RencArgs {
  const float* hd[2]; const unsigned short* WcT[2]; const float* bc[2];
  const float* W21[2]; const float* b21[2]; const float* W22[2]; const float* b22[2];
  const float* eps[2]; float* fout[2];
  const float* zin[2]; float* cyc;
};
__global__ void k_renc_head(RencArgs a)
{
  __shared__ float hdrow[256];
  __shared__ float hr[256];
  __shared__ float res[128];
  const int y = blockIdx.y;
  const int i = blockIdx.x;
  const int t = threadIdx.x;                  // 256
  hdrow[t] = a.hd[y][(size_t)i * 256 + t];
  __syncthreads();
  {
    const s16x8* wr = (const s16x8*)(a.WcT[y] + (size_t)t * 256);
    float s = a.bc[y][t];
    #pragma unroll 4
    for (int j = 0; j < 32; ++j) {
      s16x8 w = wr[j];
      const float* hp = &hdrow[j * 8];
      s += hp[0] * bf2f((unsigned short)w[0]) + hp[1] * bf2f((unsigned short)w[1])
         + hp[2] * bf2f((unsigned short)w[2]) + hp[3] * bf2f((unsigned short)w[3])
         + hp[4] * bf2f((unsigned short)w[4]) + hp[5] * bf2f((unsigned short)w[5])
         + hp[6] * bf2f((unsigned short)w[6]) + hp[7] * bf2f((unsigned short)w[7]);
    }
    hr[t] = fmaxf(s, 0.f);
  }
  __syncthreads();
  if (t < 128) {
    const int c = t & 63;
    const float* W = (t < 64) ? a.W21[y] : a.W22[y];
    float acc = (t < 64) ? a.b21[y][c] : a.b22[y][c];
    #pragma unroll 8
    for (int j = 0; j < 256; ++j) acc += hr[j] * W[j * 64 + c];
    res[t] = acc;
  }
  __syncthreads();
  if (t < 64) {
    float mu = res[t], lv = res[64 + t];
    float f = mu + a.eps[y][(size_t)i * 64 + t] * expf(0.5f * lv);
    a.fout[y][(size_t)i * 64 + t] = f;
    float d = a.zin[y][(size_t)i * 64 + t] - f;
    d = d * d;
    #pragma unroll
    for (int o = 32; o; o >>= 1) d += __shfl_xor(d, o, 64);
    if (t == 0) atomicAdd(a.cyc + y, d);
  }
}

// batched decoder heads
struct DH4 { const float* z[4]; const float* W3[4]; const float* b3[4]; float* hd[4]; };
__global__ void k_dec_head4(DH4 a)
{
  __shared__ float zrow[64];
  const int y = blockIdx.y;
  const int i = blockIdx.x;
  const int t = threadIdx.x;                  // 256
  if (t < 64) zrow[t] = a.z[y][(size_t)i * 64 + t];
  __syncthreads();
  const float* W3 = a.W3[y];
  float acc = a.b3[y][t];
  #pragma unroll
  for (int d = 0; d < 64; ++d) acc += zrow[d] * W3[d * 256 + t];
  a.hd[y][(size_t)i * 256 + t] = fmaxf(acc, 0.f);
}

__global__ void k_finish(const float* slots, float* o1, float* o2)
{
  if (threadIdx.x == 0) { *o1 = sqrtf(slots[0]); *o2 = sqrtf(slots[1]); }
}

// ---------------------------------------------------------------------------
extern "C" void kernel_launch(void* const* d_in, const int* in_sizes, int n_in,
                              void* d_out, int out_size, void* d_ws, size_t ws_size,
                              hipStream_t stream)
{
  (void)in_sizes; (void)n_in; (void)out_size; (void)ws_size;

  const float* X     = (const float*)d_in[2];
  const float* Y     = (const float*)d_in[3];
  const float* pmua  = (const float*)d_in[4];
  const float* plva  = (const float*)d_in[5];
  const float* pmub  = (const float*)d_in[6];
  const float* plvb  = (const float*)d_in[7];
  const float* epsx  = (const float*)d_in[8];
  const float* epsy  = (const float*)d_in[9];
  const float* epsxr = (const float*)d_in[10];
  const float* epsyr = (const float*)d_in[11];
  const float* W1a = (const float*)d_in[12];  const float* b1a = (const float*)d_in[13];
  const float* W21a= (const float*)d_in[14];  const float* b21a= (const float*)d_in[15];
  const float* W22a= (const float*)d_in[16];  const float* b22a= (const float*)d_in[17];
  const float* W3a = (const float*)d_in[18];  const float* b3a = (const float*)d_in[19];
  const float* W4a = (const float*)d_in[20];  const float* b4a = (const float*)d_in[21];
  const float* W1b = (const float*)d_in[22];  const float* b1b = (const float*)d_in[23];
  const float* W21b= (const float*)d_in[24];  const float* b21b= (const float*)d_in[25];
  const float* W22b= (const float*)d_in[26];  const float* b22b= (const float*)d_in[27];
  const float* W3b = (const float*)d_in[28];  const float* b3b = (const float*)d_in[29];
  const float* W4b = (const float*)d_in[30];  const float* b4b = (const float*)d_in[31];

  float* out = (float*)d_out;
  const size_t P_X = 0, P_Y = 20480000, P_X2Y = 46080000, P_Y2X = 71680000;
  const size_t Z_X = 92160000, Z_Y = 92225536;
  const size_t GMM_A = 92291072, GMM_B = 92291073;
  const size_t F_XR = 92291074, F_YR = 92356610;
  const size_t ALIGN = 92422146, CYC_X = 92422147, CYC_Y = 92422148;

  // ---- workspace carve
  char* w = (char*)d_ws;
  size_t off = 0;
  auto alloc = [&](size_t bytes) -> void* {
    void* p = w + off;
    off += (bytes + 255) & ~(size_t)255;
    return p;
  };
  unsigned short* Wt1a = (unsigned short*)alloc((size_t)256 * 20000 * 2);
  unsigned short* Wt1b = (unsigned short*)alloc((size_t)256 * 25000 * 2);
  unsigned short* W4ta = (unsigned short*)alloc((size_t)20000 * 256 * 2);
  unsigned short* W4tb = (unsigned short*)alloc((size_t)25000 * 256 * 2);
  unsigned short* WcTa = (unsigned short*)alloc((size_t)256 * 256 * 2);
  unsigned short* WcTb = (unsigned short*)alloc((size_t)256 * 256 * 2);
  float* bca  = (float*)alloc(256 * 4);
  float* bcb  = (float*)alloc(256 * 4);
  float* mu_a = (float*)alloc(1024 * 64 * 4);
  float* lv_a = (float*)alloc(1024 * 64 * 4);
  float* mu_b = (float*)alloc(1024 * 64 * 4);
  float* lv_b = (float*)alloc(1024 * 64 * 4);
  float* f1   = (float*)alloc(1024 * 4);
  float* f2   = (float*)alloc(1024 * 4);
  unsigned* mx      = (unsigned*)alloc(16 * 4);
  unsigned* nanflag = (unsigned*)alloc(256);
  float* cyc  = (float*)alloc(256);
  float* draw = (float*)alloc(1024 * 4);
  float* braw = (float*)alloc(1024 * 4);
  float* braw2 = (float*)alloc(1024 * 4);
  float* dinv = (float*)alloc(1024 * 4);
  unsigned short* Fb = (unsigned short*)alloc((size_t)1024 * 128 * 2);
  unsigned short* Fa = (unsigned short*)alloc((size_t)1024 * 128 * 2);
  float* nb = (float*)alloc(1024 * 4);
  float* na = (float*)alloc(1024 * 4);
  char* arena = (char*)alloc((size_t)32 * 1024 * 1024);
  float* partials = (float*)arena;
  size_t ao = 0;
  auto aalloc = [&](size_t bytes) -> void* {
    void* p = arena + ao;
    ao += (bytes + 255) & ~(size_t)255;
    return p;
  };
  unsigned short* cpostB  = (unsigned short*)aalloc((size_t)1024 * 1024 * 2);
  unsigned short* cpriorB = (unsigned short*)aalloc((size_t)1024 * 1024 * 2);
  float* cpp  = (float*)aalloc((size_t)1024 * 1024 * 4);
  unsigned short* Umat  = (unsigned short*)aalloc((size_t)1024 * 1024 * 2);
  float* cost  = (float*)aalloc((size_t)1024 * 1024 * 4);
  float* Kmat  = (float*)aalloc((size_t)1024 * 1024 * 4);
  unsigned short* Kb  = (unsigned short*)aalloc((size_t)1024 * 1024 * 2);
  unsigned short* KTb = (unsigned short*)aalloc((size_t)1024 * 1024 * 2);
  float* hd0 = (float*)(arena);
  float* hd1 = (float*)(arena + (size_t)1024 * 256 * 4);
  float* hd2 = (float*)(arena + (size_t)2 * 1024 * 256 * 4);
  float* hd3 = (float*)(arena + (size_t)3 * 1024 * 256 * 4);

  // ---- 1. weight transposes + init (z=4)
  {
    T4 d{};
    d.in[0] = W1a; d.out[0] = Wt1a; d.R[0] = 20000; d.C[0] = 256;
    d.in[1] = W1b; d.out[1] = Wt1b; d.R[1] = 25000; d.C[1] = 256;
    d.in[2] = W4a; d.out[2] = W4ta; d.R[2] = 256;   d.C[2] = 20000;
    d.in[3] = W4b; d.out[3] = W4tb; d.R[3] = 256;   d.C[3] = 25000;
    for (int z = 0; z < 4; ++z) {
      d.nx[z] = (d.R[z] + 63) / 64;
      d.nt[z] = d.nx[z] * ((d.C[z] + 63) / 64);
    }
    d.dinv = dinv; d.f1 = f1; d.f2 = f2; d.mx = mx; d.nanflag = nanflag;
    d.cyc = cyc; d.ga = out + GMM_A; d.gb = out + GMM_B; d.al = out + ALIGN;
    k_transpose4<<<dim3(1564, 5), 256, 0, stream>>>(d);
  }

  // ---- 2. Wcomb = W4 @ W1 -> WcT bf16 + combined bias (64 splits, grid 256)
  {
    Q4 q{};
    q.g[0].Af = W4a; q.g[0].Bt = Wt1a; q.g[0].partials = partials;
    q.g[0].M = 256; q.g[0].N = 256; q.g[0].K = 20000;
    q.g[0].lda = 20000; q.g[0].ldbt = 20000;
    q.g[0].totSteps = 313; q.g[0].nSplits = 64;
    q.g[1] = q.g[0];
    q.g[1].Af = W4b; q.g[1].Bt = Wt1b;
    q.g[1].partials = partials + (size_t)64 * 65536;
    q.g[1].K = 25000; q.g[1].lda = 25000; q.g[1].ldbt = 25000; q.g[1].totSteps = 391;
    k_gemmN<128, 256, 4, 4, EPI_PARTIAL><<<dim3(2, 64, 2), 1024, 0, stream>>>(q);
    k_wcomb_reduce<<<dim3(4, 4, 2), 256, 0, stream>>>(partials, WcTa, WcTb);
    BcArgs bc{};
    bc.b4[0] = b4a; bc.Wt1[0] = Wt1a; bc.b1[0] = b1a; bc.bc[0] = bca; bc.K[0] = 20000;
    bc.b4[1] = b4b; bc.Wt1[1] = Wt1b; bc.b1[1] = b1b; bc.bc[1] = bcb; bc.K[1] = 25000;
    k_bcvec<<<dim3(64, 2), 256, 0, stream>>>(bc);
  }

  // ---- 3. encoders (batched GEMM + fused reduce/head/featprep/GMM)
  {
    Q4 q{};
    q.g[0].Af = X; q.g[0].Bt = Wt1a; q.g[0].partials = partials;
    q.g[0].M = 1024; q.g[0].N = 256; q.g[0].K = 20000;
    q.g[0].lda = 20000; q.g[0].ldbt = 20000;
    q.g[0].totSteps = 313; q.g[0].nSplits = 16;
    q.g[1] = q.g[0];
    q.g[1].Af = Y; q.g[1].Bt = Wt1b;
    q.g[1].partials = partials + (size_t)16 * 1024 * 256;
    q.g[1].K = 25000; q.g[1].lda = 25000; q.g[1].ldbt = 25000; q.g[1].totSteps = 391;
    k_gemmN<128, 256, 4, 4, EPI_PARTIAL><<<dim3(8, 16, 2), 1024, 0, stream>>>(q);
    EF e{};
    e.partials[0] = partials; e.partials[1] = partials + (size_t)16 * 1024 * 256;
    e.bias[0] = b1a; e.bias[1] = b1b;
    e.W21[0] = W21a; e.b21[0] = b21a; e.W22[0] = W22a; e.b22[0] = b22a;
    e.eps[0] = epsx; e.mu[0] = mu_a; e.lv[0] = lv_a; e.zO[0] = out + Z_X;
    e.F[0] = Fa; e.n[0] = na;
    e.pmu[0] = pmua; e.plv[0] = plva; e.gmmO[0] = out + GMM_A;
    e.W21[1] = W21b; e.b21[1] = b21b; e.W22[1] = W22b; e.b22[1] = b22b;
    e.eps[1] = epsy; e.mu[1] = mu_b; e.lv[1] = lv_b; e.zO[1] = out + Z_Y;
    e.F[1] = Fb; e.n[1] = nb;
    e.pmu[1] = pmub; e.plv[1] = plvb; e.gmmO[1] = out + GMM_B;
    k_enc_fused<<<dim3(1024, 2), 256, 0, stream>>>(e);
  }

  // ---- 4. FGW(mu_b, mu_a, lv_b, lv_a)
  {
    DistMMArgs dm{};
    dm.Fx[0] = Fb; dm.Fy[0] = Fb; dm.nx[0] = nb; dm.ny[0] = nb;
    dm.Fx[1] = Fa; dm.Fy[1] = Fa; dm.nx[1] = na; dm.ny[1] = na;
    dm.Fx[2] = Fb; dm.Fy[2] = Fa; dm.nx[2] = nb; dm.ny[2] = na;
    dm.outB[0] = cpostB; dm.outB[1] = cpriorB; dm.outF = cpp;
    dm.frow[0] = f1; dm.frow[1] = f2;
    k_distmm<<<dim3(256, 3), 256, 0, stream>>>(dm);
  }
  G1Args g1{};
  g1.A = cpostB; g1.KTb = KTb; g1.dinv = dinv; g1.braw = braw;
  g1.U = Umat; g1.nflag = nanflag;
  FgwGemmArgs fg{};
  fg.A = Umat; fg.Bt = cpriorB;
  fg.f1 = f1; fg.f2 = f2; fg.cpp = cpp; fg.cost = cost;
  fg.loss = out + ALIGN; fg.braw2 = braw2;
  fg.Kf = Kmat; fg.dinv = dinv; fg.brawv = braw; fg.nflag = nanflag;
  for (int it = 0; it < 10; ++it) {
    g1.mode = (it == 0) ? 0 : 1;
    k_fgw_g1<<<256, 512, 0, stream>>>(g1);
    fg.mx = mx + it;
    k_fgw_gemm<EPI_COST><<<256, 512, 0, stream>>>(fg);
    k_kbuild<<<dim3(16, 16), 512, 0, stream>>>(cost, mx + it, Kmat, Kb, KTb,
                                               dinv, braw, braw2, it == 0 ? 1 : 0);
    for (int r = 0; r < 5; ++r) {
      k_matvec<<<256, 256, 0, stream>>>(Kb, r == 0 ? braw2 : braw, draw, nullptr);
      k_matvec<<<256, 256, 0, stream>>>(KTb, draw, braw, r == 4 ? dinv : nullptr);
    }
  }
  k_nanscan<<<256, 256, 0, stream>>>(Kmat, dinv, braw, nanflag);
  g1.mode = 2;
  k_fgw_g1<<<256, 512, 0, stream>>>(g1);
  k_fgw_gemm<EPI_LOSS><<<256, 512, 0, stream>>>(fg);

  // ---- 5. decoder heads
  {
    DH4 d{};
    d.z[0] = out + Z_X; d.W3[0] = W3a; d.b3[0] = b3a; d.hd[0] = hd0;   // P_X
    d.z[1] = out + Z_Y; d.W3[1] = W3a; d.b3[1] = b3a; d.hd[1] = hd1;   // P_Y2X
    d.z[2] = out + Z_Y; d.W3[2] = W3b; d.b3[2] = b3b; d.hd[2] = hd2;   // P_Y
    d.z[3] = out + Z_X; d.W3[3] = W3b; d.b3[3] = b3b; d.hd[3] = hd3;   // P_X2Y
    k_dec_head4<<<dim3(1024, 4), 256, 0, stream>>>(d);
  }

  // ---- 6. fused re-encoders (+cycle partials)
  {
    RencArgs r{};
    r.hd[0] = hd3; r.WcT[0] = WcTb; r.bc[0] = bcb;                     // enc_b(dec_b(z_x))
    r.W21[0] = W21b; r.b21[0] = b21b; r.W22[0] = W22b; r.b22[0] = b22b;
    r.eps[0] = epsxr; r.fout[0] = out + F_XR; r.zin[0] = out + Z_X;
    r.hd[1] = hd1; r.WcT[1] = WcTa; r.bc[1] = bca;                     // enc_a(dec_a(z_y))
    r.W21[1] = W21a; r.b21[1] = b21a; r.W22[1] = W22a; r.b22[1] = b22a;
    r.eps[1] = epsyr; r.fout[1] = out + F_YR; r.zin[1] = out + Z_Y;
    r.cyc = cyc;
    k_renc_head<<<dim3(1024, 2), 256, 0, stream>>>(r);
  }
  k_finish<<<1, 64, 0, stream>>>(cyc, out + CYC_X, out + CYC_Y);

  // ---- 7. decoder GEMMs (one launch, z=0..3, NT coalesced LDS-bounce stores)
  {
    Q4 q{};
    q.g[0].Af = hd0; q.g[0].Bt = W4ta; q.g[0].outF = out + P_X; q.g[0].bias = b4a;
    q.g[0].M = 1024; q.g[0].N = 20000; q.g[0].K = 256;
    q.g[0].lda = 256; q.g[0].ldbt = 256; q.g[0].ldc = 20000;
    q.g[1] = q.g[0]; q.g[1].Af = hd1; q.g[1].outF = out + P_Y2X;
    q.g[2] = q.g[0];
    q.g[2].Af = hd2; q.g[2].Bt = W4tb; q.g[2].outF = out + P_Y; q.g[2].bias = b4b;
    q.g[2].N = 25000; q.g[2].ldc = 25000;
    q.g[3] = q.g[2]; q.g[3].Af = hd3; q.g[3].outF = out + P_X2Y;
    k_gemmN<128, 128, 4, 2, EPI_BIAS><<<dim3(8, 196, 4), 512, 0, stream>>>(q);
  }
}